// Round 2
// baseline (860.319 us; speedup 1.0000x reference)
//
#include <hip/hip_runtime.h>
#include <hip/hip_bf16.h>
#include <math.h>
#include <stdint.h>

#define N_NODES 49152
#define N_EDGES 196608
#define NB      2048
#define HIDDEN  256
#define LAT     128
#define FHID    256
#define NFLOWS  4
#define MA      38
#define NNF_    38
#define NEF_    4

typedef __attribute__((ext_vector_type(8))) short bf16x8;
typedef __attribute__((ext_vector_type(4))) float f32x4;

#define MEMPIN() asm volatile("" ::: "memory")
#define BARRIER() asm volatile("s_waitcnt lgkmcnt(0)\n\ts_barrier" ::: "memory")

// ---------- bf16 helpers ----------
__device__ inline uint32_t bf16_rne_bits(float v){
    uint32_t u = __float_as_uint(v);
    u += 0x7fffu + ((u >> 16) & 1u);
    return u & 0xffff0000u;
}
__device__ inline uint16_t to_b16(float v){ return (uint16_t)(bf16_rne_bits(v) >> 16); }
__device__ inline float from_b16(uint16_t u){ return __uint_as_float((uint32_t)u << 16); }
__device__ inline uint32_t pack_hl(float v){
    uint32_t hu = bf16_rne_bits(v);
    float r = v - __uint_as_float(hu);
    uint32_t lu = bf16_rne_bits(r);
    return hu | (lu >> 16);
}

__device__ inline void unpack_frag(const uint4& x, const uint4& y, bf16x8& hi, bf16x8& lo){
    union { bf16x8 v; uint32_t u[4]; } H, L;
    H.u[0] = __builtin_amdgcn_perm(x.y, x.x, 0x07060302u);
    H.u[1] = __builtin_amdgcn_perm(x.w, x.z, 0x07060302u);
    H.u[2] = __builtin_amdgcn_perm(y.y, y.x, 0x07060302u);
    H.u[3] = __builtin_amdgcn_perm(y.w, y.z, 0x07060302u);
    L.u[0] = __builtin_amdgcn_perm(x.y, x.x, 0x05040100u);
    L.u[1] = __builtin_amdgcn_perm(x.w, x.z, 0x05040100u);
    L.u[2] = __builtin_amdgcn_perm(y.y, y.x, 0x05040100u);
    L.u[3] = __builtin_amdgcn_perm(y.w, y.z, 0x05040100u);
    hi = H.v; lo = L.v;
}

// ---------------- init / CSR build ----------------

__global__ void k_init(int* __restrict__ cursor, int* __restrict__ gstart, int* __restrict__ gcnt){
    int i = blockIdx.x*256 + threadIdx.x;
    if (i < N_NODES) cursor[i] = 0;
    if (i < NB){ gstart[i] = 0x7fffffff; gcnt[i] = 0; }
}

__global__ void k_embed(const int* __restrict__ x, const float* __restrict__ emb, uint16_t* __restrict__ h){
    int i = blockIdx.x; int c = threadIdx.x;
    h[(size_t)i*HIDDEN + c] = to_b16(emb[x[i]*HIDDEN + c]);
}

__global__ void k_deg(const int* __restrict__ dst, int* __restrict__ cursor){
    int e = blockIdx.x*256 + threadIdx.x;
    if (e < N_EDGES) atomicAdd(&cursor[dst[e]], 1);
}

__global__ void k_meta(const int* __restrict__ batch, int* __restrict__ gstart, int* __restrict__ gcnt){
    int i = blockIdx.x*256 + threadIdx.x;
    if (i < N_NODES){ int b = batch[i]; atomicMin(&gstart[b], i); atomicAdd(&gcnt[b], 1); }
}

__global__ __launch_bounds__(1024) void k_scan(int* __restrict__ cursor, int* __restrict__ offs){
    __shared__ int part[1024];
    const int tid = threadIdx.x;
    const int CH = N_NODES/1024; // 48
    int local[48];
    int s = 0;
    int base = tid*CH;
    for (int j=0;j<CH;j++){ local[j] = cursor[base+j]; s += local[j]; }
    part[tid] = s;
    __syncthreads();
    for (int off=1; off<1024; off<<=1){
        int v = (tid>=off) ? part[tid-off] : 0;
        __syncthreads();
        part[tid] += v;
        __syncthreads();
    }
    int excl = (tid==0) ? 0 : part[tid-1];
    for (int j=0;j<CH;j++){ offs[base+j] = excl; excl += local[j]; cursor[base+j] = 0; }
    if (tid == 1023) offs[N_NODES] = excl;
}

__global__ void k_scatter(const int* __restrict__ src, const int* __restrict__ dst, const int* __restrict__ attr,
                          const int* __restrict__ offs, int* __restrict__ cursor, int* __restrict__ epack){
    int e = blockIdx.x*256 + threadIdx.x;
    if (e < N_EDGES){
        int d = dst[e];
        int pos = atomicAdd(&cursor[d], 1);
        epack[offs[d] + pos] = (src[e] & 0xffff) | (attr[e] << 16);
    }
}

// ---------------- message aggregation: wave-per-node, 4-edge MLP chunks ----------------

__global__ __launch_bounds__(256) void k_aggr(const uint16_t* __restrict__ h, const float* __restrict__ eemb,
                                              const int* __restrict__ offs, const int* __restrict__ epack,
                                              uint16_t* __restrict__ t){
    __shared__ float sE[NEF_*HIDDEN];
    const int tid  = threadIdx.x;
    #pragma unroll
    for (int q=0;q<NEF_;q++) sE[q*256 + tid] = eemb[q*256 + tid];
    __syncthreads();

    const int wave = tid >> 6;
    const int lane = tid & 63;
    const int node = blockIdx.x*4 + wave;
    const int c4   = lane*4;

    uint2 hu = *(const uint2*)(h + (size_t)node*HIDDEN + c4);
    float4 acc;
    acc.x = __uint_as_float(hu.x << 16);
    acc.y = __uint_as_float(hu.x & 0xffff0000u);
    acc.z = __uint_as_float(hu.y << 16);
    acc.w = __uint_as_float(hu.y & 0xffff0000u);

    const int e0 = offs[node], e1 = offs[node+1];
    for (int j = e0; j < e1; j += 4){
        int p0 = epack[j];
        int p1 = (j+1 < e1) ? epack[j+1] : p0;
        int p2 = (j+2 < e1) ? epack[j+2] : p0;
        int p3 = (j+3 < e1) ? epack[j+3] : p0;
        uint2 g0 = *(const uint2*)(h + (size_t)(p0 & 0xffff)*HIDDEN + c4);
        uint2 g1 = *(const uint2*)(h + (size_t)(p1 & 0xffff)*HIDDEN + c4);
        uint2 g2 = *(const uint2*)(h + (size_t)(p2 & 0xffff)*HIDDEN + c4);
        uint2 g3 = *(const uint2*)(h + (size_t)(p3 & 0xffff)*HIDDEN + c4);
        {
            const float4 ev = *(const float4*)&sE[(p0 >> 16)*HIDDEN + c4];
            acc.x += fmaxf(__uint_as_float(g0.x << 16)        + ev.x, 0.f);
            acc.y += fmaxf(__uint_as_float(g0.x & 0xffff0000u) + ev.y, 0.f);
            acc.z += fmaxf(__uint_as_float(g0.y << 16)        + ev.z, 0.f);
            acc.w += fmaxf(__uint_as_float(g0.y & 0xffff0000u) + ev.w, 0.f);
        }
        if (j+1 < e1){
            const float4 ev = *(const float4*)&sE[(p1 >> 16)*HIDDEN + c4];
            acc.x += fmaxf(__uint_as_float(g1.x << 16)        + ev.x, 0.f);
            acc.y += fmaxf(__uint_as_float(g1.x & 0xffff0000u) + ev.y, 0.f);
            acc.z += fmaxf(__uint_as_float(g1.y << 16)        + ev.z, 0.f);
            acc.w += fmaxf(__uint_as_float(g1.y & 0xffff0000u) + ev.w, 0.f);
        }
        if (j+2 < e1){
            const float4 ev = *(const float4*)&sE[(p2 >> 16)*HIDDEN + c4];
            acc.x += fmaxf(__uint_as_float(g2.x << 16)        + ev.x, 0.f);
            acc.y += fmaxf(__uint_as_float(g2.x & 0xffff0000u) + ev.y, 0.f);
            acc.z += fmaxf(__uint_as_float(g2.y << 16)        + ev.z, 0.f);
            acc.w += fmaxf(__uint_as_float(g2.y & 0xffff0000u) + ev.w, 0.f);
        }
        if (j+3 < e1){
            const float4 ev = *(const float4*)&sE[(p3 >> 16)*HIDDEN + c4];
            acc.x += fmaxf(__uint_as_float(g3.x << 16)        + ev.x, 0.f);
            acc.y += fmaxf(__uint_as_float(g3.x & 0xffff0000u) + ev.y, 0.f);
            acc.z += fmaxf(__uint_as_float(g3.y << 16)        + ev.z, 0.f);
            acc.w += fmaxf(__uint_as_float(g3.y & 0xffff0000u) + ev.w, 0.f);
        }
    }

    uint2 o;
    o.x = (uint32_t)to_b16(acc.x) | ((uint32_t)to_b16(acc.y) << 16);
    o.y = (uint32_t)to_b16(acc.z) | ((uint32_t)to_b16(acc.w) << 16);
    *(uint2*)(t + (size_t)node*HIDDEN + c4) = o;
}

// ---------------- fused weight / activation converter (single launch) ----------------

#define CVT_TOTAL 4408320

__global__ void k_cvt_all(
    const float* __restrict__ conv_w1, const float* __restrict__ conv_w2,
    const float* __restrict__ mu_w, const float* __restrict__ mu_b,
    const float* __restrict__ lv_w, const float* __restrict__ lv_b,
    const float* __restrict__ fw1, const float* __restrict__ fw2,
    const float* __restrict__ dn_w1, const float* __restrict__ dn_w2,
    const float* __restrict__ de_w1, const float* __restrict__ de_w2,
    uint16_t* __restrict__ cw1b, uint16_t* __restrict__ cw2b,
    uint32_t* __restrict__ mvwpk, float* __restrict__ mvb,
    uint16_t* __restrict__ w1hi, uint16_t* __restrict__ w1lo,
    uint16_t* __restrict__ w2hi, uint16_t* __restrict__ w2lo,
    uint16_t* __restrict__ dnw1b, uint16_t* __restrict__ dnw2b,
    uint16_t* __restrict__ dew1b, uint16_t* __restrict__ dew2b)
{
    int i = blockIdx.x*256 + threadIdx.x;
    if (i < 262144){ cw1b[i] = to_b16(conv_w1[i]); return; }
    i -= 262144;
    if (i < 262144){ cw2b[i] = to_b16(conv_w2[i]); return; }
    i -= 262144;
    if (i < 65536){
        int o = i >> 8, k2 = i & 255;
        float v = (o < 128) ? mu_w[o*256 + k2] : lv_w[(o-128)*256 + k2];
        mvwpk[i] = pack_hl(v);
        if (i < 256) mvb[i] = (i < 128) ? mu_b[i] : lv_b[i-128];
        return;
    }
    i -= 65536;
    if (i < 131072){
        int o = (i >> 7) & 255; int kk = i & 127;
        float v = (kk <= (o % 127)) ? fw1[i] : 0.f;
        uint32_t h = bf16_rne_bits(v);
        w1hi[i] = (uint16_t)(h >> 16);
        w1lo[i] = (uint16_t)(bf16_rne_bits(v - __uint_as_float(h)) >> 16);
        return;
    }
    i -= 131072;
    if (i < 262144){
        int o = (i >> 8) & 255; int hh = i & 255;
        float v = ((hh % 127) < (o & 127)) ? fw2[i] : 0.f;
        uint32_t h = bf16_rne_bits(v);
        w2hi[i] = (uint16_t)(h >> 16);
        w2lo[i] = (uint16_t)(bf16_rne_bits(v - __uint_as_float(h)) >> 16);
        return;
    }
    i -= 262144;
    if (i < 32768){ dnw1b[i] = to_b16(dn_w1[i]); return; }
    i -= 32768;
    if (i < 369664){ dnw2b[i] = to_b16(dn_w2[i]); return; }
    i -= 369664;
    if (i < 65536){ dew1b[i] = to_b16(de_w1[i]); return; }
    i -= 65536;
    if (i < 2957312){ dew2b[i] = to_b16(de_w2[i]); }
}

// ---------------- fused conv v2: 16 waves/block, 16x64 per wave ----------------
// h_out = relu(relu(A@W1^T+b1)@W2^T+b2); 64-row tile, 64KB LDS -> 2 blocks/CU
// = 32 waves/CU (full slots). wave w: rowgrp = w>>2 (16 rows), band = w&3 (64 cols).

__global__ __launch_bounds__(1024) void k_conv2(
    const uint16_t* __restrict__ A,
    const uint16_t* __restrict__ W1, const float* __restrict__ B1,
    const uint16_t* __restrict__ W2, const float* __restrict__ B2,
    uint16_t* __restrict__ C)
{
    extern __shared__ __align__(16) char smem[];          // [0,32KB) A-stage, later epilogue2
    uint16_t* h1 = (uint16_t*)(smem + 32768);             // [32KB,64KB) h1 swizzled
    const int tid  = threadIdx.x;
    const int wave = tid >> 6;
    const int lane = tid & 63;
    const int l15  = lane & 15;
    const int lq   = lane >> 4;
    const int l7   = lane & 7;
    const int rg16 = (wave >> 2) * 16;      // row group base
    const int band = wave & 3;              // 64-col band
    const int row0 = blockIdx.x * 64;

    // stage A: 64 rows x 512B = 32KB, 2 iters x 1024 threads x 16B
    #pragma unroll
    for (int it = 0; it < 2; ++it) {
        int s  = it*1024 + tid;
        int m  = s >> 5;
        int gl = (s & 31) ^ (m & 7);
        const char* gp = (const char*)A + ((size_t)(row0+m)*HIDDEN)*2 + gl*16;
        __builtin_amdgcn_global_load_lds(
            (const __attribute__((address_space(1))) uint32_t*)gp,
            (__attribute__((address_space(3))) uint32_t*)(smem + (size_t)s*16),
            16, 0, 0);
    }

    // W1 first fragments issued before the stage drain (overlap latency)
    bf16x8 bw[2][4];
    #pragma unroll
    for (int nt=0;nt<4;nt++)
        bw[0][nt] = *(const bf16x8*)(W1 + (size_t)(band*64 + nt*16 + l15)*HIDDEN + lq*8);
    MEMPIN();
    __syncthreads();   // drains vmcnt(0): stage + bw[0] both ready

    // ---- GEMM1: 16x64 tile per wave ----
    f32x4 acc[4];
    #pragma unroll
    for (int nt=0;nt<4;nt++) acc[nt] = (f32x4)(0.f);

    #pragma unroll
    for (int kc = 0; kc < 8; ++kc){
        int cur = kc & 1, nxt = cur ^ 1;
        if (kc < 7){
            #pragma unroll
            for (int nt=0;nt<4;nt++)
                bw[nxt][nt] = *(const bf16x8*)(W1 + (size_t)(band*64 + nt*16 + l15)*HIDDEN + (kc+1)*32 + lq*8);
        }
        const int mb = (rg16 + l15) << 5;
        int g = kc*4 + lq;
        bf16x8 a = *(const bf16x8*)(smem + (size_t)(mb + (g ^ l7))*16);
        #pragma unroll
        for (int nt=0;nt<4;nt++)
            acc[nt] = __builtin_amdgcn_mfma_f32_16x16x32_bf16(a, bw[cur][nt], acc[nt], 0, 0, 0);
    }

    // prefetch W2 first fragments: in flight across epilogue1 + barrier
    bf16x8 bw2[2][4];
    #pragma unroll
    for (int nt=0;nt<4;nt++)
        bw2[0][nt] = *(const bf16x8*)(W2 + (size_t)(band*64 + nt*16 + l15)*HIDDEN + lq*8);
    MEMPIN();

    // epilogue1 -> h1 (granule-swizzled)
    #pragma unroll
    for (int nt=0;nt<4;nt++){
        int col = band*64 + nt*16 + l15;
        float bb = B1[col];
        #pragma unroll
        for (int reg=0;reg<4;reg++){
            int r = rg16 + lq*4 + reg;
            float v = fmaxf(acc[nt][reg] + bb, 0.f);
            h1[(r*32 + ((col>>3) ^ (r&7)))*8 + (col&7)] = to_b16(v);
        }
    }
    BARRIER();   // lgkm drain only: bw2 prefetch stays in flight

    // ---- GEMM2 ----
    #pragma unroll
    for (int nt=0;nt<4;nt++) acc[nt] = (f32x4)(0.f);

    #pragma unroll
    for (int kc = 0; kc < 8; ++kc){
        int cur = kc & 1, nxt = cur ^ 1;
        if (kc < 7){
            #pragma unroll
            for (int nt=0;nt<4;nt++)
                bw2[nxt][nt] = *(const bf16x8*)(W2 + (size_t)(band*64 + nt*16 + l15)*HIDDEN + (kc+1)*32 + lq*8);
        }
        const int m = rg16 + l15;
        bf16x8 a = *(const bf16x8*)(h1 + (size_t)(m*32 + ((kc*4 + lq) ^ (m & 7)))*8);
        #pragma unroll
        for (int nt=0;nt<4;nt++)
            acc[nt] = __builtin_amdgcn_mfma_f32_16x16x32_bf16(a, bw2[cur][nt], acc[nt], 0, 0, 0);
    }

    // epilogue2 -> A-stage area (dead since epilogue1 barrier), same swizzle.
    // No barrier needed before these writes: all waves are past GEMM1.
    uint16_t* rs = (uint16_t*)smem;
    #pragma unroll
    for (int nt=0;nt<4;nt++){
        int col = band*64 + nt*16 + l15;
        float bb = B2[col];
        #pragma unroll
        for (int reg=0;reg<4;reg++){
            int r = rg16 + lq*4 + reg;
            float v = fmaxf(acc[nt][reg] + bb, 0.f);
            rs[(r*32 + ((col>>3) ^ (r&7)))*8 + (col&7)] = to_b16(v);
        }
    }
    BARRIER();

    // coalesced copy-out: 2 iters x 1024 threads x 16B
    #pragma unroll
    for (int it = 0; it < 2; ++it){
        int idx = it*1024 + tid;
        int row = idx >> 5;
        int gc  = idx & 31;
        uint4 d = *(const uint4*)(smem + (size_t)(row*32 + (gc ^ (row & 7)))*16);
        *(uint4*)(C + (size_t)(row0+row)*HIDDEN + gc*8) = d;
    }
}

// ---------------- MFMA GEMM (mu/lv + decoders) ----------------

template<int SPLIT, int OUTM>
__global__ __launch_bounds__(256) void mfma_gemm(
    const void* __restrict__ Ap, const void* __restrict__ Wp,
    const float* __restrict__ bias, void* __restrict__ Cp,
    int M, int N, int K, int relu)
{
    extern __shared__ __align__(16) char smem[];
    const int tid  = threadIdx.x;
    const int wave = tid >> 6;
    const int lane = tid & 63;
    const int l15  = lane & 15;
    const int lq   = lane >> 4;
    const int l7   = lane & 7;
    const int row0 = blockIdx.y * 64;
    const int n0   = blockIdx.x * 256;
    const int ELB  = SPLIT ? 4 : 2;
    const int KC   = (K < 256) ? K : 256;
    const int GR   = (KC * ELB) >> 4;
    const int rsh  = (GR == 64) ? 6 : ((GR == 32) ? 5 : 4);

    f32x4 acc[4][4];
    #pragma unroll
    for (int mt=0;mt<4;mt++)
        #pragma unroll
        for (int nt=0;nt<4;nt++) acc[mt][nt] = (f32x4)(0.f);

    const char* Ab = (const char*)Ap;
    const char* Wb = (const char*)Wp;

    for (int kbase = 0; kbase < K; kbase += KC) {
        const int rounds = GR >> 2;
        for (int it = 0; it < rounds; ++it) {
            int sbase = it*256 + wave*64;
            int s  = sbase + lane;
            int m  = s >> rsh;
            int gl = (s & (GR-1)) ^ (m & 7);
            const char* gp = Ab + ((size_t)(row0+m)*K + kbase)*ELB + gl*16;
            __builtin_amdgcn_global_load_lds(
                (const __attribute__((address_space(1))) uint32_t*)gp,
                (__attribute__((address_space(3))) uint32_t*)(smem + sbase*16),
                16, 0, 0);
        }
        __syncthreads();

        for (int kc = 0; kc < (KC >> 5); ++kc) {
            bf16x8 bhi[4], blo[4];
            #pragma unroll
            for (int nt=0;nt<4;nt++){
                int n = n0 + wave*64 + nt*16 + l15;
                if (n >= N) n = N-1;
                if (SPLIT){
                    const uint4* wp4 = (const uint4*)(Wb + ((size_t)n*K + kbase + kc*32 + lq*8)*4);
                    uint4 xx = wp4[0], yy = wp4[1];
                    unpack_frag(xx, yy, bhi[nt], blo[nt]);
                } else {
                    bhi[nt] = *(const bf16x8*)(Wb + ((size_t)n*K + kbase + kc*32 + lq*8)*2);
                }
            }
            #pragma unroll
            for (int mt=0;mt<4;mt++){
                const int mb = (mt*16 + l15) << rsh;
                if (SPLIT){
                    int g0 = kc*8 + lq*2;
                    uint4 xx = *(const uint4*)(smem + (size_t)(mb + ((g0  ) ^ l7))*16);
                    uint4 yy = *(const uint4*)(smem + (size_t)(mb + ((g0+1) ^ l7))*16);
                    bf16x8 ahi, alo;
                    unpack_frag(xx, yy, ahi, alo);
                    #pragma unroll
                    for (int nt=0;nt<4;nt++){
                        acc[mt][nt] = __builtin_amdgcn_mfma_f32_16x16x32_bf16(ahi, bhi[nt], acc[mt][nt], 0, 0, 0);
                        acc[mt][nt] = __builtin_amdgcn_mfma_f32_16x16x32_bf16(ahi, blo[nt], acc[mt][nt], 0, 0, 0);
                        acc[mt][nt] = __builtin_amdgcn_mfma_f32_16x16x32_bf16(alo, bhi[nt], acc[mt][nt], 0, 0, 0);
                    }
                } else {
                    int g = kc*4 + lq;
                    bf16x8 a = *(const bf16x8*)(smem + (size_t)(mb + (g ^ l7))*16);
                    #pragma unroll
                    for (int nt=0;nt<4;nt++){
                        acc[mt][nt] = __builtin_amdgcn_mfma_f32_16x16x32_bf16(a, bhi[nt], acc[mt][nt], 0, 0, 0);
                    }
                }
            }
        }
        __syncthreads();
    }

    const int ES = (OUTM == 1) ? 2 : 4;
    char* rs = smem + wave*(64*64*ES);
    const int colbase = n0 + wave*64;
    #pragma unroll
    for (int mt=0;mt<4;mt++){
        #pragma unroll
        for (int nt=0;nt<4;nt++){
            int cl = nt*16 + l15;
            int col = colbase + cl;
            float bb = bias[col < N ? col : N-1];
            #pragma unroll
            for (int reg=0;reg<4;reg++){
                int r = mt*16 + lq*4 + reg;
                float v = acc[mt][nt][reg] + bb;
                if (relu) v = fmaxf(v, 0.f);
                if (OUTM == 1) ((uint16_t*)rs)[r*64 + cl] = to_b16(v);
                else           ((float*)rs)[r*64 + cl] = v;
            }
        }
    }
    __syncthreads();
    for (int it = 0; it < 32; ++it) {
        int r   = it*2 + (lane>>5);
        int clp = lane & 31;
        int col = colbase + clp*2;
        if (col < N){
            if (OUTM == 1){
                uint32_t d = *(const uint32_t*)((const uint16_t*)rs + r*64 + clp*2);
                *(uint32_t*)((char*)Cp + ((size_t)(row0+r)*N + col)*2) = d;
            } else {
                float2 d = *(const float2*)((const float*)rs + r*64 + clp*2);
                *(float2*)((float*)Cp + (size_t)(row0+r)*N + col) = d;
            }
        }
    }
}

// ---------------- pooling + z0 elementwise ----------------

__global__ void k_pool(const uint16_t* __restrict__ h, const int* __restrict__ gstart,
                       const int* __restrict__ gcnt, uint32_t* __restrict__ hg){
    int b = blockIdx.x; int c = threadIdx.x;
    int s0 = gstart[b]; int n = gcnt[b];
    float s = 0.f;
    for (int j=0;j<n;j++) s += from_b16(h[(size_t)(s0+j)*HIDDEN + c]);
    hg[(size_t)b*HIDDEN + c] = pack_hl(s);
}

__global__ void k_z0(const float* __restrict__ mv, const float* __restrict__ eps,
                     float* __restrict__ mu_o, float* __restrict__ lv_o, float* __restrict__ z0_o){
    int i = blockIdx.x*256 + threadIdx.x;
    if (i >= NB*LAT) return;
    int b = i >> 7, l = i & 127;
    float m = mv[(size_t)b*256 + l];
    float v = mv[(size_t)b*256 + l + 128];
    mu_o[i] = m;
    lv_o[i] = v;
    z0_o[i] = m + eps[i]*expf(0.5f*v);
}

// ---------------- fused MFMA flows v5: software-pipelined weight stream ----------------

__global__ __launch_bounds__(1024) void k_flows_mfma5(
    const float* __restrict__ z0,
    const uint16_t* __restrict__ w1hi, const uint16_t* __restrict__ w1lo, const float* __restrict__ fb1,
    const uint16_t* __restrict__ w2hi, const uint16_t* __restrict__ w2lo, const float* __restrict__ fb2,
    float* __restrict__ zK, uint16_t* __restrict__ zkb, float* __restrict__ sld)
{
    __shared__ __align__(16) uint16_t zhi[16][136];
    __shared__ __align__(16) uint16_t zlo[16][136];
    __shared__ __align__(16) uint16_t h1hi[16][280];
    __shared__ __align__(16) uint16_t h1lo[16][280];
    __shared__ __align__(16) float    oS[16][268];
    const int tid  = threadIdx.x;
    const int wave = tid >> 6;
    const int lane = tid & 63;
    const int l15  = lane & 15;
    const int lq   = lane >> 4;
    const int g0   = blockIdx.x * 16;
    const int col  = wave*16 + l15;

    const size_t wc1 = (size_t)col*LAT  + lq*8;
    const size_t wc2 = (size_t)col*FHID + lq*8;

    bf16x8 a1h[4], a1l[4];
    bf16x8 a2h[8], a2l[8];

    auto LD_W1 = [&](int kf){
        const uint16_t* W1h = w1hi + (size_t)kf*FHID*LAT;
        const uint16_t* W1l = w1lo + (size_t)kf*FHID*LAT;
        #pragma unroll
        for (int kc=0;kc<4;kc++){
            a1h[kc] = *(const bf16x8*)(W1h + wc1 + kc*32);
            a1l[kc] = *(const bf16x8*)(W1l + wc1 + kc*32);
        }
    };
    auto LD_W2A = [&](int kf){
        const uint16_t* W2h = w2hi + (size_t)kf*2*LAT*FHID;
        const uint16_t* W2l = w2lo + (size_t)kf*2*LAT*FHID;
        #pragma unroll
        for (int kc=0;kc<4;kc++){
            a2h[kc] = *(const bf16x8*)(W2h + wc2 + kc*32);
            a2l[kc] = *(const bf16x8*)(W2l + wc2 + kc*32);
        }
    };
    auto LD_W2B = [&](int kf){
        const uint16_t* W2h = w2hi + (size_t)kf*2*LAT*FHID;
        const uint16_t* W2l = w2lo + (size_t)kf*2*LAT*FHID;
        #pragma unroll
        for (int kc=4;kc<8;kc++){
            a2h[kc] = *(const bf16x8*)(W2h + wc2 + kc*32);
            a2l[kc] = *(const bf16x8*)(W2l + wc2 + kc*32);
        }
    };

    LD_W1(0);
    LD_W2A(0);
    MEMPIN();

    #pragma unroll
    for (int q=0;q<2;q++){
        int idx = q*1024 + tid;
        int r = idx >> 7, l = idx & 127;
        float v = z0[(size_t)(g0 + r)*LAT + l];
        uint32_t h = bf16_rne_bits(v);
        zhi[r][l] = (uint16_t)(h >> 16);
        zlo[r][l] = (uint16_t)(bf16_rne_bits(v - __uint_as_float(h)) >> 16);
    }
    float ldacc = 0.f;
    BARRIER();

    #pragma unroll
    for (int kf=0; kf<NFLOWS; kf++){
        const float* b1 = fb1 + kf*FHID;
        const float* b2 = fb2 + kf*2*LAT;

        {
            f32x4 acc = (f32x4)(0.f);
            #pragma unroll
            for (int kc=0;kc<4;kc++){
                bf16x8 ah = *(const bf16x8*)&zhi[l15][kc*32 + lq*8];
                bf16x8 al = *(const bf16x8*)&zlo[l15][kc*32 + lq*8];
                acc = __builtin_amdgcn_mfma_f32_16x16x32_bf16(ah, a1h[kc], acc, 0, 0, 0);
                acc = __builtin_amdgcn_mfma_f32_16x16x32_bf16(ah, a1l[kc], acc, 0, 0, 0);
                acc = __builtin_amdgcn_mfma_f32_16x16x32_bf16(al, a1h[kc], acc, 0, 0, 0);
            }
            MEMPIN();
            LD_W2B(kf);
            MEMPIN();
            float bb = b1[col];
            #pragma unroll
            for (int reg=0;reg<4;reg++){
                int r = lq*4 + reg;
                float v = fmaxf(acc[reg] + bb, 0.f);
                uint32_t h = bf16_rne_bits(v);
                h1hi[r][col] = (uint16_t)(h >> 16);
                h1lo[r][col] = (uint16_t)(bf16_rne_bits(v - __uint_as_float(h)) >> 16);
            }
        }
        BARRIER();

        {
            f32x4 acc = (f32x4)(0.f);
            #pragma unroll
            for (int kc=0;kc<4;kc++){
                bf16x8 ah = *(const bf16x8*)&h1hi[l15][kc*32 + lq*8];
                bf16x8 al = *(const bf16x8*)&h1lo[l15][kc*32 + lq*8];
                acc = __builtin_amdgcn_mfma_f32_16x16x32_bf16(ah, a2h[kc], acc, 0, 0, 0);
                acc = __builtin_amdgcn_mfma_f32_16x16x32_bf16(ah, a2l[kc], acc, 0, 0, 0);
                acc = __builtin_amdgcn_mfma_f32_16x16x32_bf16(al, a2h[kc], acc, 0, 0, 0);
            }
            MEMPIN();
            if (kf < NFLOWS-1) LD_W1(kf+1);
            MEMPIN();
            #pragma unroll
            for (int kc=4;kc<8;kc++){
                bf16x8 ah = *(const bf16x8*)&h1hi[l15][kc*32 + lq*8];
                bf16x8 al = *(const bf16x8*)&h1lo[l15][kc*32 + lq*8];
                acc = __builtin_amdgcn_mfma_f32_16x16x32_bf16(ah, a2h[kc], acc, 0, 0, 0);
                acc = __builtin_amdgcn_mfma_f32_16x16x32_bf16(ah, a2l[kc], acc, 0, 0, 0);
                acc = __builtin_amdgcn_mfma_f32_16x16x32_bf16(al, a2h[kc], acc, 0, 0, 0);
            }
            MEMPIN();
            if (kf < NFLOWS-1) LD_W2A(kf+1);
            MEMPIN();
            float bb = b2[col];
            #pragma unroll
            for (int reg=0;reg<4;reg++)
                oS[lq*4 + reg][col] = acc[reg] + bb;
        }
        BARRIER();

        {
            const int r = wave;
            float ldp = 0.f;
            #pragma unroll
            for (int j=0;j<2;j++){
                int l = lane + j*64;
                float m = oS[r][l];
                float s = oS[r][l + 128];
                float g = 1.f/(1.f + expf(-s));
                float zv = __uint_as_float((uint32_t)zhi[r][l] << 16)
                         + __uint_as_float((uint32_t)zlo[r][l] << 16);
                float zn = g*zv + (1.f - g)*m;
                uint32_t h = bf16_rne_bits(zn);
                zhi[r][l] = (uint16_t)(h >> 16);
                zlo[r][l] = (uint16_t)(bf16_rne_bits(zn - __uint_as_float(h)) >> 16);
                ldp += logf(g + 1e-8f);
            }
            #pragma unroll
            for (int off=1; off<64; off<<=1) ldp += __shfl_xor(ldp, off);
            ldacc += ldp;
        }
        BARRIER();
    }

    #pragma unroll
    for (int q=0;q<2;q++){
        int idx = q*1024 + tid;
        int r = idx >> 7, l = idx & 127;
        uint32_t h = (uint32_t)zhi[r][l] << 16;
        float zv = __uint_as_float(h) + __uint_as_float((uint32_t)zlo[r][l] << 16);
        zK[(size_t)(g0+r)*LAT + l] = zv;
        zkb[(size_t)(g0+r)*LAT + l] = (uint16_t)(h >> 16);
    }
    if (lane == 0) sld[g0 + wave] = ldacc;
}

// ---------------- edge-logits symmetrize ----------------

__global__ void k_sym(const float* __restrict__ raw, float* __restrict__ outp){
    int idx = blockIdx.x*256 + threadIdx.x;
    const int total = NB*MA*MA;
    if (idx >= total) return;
    int b = idx / (MA*MA);
    int rem = idx - b*(MA*MA);
    int i = rem / MA;
    int j = rem - i*MA;
    const size_t base = (size_t)b*(MA*MA*NEF_);
    const float4 a  = *(const float4*)(raw + base + (size_t)(i*MA + j)*NEF_);
    const float4 bt = *(const float4*)(raw + base + (size_t)(j*MA + i)*NEF_);
    float4 r;
    r.x = (a.x + bt.x)*0.5f;
    r.y = (a.y + bt.y)*0.5f;
    r.z = (a.z + bt.z)*0.5f;
    r.w = (a.w + bt.w)*0.5f;
    *(float4*)(outp + base + (size_t)(i*MA + j)*NEF_) = r;
}

// ---------------- launch ----------------

extern "C" void kernel_launch(void* const* d_in, const int* in_sizes, int n_in,
                              void* d_out, int out_size, void* d_ws, size_t ws_size,
                              hipStream_t stream){
    (void)in_sizes; (void)n_in; (void)out_size; (void)ws_size;
    const int*   x        = (const int*)d_in[0];
    const int*   eidx     = (const int*)d_in[1];
    const int*   eattr    = (const int*)d_in[2];
    const int*   batch    = (const int*)d_in[3];
    const float* eps      = (const float*)d_in[4];
    const float* node_emb = (const float*)d_in[5];
    const float* edge_emb = (const float*)d_in[6];
    const float* conv_w1  = (const float*)d_in[7];
    const float* conv_b1  = (const float*)d_in[8];
    const float* conv_w2  = (const float*)d_in[9];
    const float* conv_b2  = (const float*)d_in[10];
    const float* mu_w     = (const float*)d_in[11];
    const float* mu_b     = (const float*)d_in[12];
    const float* lv_w     = (const float*)d_in[13];
    const float* lv_b     = (const float*)d_in[14];
    const float* fw1      = (const float*)d_in[15];
    const float* fb1      = (const float*)d_in[16];
    const float* fw2      = (const float*)d_in[17];
    const float* fb2      = (const float*)d_in[18];
    const float* dn_w1    = (const float*)d_in[19];
    const float* dn_b1    = (const float*)d_in[20];
    const float* dn_w2    = (const float*)d_in[21];
    const float* dn_b2    = (const float*)d_in[22];
    const float* de_w1    = (const float*)d_in[23];
    const float* de_b1    = (const float*)d_in[24];
    const float* de_w2    = (const float*)d_in[25];
    const float* de_b2    = (const float*)d_in[26];

    float* out = (float*)d_out;
    const size_t off_node = 0;
    const size_t off_edge = (size_t)NB*MA*NNF_;
    const size_t off_mu   = off_edge + (size_t)NB*MA*MA*NEF_;
    const size_t off_lv   = off_mu + (size_t)NB*LAT;
    const size_t off_z0   = off_lv + (size_t)NB*LAT;
    const size_t off_zk   = off_z0 + (size_t)NB*LAT;
    const size_t off_sld  = off_zk + (size_t)NB*LAT;
    (void)off_node;

    char* p = (char*)d_ws;
    auto alloc = [&](size_t bytes)->char*{ char* r = p; p += (bytes + 255) & ~(size_t)255; return r; };
    uint16_t* h_b   = (uint16_t*)alloc((size_t)N_NODES*HIDDEN*2);
    uint16_t* t_b   = (uint16_t*)alloc((size_t)N_NODES*HIDDEN*2);
    int*   offs   = (int*)  alloc((size_t)(N_NODES+1)*4);
    int*   cursor = (int*)  alloc((size_t)N_NODES*4);
    int*   epack  = (int*)  alloc((size_t)N_EDGES*4);
    int*   gstart = (int*)  alloc((size_t)NB*4);
    int*   gcnt   = (int*)  alloc((size_t)NB*4);
    uint32_t* hg_pk = (uint32_t*)alloc((size_t)NB*HIDDEN*4);
    float* mv       = (float*)alloc((size_t)NB*256*4);
    uint16_t* cw1b  = (uint16_t*)alloc((size_t)4*HIDDEN*HIDDEN*2);
    uint16_t* cw2b  = (uint16_t*)alloc((size_t)4*HIDDEN*HIDDEN*2);
    uint32_t* mvwpk = (uint32_t*)alloc((size_t)256*256*4);
    float*    mvb   = (float*)  alloc((size_t)256*4);
    uint16_t* w1hi  = (uint16_t*)alloc((size_t)NFLOWS*FHID*LAT*2);
    uint16_t* w1lo  = (uint16_t*)alloc((size_t)NFLOWS*FHID*LAT*2);
    uint16_t* w2hi  = (uint16_t*)alloc((size_t)NFLOWS*2*LAT*FHID*2);
    uint16_t* w2lo  = (uint16_t*)alloc((size_t)NFLOWS*2*LAT*FHID*2);
    uint16_t* dnw1b = (uint16_t*)alloc((size_t)256*LAT*2);
    uint16_t* dnw2b = (uint16_t*)alloc((size_t)MA*NNF_*256*2);
    uint16_t* dew1b = (uint16_t*)alloc((size_t)512*LAT*2);
    uint16_t* dew2b = (uint16_t*)alloc((size_t)MA*MA*NEF_*512*2);
    uint16_t* zkb   = (uint16_t*)alloc((size_t)NB*LAT*2);
    uint16_t* hnb   = (uint16_t*)alloc((size_t)NB*256*2);
    uint16_t* heb   = (uint16_t*)alloc((size_t)NB*512*2);
    float* edge_raw = (float*)alloc((size_t)NB*MA*MA*NEF_*4);

    const int* esrc = eidx;
    const int* edst = eidx + N_EDGES;

    k_cvt_all<<<(CVT_TOTAL+255)/256, 256, 0, stream>>>(
        conv_w1, conv_w2, mu_w, mu_b, lv_w, lv_b, fw1, fw2,
        dn_w1, dn_w2, de_w1, de_w2,
        cw1b, cw2b, mvwpk, mvb, w1hi, w1lo, w2hi, w2lo,
        dnw1b, dnw2b, dew1b, dew2b);

    k_init   <<<(N_NODES+255)/256, 256, 0, stream>>>(cursor, gstart, gcnt);
    k_embed  <<<N_NODES, HIDDEN, 0, stream>>>(x, node_emb, h_b);
    k_deg    <<<(N_EDGES+255)/256, 256, 0, stream>>>(edst, cursor);
    k_meta   <<<(N_NODES+255)/256, 256, 0, stream>>>(batch, gstart, gcnt);
    k_scan   <<<1, 1024, 0, stream>>>(cursor, offs);
    k_scatter<<<(N_EDGES+255)/256, 256, 0, stream>>>(esrc, edst, eattr, offs, cursor, epack);

    const size_t SM32 = 32768, SM64 = 65536;
    for (int k=0;k<4;k++){
        k_aggr<<<N_NODES/4, 256, 0, stream>>>(h_b, edge_emb, offs, epack, t_b);
        k_conv2<<<N_NODES/64, 1024, SM64, stream>>>(
            t_b,
            cw1b + (size_t)k*HIDDEN*HIDDEN, conv_b1 + (size_t)k*HIDDEN,
            cw2b + (size_t)k*HIDDEN*HIDDEN, conv_b2 + (size_t)k*HIDDEN,
            h_b);
    }

    k_pool<<<NB, HIDDEN, 0, stream>>>(h_b, gstart, gcnt, hg_pk);
    mfma_gemm<1,2><<<dim3(1, NB/64), 256, SM64, stream>>>(hg_pk, mvwpk, mvb, mv, NB, 256, HIDDEN, 0);
    k_z0<<<(NB*LAT+255)/256, 256, 0, stream>>>(mv, eps, out+off_mu, out+off_lv, out+off_z0);

    k_flows_mfma5<<<NB/16, 1024, 0, stream>>>(out+off_z0, w1hi, w1lo, fb1, w2hi, w2lo, fb2,
                                              out+off_zk, zkb, out+off_sld);

    mfma_gemm<0,1><<<dim3(1, NB/64), 256, SM32, stream>>>(zkb, dnw1b, dn_b1, hnb, NB, 256, LAT, 1);
    mfma_gemm<0,2><<<dim3(6, NB/64), 256, SM64, stream>>>(hnb, dnw2b, dn_b2, out+off_node, NB, MA*NNF_, 256, 0);
    mfma_gemm<0,1><<<dim3(2, NB/64), 256, SM32, stream>>>(zkb, dew1b, de_b1, heb, NB, 512, LAT, 1);
    mfma_gemm<0,2><<<dim3(23, NB/64), 256, SM64, stream>>>(heb, dew2b, de_b2, edge_raw, NB, MA*MA*NEF_, 512, 0);
    k_sym<<<(NB*MA*MA + 255)/256, 256, 0, stream>>>(edge_raw, out + off_edge);
}

// Round 3
// 647.599 us; speedup vs baseline: 1.3285x; 1.3285x over previous
//
#include <hip/hip_runtime.h>
#include <hip/hip_bf16.h>
#include <math.h>
#include <stdint.h>

#define N_NODES 49152
#define N_EDGES 196608
#define NB      2048
#define HIDDEN  256
#define LAT     128
#define FHID    256
#define NFLOWS  4
#define MA      38
#define NNF_    38
#define NEF_    4

typedef __attribute__((ext_vector_type(8))) short bf16x8;
typedef __attribute__((ext_vector_type(4))) float f32x4;

#define MEMPIN() asm volatile("" ::: "memory")
#define BARRIER() asm volatile("s_waitcnt lgkmcnt(0)\n\ts_barrier" ::: "memory")

// ---------- bf16 helpers ----------
__device__ inline uint32_t bf16_rne_bits(float v){
    uint32_t u = __float_as_uint(v);
    u += 0x7fffu + ((u >> 16) & 1u);
    return u & 0xffff0000u;
}
__device__ inline uint16_t to_b16(float v){ return (uint16_t)(bf16_rne_bits(v) >> 16); }
__device__ inline float from_b16(uint16_t u){ return __uint_as_float((uint32_t)u << 16); }
__device__ inline uint32_t pack_hl(float v){
    uint32_t hu = bf16_rne_bits(v);
    float r = v - __uint_as_float(hu);
    uint32_t lu = bf16_rne_bits(r);
    return hu | (lu >> 16);
}

__device__ inline void unpack_frag(const uint4& x, const uint4& y, bf16x8& hi, bf16x8& lo){
    union { bf16x8 v; uint32_t u[4]; } H, L;
    H.u[0] = __builtin_amdgcn_perm(x.y, x.x, 0x07060302u);
    H.u[1] = __builtin_amdgcn_perm(x.w, x.z, 0x07060302u);
    H.u[2] = __builtin_amdgcn_perm(y.y, y.x, 0x07060302u);
    H.u[3] = __builtin_amdgcn_perm(y.w, y.z, 0x07060302u);
    L.u[0] = __builtin_amdgcn_perm(x.y, x.x, 0x05040100u);
    L.u[1] = __builtin_amdgcn_perm(x.w, x.z, 0x05040100u);
    L.u[2] = __builtin_amdgcn_perm(y.y, y.x, 0x05040100u);
    L.u[3] = __builtin_amdgcn_perm(y.w, y.z, 0x05040100u);
    hi = H.v; lo = L.v;
}

// ---------------- init / CSR build ----------------

__global__ void k_init(int* __restrict__ cursor, int* __restrict__ gstart, int* __restrict__ gcnt){
    int i = blockIdx.x*256 + threadIdx.x;
    if (i < N_NODES) cursor[i] = 0;
    if (i < NB){ gstart[i] = 0x7fffffff; gcnt[i] = 0; }
}

__global__ void k_embed(const int* __restrict__ x, const float* __restrict__ emb, uint16_t* __restrict__ h){
    int i = blockIdx.x; int c = threadIdx.x;
    h[(size_t)i*HIDDEN + c] = to_b16(emb[x[i]*HIDDEN + c]);
}

__global__ void k_deg(const int* __restrict__ dst, int* __restrict__ cursor){
    int e = blockIdx.x*256 + threadIdx.x;
    if (e < N_EDGES) atomicAdd(&cursor[dst[e]], 1);
}

__global__ void k_meta(const int* __restrict__ batch, int* __restrict__ gstart, int* __restrict__ gcnt){
    int i = blockIdx.x*256 + threadIdx.x;
    if (i < N_NODES){ int b = batch[i]; atomicMin(&gstart[b], i); atomicAdd(&gcnt[b], 1); }
}

__global__ __launch_bounds__(1024) void k_scan(int* __restrict__ cursor, int* __restrict__ offs){
    __shared__ int part[1024];
    const int tid = threadIdx.x;
    const int CH = N_NODES/1024; // 48
    int local[48];
    int s = 0;
    int base = tid*CH;
    for (int j=0;j<CH;j++){ local[j] = cursor[base+j]; s += local[j]; }
    part[tid] = s;
    __syncthreads();
    for (int off=1; off<1024; off<<=1){
        int v = (tid>=off) ? part[tid-off] : 0;
        __syncthreads();
        part[tid] += v;
        __syncthreads();
    }
    int excl = (tid==0) ? 0 : part[tid-1];
    for (int j=0;j<CH;j++){ offs[base+j] = excl; excl += local[j]; cursor[base+j] = 0; }
    if (tid == 1023) offs[N_NODES] = excl;
}

__global__ void k_scatter(const int* __restrict__ src, const int* __restrict__ dst, const int* __restrict__ attr,
                          const int* __restrict__ offs, int* __restrict__ cursor, int* __restrict__ epack){
    int e = blockIdx.x*256 + threadIdx.x;
    if (e < N_EDGES){
        int d = dst[e];
        int pos = atomicAdd(&cursor[d], 1);
        epack[offs[d] + pos] = (src[e] & 0xffff) | (attr[e] << 16);
    }
}

// ---------------- message aggregation: wave-per-node, 4-edge MLP chunks ----------------

__global__ __launch_bounds__(256) void k_aggr(const uint16_t* __restrict__ h, const float* __restrict__ eemb,
                                              const int* __restrict__ offs, const int* __restrict__ epack,
                                              uint16_t* __restrict__ t){
    __shared__ float sE[NEF_*HIDDEN];
    const int tid  = threadIdx.x;
    #pragma unroll
    for (int q=0;q<NEF_;q++) sE[q*256 + tid] = eemb[q*256 + tid];
    __syncthreads();

    const int wave = tid >> 6;
    const int lane = tid & 63;
    const int node = blockIdx.x*4 + wave;
    const int c4   = lane*4;

    uint2 hu = *(const uint2*)(h + (size_t)node*HIDDEN + c4);
    float4 acc;
    acc.x = __uint_as_float(hu.x << 16);
    acc.y = __uint_as_float(hu.x & 0xffff0000u);
    acc.z = __uint_as_float(hu.y << 16);
    acc.w = __uint_as_float(hu.y & 0xffff0000u);

    const int e0 = offs[node], e1 = offs[node+1];
    for (int j = e0; j < e1; j += 4){
        int p0 = epack[j];
        int p1 = (j+1 < e1) ? epack[j+1] : p0;
        int p2 = (j+2 < e1) ? epack[j+2] : p0;
        int p3 = (j+3 < e1) ? epack[j+3] : p0;
        uint2 g0 = *(const uint2*)(h + (size_t)(p0 & 0xffff)*HIDDEN + c4);
        uint2 g1 = *(const uint2*)(h + (size_t)(p1 & 0xffff)*HIDDEN + c4);
        uint2 g2 = *(const uint2*)(h + (size_t)(p2 & 0xffff)*HIDDEN + c4);
        uint2 g3 = *(const uint2*)(h + (size_t)(p3 & 0xffff)*HIDDEN + c4);
        {
            const float4 ev = *(const float4*)&sE[(p0 >> 16)*HIDDEN + c4];
            acc.x += fmaxf(__uint_as_float(g0.x << 16)        + ev.x, 0.f);
            acc.y += fmaxf(__uint_as_float(g0.x & 0xffff0000u) + ev.y, 0.f);
            acc.z += fmaxf(__uint_as_float(g0.y << 16)        + ev.z, 0.f);
            acc.w += fmaxf(__uint_as_float(g0.y & 0xffff0000u) + ev.w, 0.f);
        }
        if (j+1 < e1){
            const float4 ev = *(const float4*)&sE[(p1 >> 16)*HIDDEN + c4];
            acc.x += fmaxf(__uint_as_float(g1.x << 16)        + ev.x, 0.f);
            acc.y += fmaxf(__uint_as_float(g1.x & 0xffff0000u) + ev.y, 0.f);
            acc.z += fmaxf(__uint_as_float(g1.y << 16)        + ev.z, 0.f);
            acc.w += fmaxf(__uint_as_float(g1.y & 0xffff0000u) + ev.w, 0.f);
        }
        if (j+2 < e1){
            const float4 ev = *(const float4*)&sE[(p2 >> 16)*HIDDEN + c4];
            acc.x += fmaxf(__uint_as_float(g2.x << 16)        + ev.x, 0.f);
            acc.y += fmaxf(__uint_as_float(g2.x & 0xffff0000u) + ev.y, 0.f);
            acc.z += fmaxf(__uint_as_float(g2.y << 16)        + ev.z, 0.f);
            acc.w += fmaxf(__uint_as_float(g2.y & 0xffff0000u) + ev.w, 0.f);
        }
        if (j+3 < e1){
            const float4 ev = *(const float4*)&sE[(p3 >> 16)*HIDDEN + c4];
            acc.x += fmaxf(__uint_as_float(g3.x << 16)        + ev.x, 0.f);
            acc.y += fmaxf(__uint_as_float(g3.x & 0xffff0000u) + ev.y, 0.f);
            acc.z += fmaxf(__uint_as_float(g3.y << 16)        + ev.z, 0.f);
            acc.w += fmaxf(__uint_as_float(g3.y & 0xffff0000u) + ev.w, 0.f);
        }
    }

    uint2 o;
    o.x = (uint32_t)to_b16(acc.x) | ((uint32_t)to_b16(acc.y) << 16);
    o.y = (uint32_t)to_b16(acc.z) | ((uint32_t)to_b16(acc.w) << 16);
    *(uint2*)(t + (size_t)node*HIDDEN + c4) = o;
}

// ---------------- fused weight / activation converter (single launch) ----------------

#define CVT_TOTAL 4408320

__global__ void k_cvt_all(
    const float* __restrict__ conv_w1, const float* __restrict__ conv_w2,
    const float* __restrict__ mu_w, const float* __restrict__ mu_b,
    const float* __restrict__ lv_w, const float* __restrict__ lv_b,
    const float* __restrict__ fw1, const float* __restrict__ fw2,
    const float* __restrict__ dn_w1, const float* __restrict__ dn_w2,
    const float* __restrict__ de_w1, const float* __restrict__ de_w2,
    uint16_t* __restrict__ cw1b, uint16_t* __restrict__ cw2b,
    uint32_t* __restrict__ mvwpk, float* __restrict__ mvb,
    uint16_t* __restrict__ w1hi, uint16_t* __restrict__ w1lo,
    uint16_t* __restrict__ w2hi, uint16_t* __restrict__ w2lo,
    uint16_t* __restrict__ dnw1b, uint16_t* __restrict__ dnw2b,
    uint16_t* __restrict__ dew1b, uint16_t* __restrict__ dew2b)
{
    int i = blockIdx.x*256 + threadIdx.x;
    if (i < 262144){ cw1b[i] = to_b16(conv_w1[i]); return; }
    i -= 262144;
    if (i < 262144){ cw2b[i] = to_b16(conv_w2[i]); return; }
    i -= 262144;
    if (i < 65536){
        int o = i >> 8, k2 = i & 255;
        float v = (o < 128) ? mu_w[o*256 + k2] : lv_w[(o-128)*256 + k2];
        mvwpk[i] = pack_hl(v);
        if (i < 256) mvb[i] = (i < 128) ? mu_b[i] : lv_b[i-128];
        return;
    }
    i -= 65536;
    if (i < 131072){
        int o = (i >> 7) & 255; int kk = i & 127;
        float v = (kk <= (o % 127)) ? fw1[i] : 0.f;
        uint32_t h = bf16_rne_bits(v);
        w1hi[i] = (uint16_t)(h >> 16);
        w1lo[i] = (uint16_t)(bf16_rne_bits(v - __uint_as_float(h)) >> 16);
        return;
    }
    i -= 131072;
    if (i < 262144){
        int o = (i >> 8) & 255; int hh = i & 255;
        float v = ((hh % 127) < (o & 127)) ? fw2[i] : 0.f;
        uint32_t h = bf16_rne_bits(v);
        w2hi[i] = (uint16_t)(h >> 16);
        w2lo[i] = (uint16_t)(bf16_rne_bits(v - __uint_as_float(h)) >> 16);
        return;
    }
    i -= 262144;
    if (i < 32768){ dnw1b[i] = to_b16(dn_w1[i]); return; }
    i -= 32768;
    if (i < 369664){ dnw2b[i] = to_b16(dn_w2[i]); return; }
    i -= 369664;
    if (i < 65536){ dew1b[i] = to_b16(de_w1[i]); return; }
    i -= 65536;
    if (i < 2957312){ dew2b[i] = to_b16(de_w2[i]); }
}

// ---------------- fused conv v3: 4 waves, 64x64 per wave, 32KB LDS (3x reuse) ----------------
// h_out = relu(relu(A@W1^T+b1)@W2^T+b2). Single 32KB region holds A-stage,
// then h1 (after GEMM1-exit barrier), then the output tile. 32KB -> 4 blocks/CU
// = 16 waves/CU (vs 2 blocks/8 waves at 64KB). Weight fragments amortize over
// 16 MFMAs (the mt loop) -- the R2 regression showed 4 MFMAs/fragment starves.

__global__ __launch_bounds__(256) void k_conv2(
    const uint16_t* __restrict__ A,
    const uint16_t* __restrict__ W1, const float* __restrict__ B1,
    const uint16_t* __restrict__ W2, const float* __restrict__ B2,
    uint16_t* __restrict__ C)
{
    extern __shared__ __align__(16) char smem[];          // 32KB, reused 3x
    const int tid  = threadIdx.x;
    const int wave = tid >> 6;
    const int lane = tid & 63;
    const int l15  = lane & 15;
    const int lq   = lane >> 4;
    const int l7   = lane & 7;
    const int row0 = blockIdx.x * 64;

    // stage A: 64 rows x 512B = 32KB, granule-swizzled
    #pragma unroll
    for (int it = 0; it < 8; ++it) {
        int s  = it*256 + tid;
        int m  = s >> 5;
        int gl = (s & 31) ^ (m & 7);
        const char* gp = (const char*)A + ((size_t)(row0+m)*HIDDEN)*2 + gl*16;
        __builtin_amdgcn_global_load_lds(
            (const __attribute__((address_space(1))) uint32_t*)gp,
            (__attribute__((address_space(3))) uint32_t*)(smem + (size_t)s*16),
            16, 0, 0);
    }

    // W1 first fragments issued alongside the stage (one latency exposure)
    bf16x8 bw[2][4];
    #pragma unroll
    for (int nt=0;nt<4;nt++)
        bw[0][nt] = *(const bf16x8*)(W1 + (size_t)(wave*64 + nt*16 + l15)*HIDDEN + lq*8);
    MEMPIN();
    __syncthreads();   // vmcnt drain: stage + bw[0] ready

    // ---- GEMM1: 64x64 tile per wave ----
    f32x4 acc[4][4];
    #pragma unroll
    for (int mt=0;mt<4;mt++)
        #pragma unroll
        for (int nt=0;nt<4;nt++) acc[mt][nt] = (f32x4)(0.f);

    #pragma unroll
    for (int kc = 0; kc < 8; ++kc){
        int cur = kc & 1, nxt = cur ^ 1;
        if (kc < 7){
            #pragma unroll
            for (int nt=0;nt<4;nt++)
                bw[nxt][nt] = *(const bf16x8*)(W1 + (size_t)(wave*64 + nt*16 + l15)*HIDDEN + (kc+1)*32 + lq*8);
        }
        #pragma unroll
        for (int mt=0;mt<4;mt++){
            const int mb = (mt*16 + l15) << 5;
            int g = kc*4 + lq;
            bf16x8 a = *(const bf16x8*)(smem + (size_t)(mb + (g ^ l7))*16);
            #pragma unroll
            for (int nt=0;nt<4;nt++)
                acc[mt][nt] = __builtin_amdgcn_mfma_f32_16x16x32_bf16(a, bw[cur][nt], acc[mt][nt], 0, 0, 0);
        }
    }

    // W2 first fragments: in flight across epilogue1 + lgkm-only barriers
    bf16x8 bw2[2][4];
    #pragma unroll
    for (int nt=0;nt<4;nt++)
        bw2[0][nt] = *(const bf16x8*)(W2 + (size_t)(wave*64 + nt*16 + l15)*HIDDEN + lq*8);
    MEMPIN();

    BARRIER();   // all waves finished GEMM1's A reads -> region reusable

    // epilogue1 -> h1 into the SAME region (granule swizzle)
    uint16_t* h1 = (uint16_t*)smem;
    #pragma unroll
    for (int mt=0;mt<4;mt++){
        #pragma unroll
        for (int nt=0;nt<4;nt++){
            int col = wave*64 + nt*16 + l15;
            float bb = B1[col];
            #pragma unroll
            for (int reg=0;reg<4;reg++){
                int r = mt*16 + lq*4 + reg;
                float v = fmaxf(acc[mt][nt][reg] + bb, 0.f);
                h1[(r*32 + ((col>>3) ^ (r&7)))*8 + (col&7)] = to_b16(v);
            }
        }
    }
    BARRIER();   // h1 complete (lgkm drained); bw2 prefetch still in flight

    // ---- GEMM2 ----
    #pragma unroll
    for (int mt=0;mt<4;mt++)
        #pragma unroll
        for (int nt=0;nt<4;nt++) acc[mt][nt] = (f32x4)(0.f);

    #pragma unroll
    for (int kc = 0; kc < 8; ++kc){
        int cur = kc & 1, nxt = cur ^ 1;
        if (kc < 7){
            #pragma unroll
            for (int nt=0;nt<4;nt++)
                bw2[nxt][nt] = *(const bf16x8*)(W2 + (size_t)(wave*64 + nt*16 + l15)*HIDDEN + (kc+1)*32 + lq*8);
        }
        #pragma unroll
        for (int mt=0;mt<4;mt++){
            int m = mt*16 + l15;
            bf16x8 a = *(const bf16x8*)(h1 + (size_t)(m*32 + ((kc*4 + lq) ^ (m & 7)))*8);
            #pragma unroll
            for (int nt=0;nt<4;nt++)
                acc[mt][nt] = __builtin_amdgcn_mfma_f32_16x16x32_bf16(a, bw2[cur][nt], acc[mt][nt], 0, 0, 0);
        }
    }
    BARRIER();   // all waves finished h1 reads -> region reusable

    // epilogue2 -> same region, stage-style swizzle for coalesced copy-out
    uint16_t* rs = (uint16_t*)smem;
    #pragma unroll
    for (int mt=0;mt<4;mt++){
        #pragma unroll
        for (int nt=0;nt<4;nt++){
            int col = wave*64 + nt*16 + l15;
            float bb = B2[col];
            #pragma unroll
            for (int reg=0;reg<4;reg++){
                int r = mt*16 + lq*4 + reg;
                float v = fmaxf(acc[mt][nt][reg] + bb, 0.f);
                rs[(r*32 + ((col>>3) ^ (r&7)))*8 + (col&7)] = to_b16(v);
            }
        }
    }
    BARRIER();

    // coalesced copy-out: 8 iters x 256 threads x 16B
    #pragma unroll
    for (int it = 0; it < 8; ++it){
        int s   = it*256 + tid;
        int row = s >> 5;
        int gc  = s & 31;
        uint4 d = *(const uint4*)(smem + (size_t)(row*32 + (gc ^ (row & 7)))*16);
        *(uint4*)(C + (size_t)(row0+row)*HIDDEN + gc*8) = d;
    }
}

// ---------------- MFMA GEMM (mu/lv + decoders) ----------------

template<int SPLIT, int OUTM>
__global__ __launch_bounds__(256) void mfma_gemm(
    const void* __restrict__ Ap, const void* __restrict__ Wp,
    const float* __restrict__ bias, void* __restrict__ Cp,
    int M, int N, int K, int relu)
{
    extern __shared__ __align__(16) char smem[];
    const int tid  = threadIdx.x;
    const int wave = tid >> 6;
    const int lane = tid & 63;
    const int l15  = lane & 15;
    const int lq   = lane >> 4;
    const int l7   = lane & 7;
    const int row0 = blockIdx.y * 64;
    const int n0   = blockIdx.x * 256;
    const int ELB  = SPLIT ? 4 : 2;
    const int KC   = (K < 256) ? K : 256;
    const int GR   = (KC * ELB) >> 4;
    const int rsh  = (GR == 64) ? 6 : ((GR == 32) ? 5 : 4);

    f32x4 acc[4][4];
    #pragma unroll
    for (int mt=0;mt<4;mt++)
        #pragma unroll
        for (int nt=0;nt<4;nt++) acc[mt][nt] = (f32x4)(0.f);

    const char* Ab = (const char*)Ap;
    const char* Wb = (const char*)Wp;

    for (int kbase = 0; kbase < K; kbase += KC) {
        const int rounds = GR >> 2;
        for (int it = 0; it < rounds; ++it) {
            int sbase = it*256 + wave*64;
            int s  = sbase + lane;
            int m  = s >> rsh;
            int gl = (s & (GR-1)) ^ (m & 7);
            const char* gp = Ab + ((size_t)(row0+m)*K + kbase)*ELB + gl*16;
            __builtin_amdgcn_global_load_lds(
                (const __attribute__((address_space(1))) uint32_t*)gp,
                (__attribute__((address_space(3))) uint32_t*)(smem + sbase*16),
                16, 0, 0);
        }
        __syncthreads();

        for (int kc = 0; kc < (KC >> 5); ++kc) {
            bf16x8 bhi[4], blo[4];
            #pragma unroll
            for (int nt=0;nt<4;nt++){
                int n = n0 + wave*64 + nt*16 + l15;
                if (n >= N) n = N-1;
                if (SPLIT){
                    const uint4* wp4 = (const uint4*)(Wb + ((size_t)n*K + kbase + kc*32 + lq*8)*4);
                    uint4 xx = wp4[0], yy = wp4[1];
                    unpack_frag(xx, yy, bhi[nt], blo[nt]);
                } else {
                    bhi[nt] = *(const bf16x8*)(Wb + ((size_t)n*K + kbase + kc*32 + lq*8)*2);
                }
            }
            #pragma unroll
            for (int mt=0;mt<4;mt++){
                const int mb = (mt*16 + l15) << rsh;
                if (SPLIT){
                    int g0 = kc*8 + lq*2;
                    uint4 xx = *(const uint4*)(smem + (size_t)(mb + ((g0  ) ^ l7))*16);
                    uint4 yy = *(const uint4*)(smem + (size_t)(mb + ((g0+1) ^ l7))*16);
                    bf16x8 ahi, alo;
                    unpack_frag(xx, yy, ahi, alo);
                    #pragma unroll
                    for (int nt=0;nt<4;nt++){
                        acc[mt][nt] = __builtin_amdgcn_mfma_f32_16x16x32_bf16(ahi, bhi[nt], acc[mt][nt], 0, 0, 0);
                        acc[mt][nt] = __builtin_amdgcn_mfma_f32_16x16x32_bf16(ahi, blo[nt], acc[mt][nt], 0, 0, 0);
                        acc[mt][nt] = __builtin_amdgcn_mfma_f32_16x16x32_bf16(alo, bhi[nt], acc[mt][nt], 0, 0, 0);
                    }
                } else {
                    int g = kc*4 + lq;
                    bf16x8 a = *(const bf16x8*)(smem + (size_t)(mb + (g ^ l7))*16);
                    #pragma unroll
                    for (int nt=0;nt<4;nt++){
                        acc[mt][nt] = __builtin_amdgcn_mfma_f32_16x16x32_bf16(a, bhi[nt], acc[mt][nt], 0, 0, 0);
                    }
                }
            }
        }
        __syncthreads();
    }

    const int ES = (OUTM == 1) ? 2 : 4;
    char* rs = smem + wave*(64*64*ES);
    const int colbase = n0 + wave*64;
    #pragma unroll
    for (int mt=0;mt<4;mt++){
        #pragma unroll
        for (int nt=0;nt<4;nt++){
            int cl = nt*16 + l15;
            int col = colbase + cl;
            float bb = bias[col < N ? col : N-1];
            #pragma unroll
            for (int reg=0;reg<4;reg++){
                int r = mt*16 + lq*4 + reg;
                float v = acc[mt][nt][reg] + bb;
                if (relu) v = fmaxf(v, 0.f);
                if (OUTM == 1) ((uint16_t*)rs)[r*64 + cl] = to_b16(v);
                else           ((float*)rs)[r*64 + cl] = v;
            }
        }
    }
    __syncthreads();
    for (int it = 0; it < 32; ++it) {
        int r   = it*2 + (lane>>5);
        int clp = lane & 31;
        int col = colbase + clp*2;
        if (col < N){
            if (OUTM == 1){
                uint32_t d = *(const uint32_t*)((const uint16_t*)rs + r*64 + clp*2);
                *(uint32_t*)((char*)Cp + ((size_t)(row0+r)*N + col)*2) = d;
            } else {
                float2 d = *(const float2*)((const float*)rs + r*64 + clp*2);
                *(float2*)((float*)Cp + (size_t)(row0+r)*N + col) = d;
            }
        }
    }
}

// ---------------- pooling + z0 elementwise ----------------

__global__ void k_pool(const uint16_t* __restrict__ h, const int* __restrict__ gstart,
                       const int* __restrict__ gcnt, uint32_t* __restrict__ hg){
    int b = blockIdx.x; int c = threadIdx.x;
    int s0 = gstart[b]; int n = gcnt[b];
    float s = 0.f;
    for (int j=0;j<n;j++) s += from_b16(h[(size_t)(s0+j)*HIDDEN + c]);
    hg[(size_t)b*HIDDEN + c] = pack_hl(s);
}

__global__ void k_z0(const float* __restrict__ mv, const float* __restrict__ eps,
                     float* __restrict__ mu_o, float* __restrict__ lv_o, float* __restrict__ z0_o){
    int i = blockIdx.x*256 + threadIdx.x;
    if (i >= NB*LAT) return;
    int b = i >> 7, l = i & 127;
    float m = mv[(size_t)b*256 + l];
    float v = mv[(size_t)b*256 + l + 128];
    mu_o[i] = m;
    lv_o[i] = v;
    z0_o[i] = m + eps[i]*expf(0.5f*v);
}

// ---------------- fused MFMA flows v5: software-pipelined weight stream ----------------

__global__ __launch_bounds__(1024) void k_flows_mfma5(
    const float* __restrict__ z0,
    const uint16_t* __restrict__ w1hi, const uint16_t* __restrict__ w1lo, const float* __restrict__ fb1,
    const uint16_t* __restrict__ w2hi, const uint16_t* __restrict__ w2lo, const float* __restrict__ fb2,
    float* __restrict__ zK, uint16_t* __restrict__ zkb, float* __restrict__ sld)
{
    __shared__ __align__(16) uint16_t zhi[16][136];
    __shared__ __align__(16) uint16_t zlo[16][136];
    __shared__ __align__(16) uint16_t h1hi[16][280];
    __shared__ __align__(16) uint16_t h1lo[16][280];
    __shared__ __align__(16) float    oS[16][268];
    const int tid  = threadIdx.x;
    const int wave = tid >> 6;
    const int lane = tid & 63;
    const int l15  = lane & 15;
    const int lq   = lane >> 4;
    const int g0   = blockIdx.x * 16;
    const int col  = wave*16 + l15;

    const size_t wc1 = (size_t)col*LAT  + lq*8;
    const size_t wc2 = (size_t)col*FHID + lq*8;

    bf16x8 a1h[4], a1l[4];
    bf16x8 a2h[8], a2l[8];

    auto LD_W1 = [&](int kf){
        const uint16_t* W1h = w1hi + (size_t)kf*FHID*LAT;
        const uint16_t* W1l = w1lo + (size_t)kf*FHID*LAT;
        #pragma unroll
        for (int kc=0;kc<4;kc++){
            a1h[kc] = *(const bf16x8*)(W1h + wc1 + kc*32);
            a1l[kc] = *(const bf16x8*)(W1l + wc1 + kc*32);
        }
    };
    auto LD_W2A = [&](int kf){
        const uint16_t* W2h = w2hi + (size_t)kf*2*LAT*FHID;
        const uint16_t* W2l = w2lo + (size_t)kf*2*LAT*FHID;
        #pragma unroll
        for (int kc=0;kc<4;kc++){
            a2h[kc] = *(const bf16x8*)(W2h + wc2 + kc*32);
            a2l[kc] = *(const bf16x8*)(W2l + wc2 + kc*32);
        }
    };
    auto LD_W2B = [&](int kf){
        const uint16_t* W2h = w2hi + (size_t)kf*2*LAT*FHID;
        const uint16_t* W2l = w2lo + (size_t)kf*2*LAT*FHID;
        #pragma unroll
        for (int kc=4;kc<8;kc++){
            a2h[kc] = *(const bf16x8*)(W2h + wc2 + kc*32);
            a2l[kc] = *(const bf16x8*)(W2l + wc2 + kc*32);
        }
    };

    LD_W1(0);
    LD_W2A(0);
    MEMPIN();

    #pragma unroll
    for (int q=0;q<2;q++){
        int idx = q*1024 + tid;
        int r = idx >> 7, l = idx & 127;
        float v = z0[(size_t)(g0 + r)*LAT + l];
        uint32_t h = bf16_rne_bits(v);
        zhi[r][l] = (uint16_t)(h >> 16);
        zlo[r][l] = (uint16_t)(bf16_rne_bits(v - __uint_as_float(h)) >> 16);
    }
    float ldacc = 0.f;
    BARRIER();

    #pragma unroll
    for (int kf=0; kf<NFLOWS; kf++){
        const float* b1 = fb1 + kf*FHID;
        const float* b2 = fb2 + kf*2*LAT;

        {
            f32x4 acc = (f32x4)(0.f);
            #pragma unroll
            for (int kc=0;kc<4;kc++){
                bf16x8 ah = *(const bf16x8*)&zhi[l15][kc*32 + lq*8];
                bf16x8 al = *(const bf16x8*)&zlo[l15][kc*32 + lq*8];
                acc = __builtin_amdgcn_mfma_f32_16x16x32_bf16(ah, a1h[kc], acc, 0, 0, 0);
                acc = __builtin_amdgcn_mfma_f32_16x16x32_bf16(ah, a1l[kc], acc, 0, 0, 0);
                acc = __builtin_amdgcn_mfma_f32_16x16x32_bf16(al, a1h[kc], acc, 0, 0, 0);
            }
            MEMPIN();
            LD_W2B(kf);
            MEMPIN();
            float bb = b1[col];
            #pragma unroll
            for (int reg=0;reg<4;reg++){
                int r = lq*4 + reg;
                float v = fmaxf(acc[reg] + bb, 0.f);
                uint32_t h = bf16_rne_bits(v);
                h1hi[r][col] = (uint16_t)(h >> 16);
                h1lo[r][col] = (uint16_t)(bf16_rne_bits(v - __uint_as_float(h)) >> 16);
            }
        }
        BARRIER();

        {
            f32x4 acc = (f32x4)(0.f);
            #pragma unroll
            for (int kc=0;kc<4;kc++){
                bf16x8 ah = *(const bf16x8*)&h1hi[l15][kc*32 + lq*8];
                bf16x8 al = *(const bf16x8*)&h1lo[l15][kc*32 + lq*8];
                acc = __builtin_amdgcn_mfma_f32_16x16x32_bf16(ah, a2h[kc], acc, 0, 0, 0);
                acc = __builtin_amdgcn_mfma_f32_16x16x32_bf16(ah, a2l[kc], acc, 0, 0, 0);
                acc = __builtin_amdgcn_mfma_f32_16x16x32_bf16(al, a2h[kc], acc, 0, 0, 0);
            }
            MEMPIN();
            if (kf < NFLOWS-1) LD_W1(kf+1);
            MEMPIN();
            #pragma unroll
            for (int kc=4;kc<8;kc++){
                bf16x8 ah = *(const bf16x8*)&h1hi[l15][kc*32 + lq*8];
                bf16x8 al = *(const bf16x8*)&h1lo[l15][kc*32 + lq*8];
                acc = __builtin_amdgcn_mfma_f32_16x16x32_bf16(ah, a2h[kc], acc, 0, 0, 0);
                acc = __builtin_amdgcn_mfma_f32_16x16x32_bf16(ah, a2l[kc], acc, 0, 0, 0);
                acc = __builtin_amdgcn_mfma_f32_16x16x32_bf16(al, a2h[kc], acc, 0, 0, 0);
            }
            MEMPIN();
            if (kf < NFLOWS-1) LD_W2A(kf+1);
            MEMPIN();
            float bb = b2[col];
            #pragma unroll
            for (int reg=0;reg<4;reg++)
                oS[lq*4 + reg][col] = acc[reg] + bb;
        }
        BARRIER();

        {
            const int r = wave;
            float ldp = 0.f;
            #pragma unroll
            for (int j=0;j<2;j++){
                int l = lane + j*64;
                float m = oS[r][l];
                float s = oS[r][l + 128];
                float g = 1.f/(1.f + expf(-s));
                float zv = __uint_as_float((uint32_t)zhi[r][l] << 16)
                         + __uint_as_float((uint32_t)zlo[r][l] << 16);
                float zn = g*zv + (1.f - g)*m;
                uint32_t h = bf16_rne_bits(zn);
                zhi[r][l] = (uint16_t)(h >> 16);
                zlo[r][l] = (uint16_t)(bf16_rne_bits(zn - __uint_as_float(h)) >> 16);
                ldp += logf(g + 1e-8f);
            }
            #pragma unroll
            for (int off=1; off<64; off<<=1) ldp += __shfl_xor(ldp, off);
            ldacc += ldp;
        }
        BARRIER();
    }

    #pragma unroll
    for (int q=0;q<2;q++){
        int idx = q*1024 + tid;
        int r = idx >> 7, l = idx & 127;
        uint32_t h = (uint32_t)zhi[r][l] << 16;
        float zv = __uint_as_float(h) + __uint_as_float((uint32_t)zlo[r][l] << 16);
        zK[(size_t)(g0+r)*LAT + l] = zv;
        zkb[(size_t)(g0+r)*LAT + l] = (uint16_t)(h >> 16);
    }
    if (lane == 0) sld[g0 + wave] = ldacc;
}

// ---------------- edge-logits symmetrize ----------------

__global__ void k_sym(const float* __restrict__ raw, float* __restrict__ outp){
    int idx = blockIdx.x*256 + threadIdx.x;
    const int total = NB*MA*MA;
    if (idx >= total) return;
    int b = idx / (MA*MA);
    int rem = idx - b*(MA*MA);
    int i = rem / MA;
    int j = rem - i*MA;
    const size_t base = (size_t)b*(MA*MA*NEF_);
    const float4 a  = *(const float4*)(raw + base + (size_t)(i*MA + j)*NEF_);
    const float4 bt = *(const float4*)(raw + base + (size_t)(j*MA + i)*NEF_);
    float4 r;
    r.x = (a.x + bt.x)*0.5f;
    r.y = (a.y + bt.y)*0.5f;
    r.z = (a.z + bt.z)*0.5f;
    r.w = (a.w + bt.w)*0.5f;
    *(float4*)(outp + base + (size_t)(i*MA + j)*NEF_) = r;
}

// ---------------- launch ----------------

extern "C" void kernel_launch(void* const* d_in, const int* in_sizes, int n_in,
                              void* d_out, int out_size, void* d_ws, size_t ws_size,
                              hipStream_t stream){
    (void)in_sizes; (void)n_in; (void)out_size; (void)ws_size;
    const int*   x        = (const int*)d_in[0];
    const int*   eidx     = (const int*)d_in[1];
    const int*   eattr    = (const int*)d_in[2];
    const int*   batch    = (const int*)d_in[3];
    const float* eps      = (const float*)d_in[4];
    const float* node_emb = (const float*)d_in[5];
    const float* edge_emb = (const float*)d_in[6];
    const float* conv_w1  = (const float*)d_in[7];
    const float* conv_b1  = (const float*)d_in[8];
    const float* conv_w2  = (const float*)d_in[9];
    const float* conv_b2  = (const float*)d_in[10];
    const float* mu_w     = (const float*)d_in[11];
    const float* mu_b     = (const float*)d_in[12];
    const float* lv_w     = (const float*)d_in[13];
    const float* lv_b     = (const float*)d_in[14];
    const float* fw1      = (const float*)d_in[15];
    const float* fb1      = (const float*)d_in[16];
    const float* fw2      = (const float*)d_in[17];
    const float* fb2      = (const float*)d_in[18];
    const float* dn_w1    = (const float*)d_in[19];
    const float* dn_b1    = (const float*)d_in[20];
    const float* dn_w2    = (const float*)d_in[21];
    const float* dn_b2    = (const float*)d_in[22];
    const float* de_w1    = (const float*)d_in[23];
    const float* de_b1    = (const float*)d_in[24];
    const float* de_w2    = (const float*)d_in[25];
    const float* de_b2    = (const float*)d_in[26];

    float* out = (float*)d_out;
    const size_t off_node = 0;
    const size_t off_edge = (size_t)NB*MA*NNF_;
    const size_t off_mu   = off_edge + (size_t)NB*MA*MA*NEF_;
    const size_t off_lv   = off_mu + (size_t)NB*LAT;
    const size_t off_z0   = off_lv + (size_t)NB*LAT;
    const size_t off_zk   = off_z0 + (size_t)NB*LAT;
    const size_t off_sld  = off_zk + (size_t)NB*LAT;
    (void)off_node;

    char* p = (char*)d_ws;
    auto alloc = [&](size_t bytes)->char*{ char* r = p; p += (bytes + 255) & ~(size_t)255; return r; };
    uint16_t* h_b   = (uint16_t*)alloc((size_t)N_NODES*HIDDEN*2);
    uint16_t* t_b   = (uint16_t*)alloc((size_t)N_NODES*HIDDEN*2);
    int*   offs   = (int*)  alloc((size_t)(N_NODES+1)*4);
    int*   cursor = (int*)  alloc((size_t)N_NODES*4);
    int*   epack  = (int*)  alloc((size_t)N_EDGES*4);
    int*   gstart = (int*)  alloc((size_t)NB*4);
    int*   gcnt   = (int*)  alloc((size_t)NB*4);
    uint32_t* hg_pk = (uint32_t*)alloc((size_t)NB*HIDDEN*4);
    float* mv       = (float*)alloc((size_t)NB*256*4);
    uint16_t* cw1b  = (uint16_t*)alloc((size_t)4*HIDDEN*HIDDEN*2);
    uint16_t* cw2b  = (uint16_t*)alloc((size_t)4*HIDDEN*HIDDEN*2);
    uint32_t* mvwpk = (uint32_t*)alloc((size_t)256*256*4);
    float*    mvb   = (float*)  alloc((size_t)256*4);
    uint16_t* w1hi  = (uint16_t*)alloc((size_t)NFLOWS*FHID*LAT*2);
    uint16_t* w1lo  = (uint16_t*)alloc((size_t)NFLOWS*FHID*LAT*2);
    uint16_t* w2hi  = (uint16_t*)alloc((size_t)NFLOWS*2*LAT*FHID*2);
    uint16_t* w2lo  = (uint16_t*)alloc((size_t)NFLOWS*2*LAT*FHID*2);
    uint16_t* dnw1b = (uint16_t*)alloc((size_t)256*LAT*2);
    uint16_t* dnw2b = (uint16_t*)alloc((size_t)MA*NNF_*256*2);
    uint16_t* dew1b = (uint16_t*)alloc((size_t)512*LAT*2);
    uint16_t* dew2b = (uint16_t*)alloc((size_t)MA*MA*NEF_*512*2);
    uint16_t* zkb   = (uint16_t*)alloc((size_t)NB*LAT*2);
    uint16_t* hnb   = (uint16_t*)alloc((size_t)NB*256*2);
    uint16_t* heb   = (uint16_t*)alloc((size_t)NB*512*2);
    float* edge_raw = (float*)alloc((size_t)NB*MA*MA*NEF_*4);

    const int* esrc = eidx;
    const int* edst = eidx + N_EDGES;

    k_cvt_all<<<(CVT_TOTAL+255)/256, 256, 0, stream>>>(
        conv_w1, conv_w2, mu_w, mu_b, lv_w, lv_b, fw1, fw2,
        dn_w1, dn_w2, de_w1, de_w2,
        cw1b, cw2b, mvwpk, mvb, w1hi, w1lo, w2hi, w2lo,
        dnw1b, dnw2b, dew1b, dew2b);

    k_init   <<<(N_NODES+255)/256, 256, 0, stream>>>(cursor, gstart, gcnt);
    k_embed  <<<N_NODES, HIDDEN, 0, stream>>>(x, node_emb, h_b);
    k_deg    <<<(N_EDGES+255)/256, 256, 0, stream>>>(edst, cursor);
    k_meta   <<<(N_NODES+255)/256, 256, 0, stream>>>(batch, gstart, gcnt);
    k_scan   <<<1, 1024, 0, stream>>>(cursor, offs);
    k_scatter<<<(N_EDGES+255)/256, 256, 0, stream>>>(esrc, edst, eattr, offs, cursor, epack);

    const size_t SM32 = 32768, SM64 = 65536;
    for (int k=0;k<4;k++){
        k_aggr<<<N_NODES/4, 256, 0, stream>>>(h_b, edge_emb, offs, epack, t_b);
        k_conv2<<<N_NODES/64, 256, SM32, stream>>>(
            t_b,
            cw1b + (size_t)k*HIDDEN*HIDDEN, conv_b1 + (size_t)k*HIDDEN,
            cw2b + (size_t)k*HIDDEN*HIDDEN, conv_b2 + (size_t)k*HIDDEN,
            h_b);
    }

    k_pool<<<NB, HIDDEN, 0, stream>>>(h_b, gstart, gcnt, hg_pk);
    mfma_gemm<1,2><<<dim3(1, NB/64), 256, SM64, stream>>>(hg_pk, mvwpk, mvb, mv, NB, 256, HIDDEN, 0);
    k_z0<<<(NB*LAT+255)/256, 256, 0, stream>>>(mv, eps, out+off_mu, out+off_lv, out+off_z0);

    k_flows_mfma5<<<NB/16, 1024, 0, stream>>>(out+off_z0, w1hi, w1lo, fb1, w2hi, w2lo, fb2,
                                              out+off_zk, zkb, out+off_sld);

    mfma_gemm<0,1><<<dim3(1, NB/64), 256, SM32, stream>>>(zkb, dnw1b, dn_b1, hnb, NB, 256, LAT, 1);
    mfma_gemm<0,2><<<dim3(6, NB/64), 256, SM64, stream>>>(hnb, dnw2b, dn_b2, out+off_node, NB, MA*NNF_, 256, 0);
    mfma_gemm<0,1><<<dim3(2, NB/64), 256, SM32, stream>>>(zkb, dew1b, de_b1, heb, NB, 512, LAT, 1);
    mfma_gemm<0,2><<<dim3(23, NB/64), 256, SM64, stream>>>(heb, dew2b, de_b2, edge_raw, NB, MA*MA*NEF_, 512, 0);
    k_sym<<<(NB*MA*MA + 255)/256, 256, 0, stream>>>(edge_raw, out + off_edge);
}

// Round 4
// 640.986 us; speedup vs baseline: 1.3422x; 1.0103x over previous
//
#include <hip/hip_runtime.h>
#include <hip/hip_bf16.h>
#include <math.h>
#include <stdint.h>

#define N_NODES 49152
#define N_EDGES 196608
#define NB      2048
#define HIDDEN  256
#define LAT     128
#define FHID    256
#define NFLOWS  4
#define MA      38
#define NNF_    38
#define NEF_    4

typedef __attribute__((ext_vector_type(8))) short bf16x8;
typedef __attribute__((ext_vector_type(4))) float f32x4;

#define MEMPIN() asm volatile("" ::: "memory")
#define BARRIER() asm volatile("s_waitcnt lgkmcnt(0)\n\ts_barrier" ::: "memory")
#define SBAR0() __builtin_amdgcn_sched_barrier(0)
#define MFMA16 __builtin_amdgcn_mfma_f32_16x16x32_bf16

// volatile asm load: cannot be sunk/reordered by the compiler (defeats the
// restrict+invariant sinking that flattened k_flows_mfma5 to VGPR=64).
__device__ inline void gload16(uint4 &d, const void* a){
    asm volatile("global_load_dwordx4 %0, %1, off" : "=v"(d) : "v"(a));
}

// ---------- bf16 helpers ----------
__device__ inline uint32_t bf16_rne_bits(float v){
    uint32_t u = __float_as_uint(v);
    u += 0x7fffu + ((u >> 16) & 1u);
    return u & 0xffff0000u;
}
__device__ inline uint16_t to_b16(float v){ return (uint16_t)(bf16_rne_bits(v) >> 16); }
__device__ inline float from_b16(uint16_t u){ return __uint_as_float((uint32_t)u << 16); }
__device__ inline uint32_t pack_hl(float v){
    uint32_t hu = bf16_rne_bits(v);
    float r = v - __uint_as_float(hu);
    uint32_t lu = bf16_rne_bits(r);
    return hu | (lu >> 16);
}

__device__ inline void unpack_frag(const uint4& x, const uint4& y, bf16x8& hi, bf16x8& lo){
    union { bf16x8 v; uint32_t u[4]; } H, L;
    H.u[0] = __builtin_amdgcn_perm(x.y, x.x, 0x07060302u);
    H.u[1] = __builtin_amdgcn_perm(x.w, x.z, 0x07060302u);
    H.u[2] = __builtin_amdgcn_perm(y.y, y.x, 0x07060302u);
    H.u[3] = __builtin_amdgcn_perm(y.w, y.z, 0x07060302u);
    L.u[0] = __builtin_amdgcn_perm(x.y, x.x, 0x05040100u);
    L.u[1] = __builtin_amdgcn_perm(x.w, x.z, 0x05040100u);
    L.u[2] = __builtin_amdgcn_perm(y.y, y.x, 0x05040100u);
    L.u[3] = __builtin_amdgcn_perm(y.w, y.z, 0x05040100u);
    hi = H.v; lo = L.v;
}

__device__ inline bf16x8 as_bf16x8(const uint4& u){
    union { uint4 u; bf16x8 b; } cv; cv.u = u; return cv.b;
}

// ---------------- init / CSR build ----------------

__global__ void k_init(int* __restrict__ cursor, int* __restrict__ gstart, int* __restrict__ gcnt){
    int i = blockIdx.x*256 + threadIdx.x;
    if (i < N_NODES) cursor[i] = 0;
    if (i < NB){ gstart[i] = 0x7fffffff; gcnt[i] = 0; }
}

__global__ void k_embed(const int* __restrict__ x, const float* __restrict__ emb, uint16_t* __restrict__ h){
    int i = blockIdx.x; int c = threadIdx.x;
    h[(size_t)i*HIDDEN + c] = to_b16(emb[x[i]*HIDDEN + c]);
}

__global__ void k_deg(const int* __restrict__ dst, int* __restrict__ cursor){
    int e = blockIdx.x*256 + threadIdx.x;
    if (e < N_EDGES) atomicAdd(&cursor[dst[e]], 1);
}

__global__ void k_meta(const int* __restrict__ batch, int* __restrict__ gstart, int* __restrict__ gcnt){
    int i = blockIdx.x*256 + threadIdx.x;
    if (i < N_NODES){ int b = batch[i]; atomicMin(&gstart[b], i); atomicAdd(&gcnt[b], 1); }
}

__global__ __launch_bounds__(1024) void k_scan(int* __restrict__ cursor, int* __restrict__ offs){
    __shared__ int part[1024];
    const int tid = threadIdx.x;
    const int CH = N_NODES/1024; // 48
    int local[48];
    int s = 0;
    int base = tid*CH;
    for (int j=0;j<CH;j++){ local[j] = cursor[base+j]; s += local[j]; }
    part[tid] = s;
    __syncthreads();
    for (int off=1; off<1024; off<<=1){
        int v = (tid>=off) ? part[tid-off] : 0;
        __syncthreads();
        part[tid] += v;
        __syncthreads();
    }
    int excl = (tid==0) ? 0 : part[tid-1];
    for (int j=0;j<CH;j++){ offs[base+j] = excl; excl += local[j]; cursor[base+j] = 0; }
    if (tid == 1023) offs[N_NODES] = excl;
}

__global__ void k_scatter(const int* __restrict__ src, const int* __restrict__ dst, const int* __restrict__ attr,
                          const int* __restrict__ offs, int* __restrict__ cursor, int* __restrict__ epack){
    int e = blockIdx.x*256 + threadIdx.x;
    if (e < N_EDGES){
        int d = dst[e];
        int pos = atomicAdd(&cursor[d], 1);
        epack[offs[d] + pos] = (src[e] & 0xffff) | (attr[e] << 16);
    }
}

// ---------------- message aggregation: wave-per-node, 4-edge MLP chunks ----------------

__global__ __launch_bounds__(256) void k_aggr(const uint16_t* __restrict__ h, const float* __restrict__ eemb,
                                              const int* __restrict__ offs, const int* __restrict__ epack,
                                              uint16_t* __restrict__ t){
    __shared__ float sE[NEF_*HIDDEN];
    const int tid  = threadIdx.x;
    #pragma unroll
    for (int q=0;q<NEF_;q++) sE[q*256 + tid] = eemb[q*256 + tid];
    __syncthreads();

    const int wave = tid >> 6;
    const int lane = tid & 63;
    const int node = blockIdx.x*4 + wave;
    const int c4   = lane*4;

    uint2 hu = *(const uint2*)(h + (size_t)node*HIDDEN + c4);
    float4 acc;
    acc.x = __uint_as_float(hu.x << 16);
    acc.y = __uint_as_float(hu.x & 0xffff0000u);
    acc.z = __uint_as_float(hu.y << 16);
    acc.w = __uint_as_float(hu.y & 0xffff0000u);

    const int e0 = offs[node], e1 = offs[node+1];
    for (int j = e0; j < e1; j += 4){
        int p0 = epack[j];
        int p1 = (j+1 < e1) ? epack[j+1] : p0;
        int p2 = (j+2 < e1) ? epack[j+2] : p0;
        int p3 = (j+3 < e1) ? epack[j+3] : p0;
        uint2 g0 = *(const uint2*)(h + (size_t)(p0 & 0xffff)*HIDDEN + c4);
        uint2 g1 = *(const uint2*)(h + (size_t)(p1 & 0xffff)*HIDDEN + c4);
        uint2 g2 = *(const uint2*)(h + (size_t)(p2 & 0xffff)*HIDDEN + c4);
        uint2 g3 = *(const uint2*)(h + (size_t)(p3 & 0xffff)*HIDDEN + c4);
        {
            const float4 ev = *(const float4*)&sE[(p0 >> 16)*HIDDEN + c4];
            acc.x += fmaxf(__uint_as_float(g0.x << 16)        + ev.x, 0.f);
            acc.y += fmaxf(__uint_as_float(g0.x & 0xffff0000u) + ev.y, 0.f);
            acc.z += fmaxf(__uint_as_float(g0.y << 16)        + ev.z, 0.f);
            acc.w += fmaxf(__uint_as_float(g0.y & 0xffff0000u) + ev.w, 0.f);
        }
        if (j+1 < e1){
            const float4 ev = *(const float4*)&sE[(p1 >> 16)*HIDDEN + c4];
            acc.x += fmaxf(__uint_as_float(g1.x << 16)        + ev.x, 0.f);
            acc.y += fmaxf(__uint_as_float(g1.x & 0xffff0000u) + ev.y, 0.f);
            acc.z += fmaxf(__uint_as_float(g1.y << 16)        + ev.z, 0.f);
            acc.w += fmaxf(__uint_as_float(g1.y & 0xffff0000u) + ev.w, 0.f);
        }
        if (j+2 < e1){
            const float4 ev = *(const float4*)&sE[(p2 >> 16)*HIDDEN + c4];
            acc.x += fmaxf(__uint_as_float(g2.x << 16)        + ev.x, 0.f);
            acc.y += fmaxf(__uint_as_float(g2.x & 0xffff0000u) + ev.y, 0.f);
            acc.z += fmaxf(__uint_as_float(g2.y << 16)        + ev.z, 0.f);
            acc.w += fmaxf(__uint_as_float(g2.y & 0xffff0000u) + ev.w, 0.f);
        }
        if (j+3 < e1){
            const float4 ev = *(const float4*)&sE[(p3 >> 16)*HIDDEN + c4];
            acc.x += fmaxf(__uint_as_float(g3.x << 16)        + ev.x, 0.f);
            acc.y += fmaxf(__uint_as_float(g3.x & 0xffff0000u) + ev.y, 0.f);
            acc.z += fmaxf(__uint_as_float(g3.y << 16)        + ev.z, 0.f);
            acc.w += fmaxf(__uint_as_float(g3.y & 0xffff0000u) + ev.w, 0.f);
        }
    }

    uint2 o;
    o.x = (uint32_t)to_b16(acc.x) | ((uint32_t)to_b16(acc.y) << 16);
    o.y = (uint32_t)to_b16(acc.z) | ((uint32_t)to_b16(acc.w) << 16);
    *(uint2*)(t + (size_t)node*HIDDEN + c4) = o;
}

// ---------------- fused weight / activation converter (single launch) ----------------

#define CVT_TOTAL 4408320

__global__ void k_cvt_all(
    const float* __restrict__ conv_w1, const float* __restrict__ conv_w2,
    const float* __restrict__ mu_w, const float* __restrict__ mu_b,
    const float* __restrict__ lv_w, const float* __restrict__ lv_b,
    const float* __restrict__ fw1, const float* __restrict__ fw2,
    const float* __restrict__ dn_w1, const float* __restrict__ dn_w2,
    const float* __restrict__ de_w1, const float* __restrict__ de_w2,
    uint16_t* __restrict__ cw1b, uint16_t* __restrict__ cw2b,
    uint32_t* __restrict__ mvwpk, float* __restrict__ mvb,
    uint16_t* __restrict__ w1hi, uint16_t* __restrict__ w1lo,
    uint16_t* __restrict__ w2hi, uint16_t* __restrict__ w2lo,
    uint16_t* __restrict__ dnw1b, uint16_t* __restrict__ dnw2b,
    uint16_t* __restrict__ dew1b, uint16_t* __restrict__ dew2b)
{
    int i = blockIdx.x*256 + threadIdx.x;
    if (i < 262144){ cw1b[i] = to_b16(conv_w1[i]); return; }
    i -= 262144;
    if (i < 262144){ cw2b[i] = to_b16(conv_w2[i]); return; }
    i -= 262144;
    if (i < 65536){
        int o = i >> 8, k2 = i & 255;
        float v = (o < 128) ? mu_w[o*256 + k2] : lv_w[(o-128)*256 + k2];
        mvwpk[i] = pack_hl(v);
        if (i < 256) mvb[i] = (i < 128) ? mu_b[i] : lv_b[i-128];
        return;
    }
    i -= 65536;
    if (i < 131072){
        int o = (i >> 7) & 255; int kk = i & 127;
        float v = (kk <= (o % 127)) ? fw1[i] : 0.f;
        uint32_t h = bf16_rne_bits(v);
        w1hi[i] = (uint16_t)(h >> 16);
        w1lo[i] = (uint16_t)(bf16_rne_bits(v - __uint_as_float(h)) >> 16);
        return;
    }
    i -= 131072;
    if (i < 262144){
        int o = (i >> 8) & 255; int hh = i & 255;
        float v = ((hh % 127) < (o & 127)) ? fw2[i] : 0.f;
        uint32_t h = bf16_rne_bits(v);
        w2hi[i] = (uint16_t)(h >> 16);
        w2lo[i] = (uint16_t)(bf16_rne_bits(v - __uint_as_float(h)) >> 16);
        return;
    }
    i -= 262144;
    if (i < 32768){ dnw1b[i] = to_b16(dn_w1[i]); return; }
    i -= 32768;
    if (i < 369664){ dnw2b[i] = to_b16(dn_w2[i]); return; }
    i -= 369664;
    if (i < 65536){ dew1b[i] = to_b16(de_w1[i]); return; }
    i -= 65536;
    if (i < 2957312){ dew2b[i] = to_b16(de_w2[i]); }
}

// ---------------- fused conv v3: 4 waves, 64x64 per wave, 32KB LDS (3x reuse) ----------------

__global__ __launch_bounds__(256) void k_conv2(
    const uint16_t* __restrict__ A,
    const uint16_t* __restrict__ W1, const float* __restrict__ B1,
    const uint16_t* __restrict__ W2, const float* __restrict__ B2,
    uint16_t* __restrict__ C)
{
    extern __shared__ __align__(16) char smem[];          // 32KB, reused 3x
    const int tid  = threadIdx.x;
    const int wave = tid >> 6;
    const int lane = tid & 63;
    const int l15  = lane & 15;
    const int lq   = lane >> 4;
    const int l7   = lane & 7;
    const int row0 = blockIdx.x * 64;

    #pragma unroll
    for (int it = 0; it < 8; ++it) {
        int s  = it*256 + tid;
        int m  = s >> 5;
        int gl = (s & 31) ^ (m & 7);
        const char* gp = (const char*)A + ((size_t)(row0+m)*HIDDEN)*2 + gl*16;
        __builtin_amdgcn_global_load_lds(
            (const __attribute__((address_space(1))) uint32_t*)gp,
            (__attribute__((address_space(3))) uint32_t*)(smem + (size_t)s*16),
            16, 0, 0);
    }

    bf16x8 bw[2][4];
    #pragma unroll
    for (int nt=0;nt<4;nt++)
        bw[0][nt] = *(const bf16x8*)(W1 + (size_t)(wave*64 + nt*16 + l15)*HIDDEN + lq*8);
    MEMPIN();
    __syncthreads();

    f32x4 acc[4][4];
    #pragma unroll
    for (int mt=0;mt<4;mt++)
        #pragma unroll
        for (int nt=0;nt<4;nt++) acc[mt][nt] = (f32x4)(0.f);

    #pragma unroll
    for (int kc = 0; kc < 8; ++kc){
        int cur = kc & 1, nxt = cur ^ 1;
        if (kc < 7){
            #pragma unroll
            for (int nt=0;nt<4;nt++)
                bw[nxt][nt] = *(const bf16x8*)(W1 + (size_t)(wave*64 + nt*16 + l15)*HIDDEN + (kc+1)*32 + lq*8);
        }
        #pragma unroll
        for (int mt=0;mt<4;mt++){
            const int mb = (mt*16 + l15) << 5;
            int g = kc*4 + lq;
            bf16x8 a = *(const bf16x8*)(smem + (size_t)(mb + (g ^ l7))*16);
            #pragma unroll
            for (int nt=0;nt<4;nt++)
                acc[mt][nt] = MFMA16(a, bw[cur][nt], acc[mt][nt], 0, 0, 0);
        }
    }

    bf16x8 bw2[2][4];
    #pragma unroll
    for (int nt=0;nt<4;nt++)
        bw2[0][nt] = *(const bf16x8*)(W2 + (size_t)(wave*64 + nt*16 + l15)*HIDDEN + lq*8);
    MEMPIN();

    BARRIER();

    uint16_t* h1 = (uint16_t*)smem;
    #pragma unroll
    for (int mt=0;mt<4;mt++){
        #pragma unroll
        for (int nt=0;nt<4;nt++){
            int col = wave*64 + nt*16 + l15;
            float bb = B1[col];
            #pragma unroll
            for (int reg=0;reg<4;reg++){
                int r = mt*16 + lq*4 + reg;
                float v = fmaxf(acc[mt][nt][reg] + bb, 0.f);
                h1[(r*32 + ((col>>3) ^ (r&7)))*8 + (col&7)] = to_b16(v);
            }
        }
    }
    BARRIER();

    #pragma unroll
    for (int mt=0;mt<4;mt++)
        #pragma unroll
        for (int nt=0;nt<4;nt++) acc[mt][nt] = (f32x4)(0.f);

    #pragma unroll
    for (int kc = 0; kc < 8; ++kc){
        int cur = kc & 1, nxt = cur ^ 1;
        if (kc < 7){
            #pragma unroll
            for (int nt=0;nt<4;nt++)
                bw2[nxt][nt] = *(const bf16x8*)(W2 + (size_t)(wave*64 + nt*16 + l15)*HIDDEN + (kc+1)*32 + lq*8);
        }
        #pragma unroll
        for (int mt=0;mt<4;mt++){
            int m = mt*16 + l15;
            bf16x8 a = *(const bf16x8*)(h1 + (size_t)(m*32 + ((kc*4 + lq) ^ (m & 7)))*8);
            #pragma unroll
            for (int nt=0;nt<4;nt++)
                acc[mt][nt] = MFMA16(a, bw2[cur][nt], acc[mt][nt], 0, 0, 0);
        }
    }
    BARRIER();

    uint16_t* rs = (uint16_t*)smem;
    #pragma unroll
    for (int mt=0;mt<4;mt++){
        #pragma unroll
        for (int nt=0;nt<4;nt++){
            int col = wave*64 + nt*16 + l15;
            float bb = B2[col];
            #pragma unroll
            for (int reg=0;reg<4;reg++){
                int r = mt*16 + lq*4 + reg;
                float v = fmaxf(acc[mt][nt][reg] + bb, 0.f);
                rs[(r*32 + ((col>>3) ^ (r&7)))*8 + (col&7)] = to_b16(v);
            }
        }
    }
    BARRIER();

    #pragma unroll
    for (int it = 0; it < 8; ++it){
        int s   = it*256 + tid;
        int row = s >> 5;
        int gc  = s & 31;
        uint4 d = *(const uint4*)(smem + (size_t)(row*32 + (gc ^ (row & 7)))*16);
        *(uint4*)(C + (size_t)(row0+row)*HIDDEN + gc*8) = d;
    }
}

// ---------------- MFMA GEMM (mu/lv + decoders) ----------------

template<int SPLIT, int OUTM>
__global__ __launch_bounds__(256) void mfma_gemm(
    const void* __restrict__ Ap, const void* __restrict__ Wp,
    const float* __restrict__ bias, void* __restrict__ Cp,
    int M, int N, int K, int relu)
{
    extern __shared__ __align__(16) char smem[];
    const int tid  = threadIdx.x;
    const int wave = tid >> 6;
    const int lane = tid & 63;
    const int l15  = lane & 15;
    const int lq   = lane >> 4;
    const int l7   = lane & 7;
    const int row0 = blockIdx.y * 64;
    const int n0   = blockIdx.x * 256;
    const int ELB  = SPLIT ? 4 : 2;
    const int KC   = (K < 256) ? K : 256;
    const int GR   = (KC * ELB) >> 4;
    const int rsh  = (GR == 64) ? 6 : ((GR == 32) ? 5 : 4);

    f32x4 acc[4][4];
    #pragma unroll
    for (int mt=0;mt<4;mt++)
        #pragma unroll
        for (int nt=0;nt<4;nt++) acc[mt][nt] = (f32x4)(0.f);

    const char* Ab = (const char*)Ap;
    const char* Wb = (const char*)Wp;

    for (int kbase = 0; kbase < K; kbase += KC) {
        const int rounds = GR >> 2;
        for (int it = 0; it < rounds; ++it) {
            int sbase = it*256 + wave*64;
            int s  = sbase + lane;
            int m  = s >> rsh;
            int gl = (s & (GR-1)) ^ (m & 7);
            const char* gp = Ab + ((size_t)(row0+m)*K + kbase)*ELB + gl*16;
            __builtin_amdgcn_global_load_lds(
                (const __attribute__((address_space(1))) uint32_t*)gp,
                (__attribute__((address_space(3))) uint32_t*)(smem + sbase*16),
                16, 0, 0);
        }
        __syncthreads();

        for (int kc = 0; kc < (KC >> 5); ++kc) {
            bf16x8 bhi[4], blo[4];
            #pragma unroll
            for (int nt=0;nt<4;nt++){
                int n = n0 + wave*64 + nt*16 + l15;
                if (n >= N) n = N-1;
                if (SPLIT){
                    const uint4* wp4 = (const uint4*)(Wb + ((size_t)n*K + kbase + kc*32 + lq*8)*4);
                    uint4 xx = wp4[0], yy = wp4[1];
                    unpack_frag(xx, yy, bhi[nt], blo[nt]);
                } else {
                    bhi[nt] = *(const bf16x8*)(Wb + ((size_t)n*K + kbase + kc*32 + lq*8)*2);
                }
            }
            #pragma unroll
            for (int mt=0;mt<4;mt++){
                const int mb = (mt*16 + l15) << rsh;
                if (SPLIT){
                    int g0 = kc*8 + lq*2;
                    uint4 xx = *(const uint4*)(smem + (size_t)(mb + ((g0  ) ^ l7))*16);
                    uint4 yy = *(const uint4*)(smem + (size_t)(mb + ((g0+1) ^ l7))*16);
                    bf16x8 ahi, alo;
                    unpack_frag(xx, yy, ahi, alo);
                    #pragma unroll
                    for (int nt=0;nt<4;nt++){
                        acc[mt][nt] = MFMA16(ahi, bhi[nt], acc[mt][nt], 0, 0, 0);
                        acc[mt][nt] = MFMA16(ahi, blo[nt], acc[mt][nt], 0, 0, 0);
                        acc[mt][nt] = MFMA16(alo, bhi[nt], acc[mt][nt], 0, 0, 0);
                    }
                } else {
                    int g = kc*4 + lq;
                    bf16x8 a = *(const bf16x8*)(smem + (size_t)(mb + (g ^ l7))*16);
                    #pragma unroll
                    for (int nt=0;nt<4;nt++){
                        acc[mt][nt] = MFMA16(a, bhi[nt], acc[mt][nt], 0, 0, 0);
                    }
                }
            }
        }
        __syncthreads();
    }

    const int ES = (OUTM == 1) ? 2 : 4;
    char* rs = smem + wave*(64*64*ES);
    const int colbase = n0 + wave*64;
    #pragma unroll
    for (int mt=0;mt<4;mt++){
        #pragma unroll
        for (int nt=0;nt<4;nt++){
            int cl = nt*16 + l15;
            int col = colbase + cl;
            float bb = bias[col < N ? col : N-1];
            #pragma unroll
            for (int reg=0;reg<4;reg++){
                int r = mt*16 + lq*4 + reg;
                float v = acc[mt][nt][reg] + bb;
                if (relu) v = fmaxf(v, 0.f);
                if (OUTM == 1) ((uint16_t*)rs)[r*64 + cl] = to_b16(v);
                else           ((float*)rs)[r*64 + cl] = v;
            }
        }
    }
    __syncthreads();
    for (int it = 0; it < 32; ++it) {
        int r   = it*2 + (lane>>5);
        int clp = lane & 31;
        int col = colbase + clp*2;
        if (col < N){
            if (OUTM == 1){
                uint32_t d = *(const uint32_t*)((const uint16_t*)rs + r*64 + clp*2);
                *(uint32_t*)((char*)Cp + ((size_t)(row0+r)*N + col)*2) = d;
            } else {
                float2 d = *(const float2*)((const float*)rs + r*64 + clp*2);
                *(float2*)((float*)Cp + (size_t)(row0+r)*N + col) = d;
            }
        }
    }
}

// ---------------- pooling + z0 elementwise ----------------

__global__ void k_pool(const uint16_t* __restrict__ h, const int* __restrict__ gstart,
                       const int* __restrict__ gcnt, uint32_t* __restrict__ hg){
    int b = blockIdx.x; int c = threadIdx.x;
    int s0 = gstart[b]; int n = gcnt[b];
    float s = 0.f;
    for (int j=0;j<n;j++) s += from_b16(h[(size_t)(s0+j)*HIDDEN + c]);
    hg[(size_t)b*HIDDEN + c] = pack_hl(s);
}

__global__ void k_z0(const float* __restrict__ mv, const float* __restrict__ eps,
                     float* __restrict__ mu_o, float* __restrict__ lv_o, float* __restrict__ z0_o){
    int i = blockIdx.x*256 + threadIdx.x;
    if (i >= NB*LAT) return;
    int b = i >> 7, l = i & 127;
    float m = mv[(size_t)b*256 + l];
    float v = mv[(size_t)b*256 + l + 128];
    mu_o[i] = m;
    lv_o[i] = v;
    z0_o[i] = m + eps[i]*expf(0.5f*v);
}

// ---------------- fused MFMA flows v6: asm-load pipeline, counted vmcnt ----------------
// 128 blocks x 512 threads (8 waves); 16 graphs/block; wave w owns output col
// groups {32w..32w+16, 32w+16..32w+32}. Weights stream through two 64-VGPR
// register banks R[0]/R[1] via volatile asm global_load_dwordx4 (cannot be
// sunk) with counted s_waitcnt vmcnt(16) (T4): one 16-load group always in
// flight. Per-flow bank roles alternate:
//   s=kf&1: W1(kf)=R[s], W2A(kf)=R[s^1]; W2B(kf)->R[s]; W1(kf+1)->R[s^1];
//   W2A(kf+1)->R[s].
// Biases preloaded+pinned so no compiler vector loads pollute vmcnt in-loop.

#define WAITV16() { asm volatile("s_waitcnt vmcnt(16)" ::: "memory"); SBAR0(); }
#define WAITV0()  { asm volatile("s_waitcnt vmcnt(0)" ::: "memory"); SBAR0(); }

__global__ __launch_bounds__(512) void k_flows_mfma6(
    const float* __restrict__ z0,
    const uint16_t* __restrict__ w1hi, const uint16_t* __restrict__ w1lo, const float* __restrict__ fb1,
    const uint16_t* __restrict__ w2hi, const uint16_t* __restrict__ w2lo, const float* __restrict__ fb2,
    float* __restrict__ zK, uint16_t* __restrict__ zkb, float* __restrict__ sld)
{
    __shared__ __align__(16) uint16_t zhi[16][136];
    __shared__ __align__(16) uint16_t zlo[16][136];
    __shared__ __align__(16) uint16_t h1hi[16][280];
    __shared__ __align__(16) uint16_t h1lo[16][280];
    __shared__ __align__(16) float    oS[16][268];
    const int tid  = threadIdx.x;
    const int wave = tid >> 6;          // 0..7
    const int lane = tid & 63;
    const int l15  = lane & 15;
    const int lq   = lane >> 4;
    const int g0   = blockIdx.x * 16;
    const int col0 = wave*32 + l15;     // group 0 column
    const int col1 = col0 + 16;         // group 1 column

    uint4 R[2][16];                     // two 64-VGPR weight banks
    // index inside a bank: g*8 + kc_local*2 + p  (p: 0=hi, 1=lo)

    // ---- prologue: issue W1(0)->R[0], W2A(0)->R[1] (volatile, ordered) ----
    #pragma unroll
    for (int g=0; g<2; ++g){
        const size_t c = (size_t)(wave*32 + g*16 + l15);
        #pragma unroll
        for (int kc=0; kc<4; ++kc){
            gload16(R[0][g*8+kc*2+0], w1hi + c*LAT + kc*32 + lq*8);
            gload16(R[0][g*8+kc*2+1], w1lo + c*LAT + kc*32 + lq*8);
        }
    }
    #pragma unroll
    for (int g=0; g<2; ++g){
        const size_t c = (size_t)(wave*32 + g*16 + l15);
        #pragma unroll
        for (int kc=0; kc<4; ++kc){
            gload16(R[1][g*8+kc*2+0], w2hi + c*FHID + kc*32 + lq*8);
            gload16(R[1][g*8+kc*2+1], w2lo + c*FHID + kc*32 + lq*8);
        }
    }

    // biases: preload + pin to registers (keeps the flow loop free of
    // compiler-generated vector loads, so vmcnt counting stays exact)
    float b1r[4][2], b2r[4][2];
    #pragma unroll
    for (int kf=0;kf<4;kf++){
        b1r[kf][0] = fb1[kf*FHID + col0];
        b1r[kf][1] = fb1[kf*FHID + col1];
        b2r[kf][0] = fb2[kf*2*LAT + col0];
        b2r[kf][1] = fb2[kf*2*LAT + col1];
        asm volatile("" : "+v"(b1r[kf][0]), "+v"(b1r[kf][1]),
                          "+v"(b2r[kf][0]), "+v"(b2r[kf][1]));
    }

    // z0 staging (hi/lo split)
    #pragma unroll
    for (int q=0;q<4;q++){
        int idx = q*512 + tid;
        int r = idx >> 7, l = idx & 127;
        float v = z0[(size_t)(g0 + r)*LAT + l];
        uint32_t h = bf16_rne_bits(v);
        zhi[r][l] = (uint16_t)(h >> 16);
        zlo[r][l] = (uint16_t)(bf16_rne_bits(v - __uint_as_float(h)) >> 16);
    }
    float ldacc = 0.f;

    asm volatile("s_waitcnt vmcnt(16) lgkmcnt(0)" ::: "memory");  // W1(0) ready; W2A may stay in flight
    SBAR0();
    __builtin_amdgcn_s_barrier();

    #pragma unroll
    for (int kf=0; kf<NFLOWS; kf++){
        const int s = kf & 1;
        const uint16_t* W2h = w2hi + (size_t)kf*2*LAT*FHID;
        const uint16_t* W2l = w2lo + (size_t)kf*2*LAT*FHID;

        // ---- GEMM1: h1 = relu(z @ W1^T + b1), W1 = R[s] ----
        {
            f32x4 a0 = (f32x4)(0.f), a1 = (f32x4)(0.f);
            #pragma unroll
            for (int kc=0;kc<4;kc++){
                bf16x8 ah = *(const bf16x8*)&zhi[l15][kc*32 + lq*8];
                bf16x8 al = *(const bf16x8*)&zlo[l15][kc*32 + lq*8];
                bf16x8 w0h = as_bf16x8(R[s][kc*2+0]);
                bf16x8 w0l = as_bf16x8(R[s][kc*2+1]);
                bf16x8 w1h_ = as_bf16x8(R[s][8+kc*2+0]);
                bf16x8 w1l_ = as_bf16x8(R[s][8+kc*2+1]);
                a0 = MFMA16(ah, w0h, a0, 0, 0, 0);
                a0 = MFMA16(ah, w0l, a0, 0, 0, 0);
                a0 = MFMA16(al, w0h, a0, 0, 0, 0);
                a1 = MFMA16(ah, w1h_, a1, 0, 0, 0);
                a1 = MFMA16(ah, w1l_, a1, 0, 0, 0);
                a1 = MFMA16(al, w1h_, a1, 0, 0, 0);
            }
            // issue W2B(kf) -> R[s] (W1 regs dead after the MFMAs above)
            #pragma unroll
            for (int g=0; g<2; ++g){
                const size_t c = (size_t)(wave*32 + g*16 + l15);
                #pragma unroll
                for (int kc=4; kc<8; ++kc){
                    gload16(R[s][g*8+(kc-4)*2+0], W2h + c*FHID + kc*32 + lq*8);
                    gload16(R[s][g*8+(kc-4)*2+1], W2l + c*FHID + kc*32 + lq*8);
                }
            }
            // epilogue1
            #pragma unroll
            for (int reg=0;reg<4;reg++){
                int r = lq*4 + reg;
                float v0 = fmaxf(a0[reg] + b1r[kf][0], 0.f);
                uint32_t h0 = bf16_rne_bits(v0);
                h1hi[r][col0] = (uint16_t)(h0 >> 16);
                h1lo[r][col0] = (uint16_t)(bf16_rne_bits(v0 - __uint_as_float(h0)) >> 16);
                float v1 = fmaxf(a1[reg] + b1r[kf][1], 0.f);
                uint32_t h1_ = bf16_rne_bits(v1);
                h1hi[r][col1] = (uint16_t)(h1_ >> 16);
                h1lo[r][col1] = (uint16_t)(bf16_rne_bits(v1 - __uint_as_float(h1_)) >> 16);
            }
        }
        BARRIER();

        // ---- GEMM2: out = h1 @ W2^T + b2 ----
        {
            f32x4 a0 = (f32x4)(0.f), a1 = (f32x4)(0.f);
            WAITV16();   // W2A(kf) = R[s^1] arrived (W2B still in flight)
            #pragma unroll
            for (int kc=0;kc<4;kc++){
                bf16x8 ah = *(const bf16x8*)&h1hi[l15][kc*32 + lq*8];
                bf16x8 al = *(const bf16x8*)&h1lo[l15][kc*32 + lq*8];
                bf16x8 w0h = as_bf16x8(R[s^1][kc*2+0]);
                bf16x8 w0l = as_bf16x8(R[s^1][kc*2+1]);
                bf16x8 w1h_ = as_bf16x8(R[s^1][8+kc*2+0]);
                bf16x8 w1l_ = as_bf16x8(R[s^1][8+kc*2+1]);
                a0 = MFMA16(ah, w0h, a0, 0, 0, 0);
                a0 = MFMA16(ah, w0l, a0, 0, 0, 0);
                a0 = MFMA16(al, w0h, a0, 0, 0, 0);
                a1 = MFMA16(ah, w1h_, a1, 0, 0, 0);
                a1 = MFMA16(ah, w1l_, a1, 0, 0, 0);
                a1 = MFMA16(al, w1h_, a1, 0, 0, 0);
            }
            // issue W1(kf+1) -> R[s^1] (W2A regs dead)
            if (kf < NFLOWS-1){
                const uint16_t* W1hn = w1hi + (size_t)(kf+1)*FHID*LAT;
                const uint16_t* W1ln = w1lo + (size_t)(kf+1)*FHID*LAT;
                #pragma unroll
                for (int g=0; g<2; ++g){
                    const size_t c = (size_t)(wave*32 + g*16 + l15);
                    #pragma unroll
                    for (int kc=0; kc<4; ++kc){
                        gload16(R[s^1][g*8+kc*2+0], W1hn + c*LAT + kc*32 + lq*8);
                        gload16(R[s^1][g*8+kc*2+1], W1ln + c*LAT + kc*32 + lq*8);
                    }
                }
                WAITV16();  // W2B(kf) done (W1 next in flight)
            } else {
                WAITV0();   // last flow: drain W2B
            }
            #pragma unroll
            for (int kc=4;kc<8;kc++){
                bf16x8 ah = *(const bf16x8*)&h1hi[l15][kc*32 + lq*8];
                bf16x8 al = *(const bf16x8*)&h1lo[l15][kc*32 + lq*8];
                bf16x8 w0h = as_bf16x8(R[s][(kc-4)*2+0]);
                bf16x8 w0l = as_bf16x8(R[s][(kc-4)*2+1]);
                bf16x8 w1h_ = as_bf16x8(R[s][8+(kc-4)*2+0]);
                bf16x8 w1l_ = as_bf16x8(R[s][8+(kc-4)*2+1]);
                a0 = MFMA16(ah, w0h, a0, 0, 0, 0);
                a0 = MFMA16(ah, w0l, a0, 0, 0, 0);
                a0 = MFMA16(al, w0h, a0, 0, 0, 0);
                a1 = MFMA16(ah, w1h_, a1, 0, 0, 0);
                a1 = MFMA16(ah, w1l_, a1, 0, 0, 0);
                a1 = MFMA16(al, w1h_, a1, 0, 0, 0);
            }
            // issue W2A(kf+1) -> R[s] (W2B regs dead)
            if (kf < NFLOWS-1){
                const uint16_t* W2hn = w2hi + (size_t)(kf+1)*2*LAT*FHID;
                const uint16_t* W2ln = w2lo + (size_t)(kf+1)*2*LAT*FHID;
                #pragma unroll
                for (int g=0; g<2; ++g){
                    const size_t c = (size_t)(wave*32 + g*16 + l15);
                    #pragma unroll
                    for (int kc=0; kc<4; ++kc){
                        gload16(R[s][g*8+kc*2+0], W2hn + c*FHID + kc*32 + lq*8);
                        gload16(R[s][g*8+kc*2+1], W2ln + c*FHID + kc*32 + lq*8);
                    }
                }
            }
            #pragma unroll
            for (int reg=0;reg<4;reg++){
                oS[lq*4 + reg][col0] = a0[reg] + b2r[kf][0];
                oS[lq*4 + reg][col1] = a1[reg] + b2r[kf][1];
            }
        }
        BARRIER();

        // ---- z update + log-det: wave w rows {2w, 2w+1}, half-wave per row ----
        {
            const int r  = 2*wave + (lane >> 5);
            const int ln = lane & 31;
            float ldp = 0.f;
            #pragma unroll
            for (int j=0;j<4;j++){
                int l = ln + j*32;
                float m = oS[r][l];
                float s2 = oS[r][l + 128];
                float g = 1.f/(1.f + expf(-s2));
                float zv = __uint_as_float((uint32_t)zhi[r][l] << 16)
                         + __uint_as_float((uint32_t)zlo[r][l] << 16);
                float zn = g*zv + (1.f - g)*m;
                uint32_t h = bf16_rne_bits(zn);
                zhi[r][l] = (uint16_t)(h >> 16);
                zlo[r][l] = (uint16_t)(bf16_rne_bits(zn - __uint_as_float(h)) >> 16);
                ldp += logf(g + 1e-8f);
            }
            #pragma unroll
            for (int off=1; off<32; off<<=1) ldp += __shfl_xor(ldp, off);
            ldacc += ldp;
        }
        BARRIER();

        if (kf < NFLOWS-1){
            WAITV16();   // W1(kf+1) done; W2A(kf+1) stays in flight through GEMM1
        }
    }

    #pragma unroll
    for (int q=0;q<4;q++){
        int idx = q*512 + tid;
        int r = idx >> 7, l = idx & 127;
        uint32_t h = (uint32_t)zhi[r][l] << 16;
        float zv = __uint_as_float(h) + __uint_as_float((uint32_t)zlo[r][l] << 16);
        zK[(size_t)(g0+r)*LAT + l] = zv;
        zkb[(size_t)(g0+r)*LAT + l] = (uint16_t)(h >> 16);
    }
    if ((lane & 31) == 0) sld[g0 + 2*wave + (lane >> 5)] = ldacc;
}

// ---------------- edge-logits symmetrize ----------------

__global__ void k_sym(const float* __restrict__ raw, float* __restrict__ outp){
    int idx = blockIdx.x*256 + threadIdx.x;
    const int total = NB*MA*MA;
    if (idx >= total) return;
    int b = idx / (MA*MA);
    int rem = idx - b*(MA*MA);
    int i = rem / MA;
    int j = rem - i*MA;
    const size_t base = (size_t)b*(MA*MA*NEF_);
    const float4 a  = *(const float4*)(raw + base + (size_t)(i*MA + j)*NEF_);
    const float4 bt = *(const float4*)(raw + base + (size_t)(j*MA + i)*NEF_);
    float4 r;
    r.x = (a.x + bt.x)*0.5f;
    r.y = (a.y + bt.y)*0.5f;
    r.z = (a.z + bt.z)*0.5f;
    r.w = (a.w + bt.w)*0.5f;
    *(float4*)(outp + base + (size_t)(i*MA + j)*NEF_) = r;
}

// ---------------- launch ----------------

extern "C" void kernel_launch(void* const* d_in, const int* in_sizes, int n_in,
                              void* d_out, int out_size, void* d_ws, size_t ws_size,
                              hipStream_t stream){
    (void)in_sizes; (void)n_in; (void)out_size; (void)ws_size;
    const int*   x        = (const int*)d_in[0];
    const int*   eidx     = (const int*)d_in[1];
    const int*   eattr    = (const int*)d_in[2];
    const int*   batch    = (const int*)d_in[3];
    const float* eps      = (const float*)d_in[4];
    const float* node_emb = (const float*)d_in[5];
    const float* edge_emb = (const float*)d_in[6];
    const float* conv_w1  = (const float*)d_in[7];
    const float* conv_b1  = (const float*)d_in[8];
    const float* conv_w2  = (const float*)d_in[9];
    const float* conv_b2  = (const float*)d_in[10];
    const float* mu_w     = (const float*)d_in[11];
    const float* mu_b     = (const float*)d_in[12];
    const float* lv_w     = (const float*)d_in[13];
    const float* lv_b     = (const float*)d_in[14];
    const float* fw1      = (const float*)d_in[15];
    const float* fb1      = (const float*)d_in[16];
    const float* fw2      = (const float*)d_in[17];
    const float* fb2      = (const float*)d_in[18];
    const float* dn_w1    = (const float*)d_in[19];
    const float* dn_b1    = (const float*)d_in[20];
    const float* dn_w2    = (const float*)d_in[21];
    const float* dn_b2    = (const float*)d_in[22];
    const float* de_w1    = (const float*)d_in[23];
    const float* de_b1    = (const float*)d_in[24];
    const float* de_w2    = (const float*)d_in[25];
    const float* de_b2    = (const float*)d_in[26];

    float* out = (float*)d_out;
    const size_t off_node = 0;
    const size_t off_edge = (size_t)NB*MA*NNF_;
    const size_t off_mu   = off_edge + (size_t)NB*MA*MA*NEF_;
    const size_t off_lv   = off_mu + (size_t)NB*LAT;
    const size_t off_z0   = off_lv + (size_t)NB*LAT;
    const size_t off_zk   = off_z0 + (size_t)NB*LAT;
    const size_t off_sld  = off_zk + (size_t)NB*LAT;
    (void)off_node;

    char* p = (char*)d_ws;
    auto alloc = [&](size_t bytes)->char*{ char* r = p; p += (bytes + 255) & ~(size_t)255; return r; };
    uint16_t* h_b   = (uint16_t*)alloc((size_t)N_NODES*HIDDEN*2);
    uint16_t* t_b   = (uint16_t*)alloc((size_t)N_NODES*HIDDEN*2);
    int*   offs   = (int*)  alloc((size_t)(N_NODES+1)*4);
    int*   cursor = (int*)  alloc((size_t)N_NODES*4);
    int*   epack  = (int*)  alloc((size_t)N_EDGES*4);
    int*   gstart = (int*)  alloc((size_t)NB*4);
    int*   gcnt   = (int*)  alloc((size_t)NB*4);
    uint32_t* hg_pk = (uint32_t*)alloc((size_t)NB*HIDDEN*4);
    float* mv       = (float*)alloc((size_t)NB*256*4);
    uint16_t* cw1b  = (uint16_t*)alloc((size_t)4*HIDDEN*HIDDEN*2);
    uint16_t* cw2b  = (uint16_t*)alloc((size_t)4*HIDDEN*HIDDEN*2);
    uint32_t* mvwpk = (uint32_t*)alloc((size_t)256*256*4);
    float*    mvb   = (float*)  alloc((size_t)256*4);
    uint16_t* w1hi  = (uint16_t*)alloc((size_t)NFLOWS*FHID*LAT*2);
    uint16_t* w1lo  = (uint16_t*)alloc((size_t)NFLOWS*FHID*LAT*2);
    uint16_t* w2hi  = (uint16_t*)alloc((size_t)NFLOWS*2*LAT*FHID*2);
    uint16_t* w2lo  = (uint16_t*)alloc((size_t)NFLOWS*2*LAT*FHID*2);
    uint16_t* dnw1b = (uint16_t*)alloc((size_t)256*LAT*2);
    uint16_t* dnw2b = (uint16_t*)alloc((size_t)MA*NNF_*256*2);
    uint16_t* dew1b = (uint16_t*)alloc((size_t)512*LAT*2);
    uint16_t* dew2b = (uint16_t*)alloc((size_t)MA*MA*NEF_*512*2);
    uint16_t* zkb   = (uint16_t*)alloc((size_t)NB*LAT*2);
    uint16_t* hnb   = (uint16_t*)alloc((size_t)NB*256*2);
    uint16_t* heb   = (uint16_t*)alloc((size_t)NB*512*2);
    float* edge_raw = (float*)alloc((size_t)NB*MA*MA*NEF_*4);

    const int* esrc = eidx;
    const int* edst = eidx + N_EDGES;

    k_cvt_all<<<(CVT_TOTAL+255)/256, 256, 0, stream>>>(
        conv_w1, conv_w2, mu_w, mu_b, lv_w, lv_b, fw1, fw2,
        dn_w1, dn_w2, de_w1, de_w2,
        cw1b, cw2b, mvwpk, mvb, w1hi, w1lo, w2hi, w2lo,
        dnw1b, dnw2b, dew1b, dew2b);

    k_init   <<<(N_NODES+255)/256, 256, 0, stream>>>(cursor, gstart, gcnt);
    k_embed  <<<N_NODES, HIDDEN, 0, stream>>>(x, node_emb, h_b);
    k_deg    <<<(N_EDGES+255)/256, 256, 0, stream>>>(edst, cursor);
    k_meta   <<<(N_NODES+255)/256, 256, 0, stream>>>(batch, gstart, gcnt);
    k_scan   <<<1, 1024, 0, stream>>>(cursor, offs);
    k_scatter<<<(N_EDGES+255)/256, 256, 0, stream>>>(esrc, edst, eattr, offs, cursor, epack);

    const size_t SM32 = 32768, SM64 = 65536;
    for (int k=0;k<4;k++){
        k_aggr<<<N_NODES/4, 256, 0, stream>>>(h_b, edge_emb, offs, epack, t_b);
        k_conv2<<<N_NODES/64, 256, SM32, stream>>>(
            t_b,
            cw1b + (size_t)k*HIDDEN*HIDDEN, conv_b1 + (size_t)k*HIDDEN,
            cw2b + (size_t)k*HIDDEN*HIDDEN, conv_b2 + (size_t)k*HIDDEN,
            h_b);
    }

    k_pool<<<NB, HIDDEN, 0, stream>>>(h_b, gstart, gcnt, hg_pk);
    mfma_gemm<1,2><<<dim3(1, NB/64), 256, SM64, stream>>>(hg_pk, mvwpk, mvb, mv, NB, 256, HIDDEN, 0);
    k_z0<<<(NB*LAT+255)/256, 256, 0, stream>>>(mv, eps, out+off_mu, out+off_lv, out+off_z0);

    k_flows_mfma6<<<NB/16, 512, 0, stream>>>(out+off_z0, w1hi, w1lo, fb1, w2hi, w2lo, fb2,
                                             out+off_zk, zkb, out+off_sld);

    mfma_gemm<0,1><<<dim3(1, NB/64), 256, SM32, stream>>>(zkb, dnw1b, dn_b1, hnb, NB, 256, LAT, 1);
    mfma_gemm<0,2><<<dim3(6, NB/64), 256, SM64, stream>>>(hnb, dnw2b, dn_b2, out+off_node, NB, MA*NNF_, 256, 0);
    mfma_gemm<0,1><<<dim3(2, NB/64), 256, SM32, stream>>>(zkb, dew1b, de_b1, heb, NB, 512, LAT, 1);
    mfma_gemm<0,2><<<dim3(23, NB/64), 256, SM64, stream>>>(heb, dew2b, de_b2, edge_raw, NB, MA*MA*NEF_, 512, 0);
    k_sym<<<(NB*MA*MA + 255)/256, 256, 0, stream>>>(edge_raw, out + off_edge);
}

// Round 5
// 585.930 us; speedup vs baseline: 1.4683x; 1.0940x over previous
//
#include <hip/hip_runtime.h>
#include <hip/hip_bf16.h>
#include <math.h>
#include <stdint.h>

#define N_NODES 49152
#define N_EDGES 196608
#define NB      2048
#define HIDDEN  256
#define LAT     128
#define FHID    256
#define NFLOWS  4
#define MA      38
#define NNF_    38
#define NEF_    4

typedef __attribute__((ext_vector_type(8))) short bf16x8;
typedef __attribute__((ext_vector_type(4))) float f32x4;

#define MEMPIN() asm volatile("" ::: "memory")
#define BARRIER() asm volatile("s_waitcnt lgkmcnt(0)\n\ts_barrier" ::: "memory")
#define SBAR0() __builtin_amdgcn_sched_barrier(0)
#define MFMA16 __builtin_amdgcn_mfma_f32_16x16x32_bf16

// volatile asm load: cannot be sunk/reordered by the compiler.
__device__ inline void gload16(uint4 &d, const void* a){
    asm volatile("global_load_dwordx4 %0, %1, off" : "=v"(d) : "v"(a));
}

// ---------- bf16 helpers ----------
__device__ inline uint32_t bf16_rne_bits(float v){
    uint32_t u = __float_as_uint(v);
    u += 0x7fffu + ((u >> 16) & 1u);
    return u & 0xffff0000u;
}
__device__ inline uint16_t to_b16(float v){ return (uint16_t)(bf16_rne_bits(v) >> 16); }
__device__ inline float from_b16(uint16_t u){ return __uint_as_float((uint32_t)u << 16); }
__device__ inline uint32_t pack_hl(float v){
    uint32_t hu = bf16_rne_bits(v);
    float r = v - __uint_as_float(hu);
    uint32_t lu = bf16_rne_bits(r);
    return hu | (lu >> 16);
}

__device__ inline void unpack_frag(const uint4& x, const uint4& y, bf16x8& hi, bf16x8& lo){
    union { bf16x8 v; uint32_t u[4]; } H, L;
    H.u[0] = __builtin_amdgcn_perm(x.y, x.x, 0x07060302u);
    H.u[1] = __builtin_amdgcn_perm(x.w, x.z, 0x07060302u);
    H.u[2] = __builtin_amdgcn_perm(y.y, y.x, 0x07060302u);
    H.u[3] = __builtin_amdgcn_perm(y.w, y.z, 0x07060302u);
    L.u[0] = __builtin_amdgcn_perm(x.y, x.x, 0x05040100u);
    L.u[1] = __builtin_amdgcn_perm(x.w, x.z, 0x05040100u);
    L.u[2] = __builtin_amdgcn_perm(y.y, y.x, 0x05040100u);
    L.u[3] = __builtin_amdgcn_perm(y.w, y.z, 0x05040100u);
    hi = H.v; lo = L.v;
}

__device__ inline bf16x8 as_bf16x8(const uint4& u){
    union { uint4 u; bf16x8 b; } cv; cv.u = u; return cv.b;
}

// ---------------- init / CSR build ----------------

__global__ void k_init(int* __restrict__ cursor, int* __restrict__ gstart, int* __restrict__ gcnt){
    int i = blockIdx.x*256 + threadIdx.x;
    if (i < N_NODES) cursor[i] = 0;
    if (i < NB){ gstart[i] = 0x7fffffff; gcnt[i] = 0; }
}

__global__ void k_embed(const int* __restrict__ x, const float* __restrict__ emb, uint16_t* __restrict__ h){
    int i = blockIdx.x; int c = threadIdx.x;
    h[(size_t)i*HIDDEN + c] = to_b16(emb[x[i]*HIDDEN + c]);
}

__global__ void k_deg(const int* __restrict__ dst, int* __restrict__ cursor){
    int e = blockIdx.x*256 + threadIdx.x;
    if (e < N_EDGES) atomicAdd(&cursor[dst[e]], 1);
}

__global__ void k_meta(const int* __restrict__ batch, int* __restrict__ gstart, int* __restrict__ gcnt){
    int i = blockIdx.x*256 + threadIdx.x;
    if (i < N_NODES){ int b = batch[i]; atomicMin(&gstart[b], i); atomicAdd(&gcnt[b], 1); }
}

__global__ __launch_bounds__(1024) void k_scan(int* __restrict__ cursor, int* __restrict__ offs){
    __shared__ int part[1024];
    const int tid = threadIdx.x;
    const int CH = N_NODES/1024; // 48
    int local[48];
    int s = 0;
    int base = tid*CH;
    for (int j=0;j<CH;j++){ local[j] = cursor[base+j]; s += local[j]; }
    part[tid] = s;
    __syncthreads();
    for (int off=1; off<1024; off<<=1){
        int v = (tid>=off) ? part[tid-off] : 0;
        __syncthreads();
        part[tid] += v;
        __syncthreads();
    }
    int excl = (tid==0) ? 0 : part[tid-1];
    for (int j=0;j<CH;j++){ offs[base+j] = excl; excl += local[j]; cursor[base+j] = 0; }
    if (tid == 1023) offs[N_NODES] = excl;
}

__global__ void k_scatter(const int* __restrict__ src, const int* __restrict__ dst, const int* __restrict__ attr,
                          const int* __restrict__ offs, int* __restrict__ cursor, int* __restrict__ epack){
    int e = blockIdx.x*256 + threadIdx.x;
    if (e < N_EDGES){
        int d = dst[e];
        int pos = atomicAdd(&cursor[d], 1);
        epack[offs[d] + pos] = (src[e] & 0xffff) | (attr[e] << 16);
    }
}

// ---------------- message aggregation: wave-per-node, 4-edge MLP chunks ----------------

__global__ __launch_bounds__(256) void k_aggr(const uint16_t* __restrict__ h, const float* __restrict__ eemb,
                                              const int* __restrict__ offs, const int* __restrict__ epack,
                                              uint16_t* __restrict__ t){
    __shared__ float sE[NEF_*HIDDEN];
    const int tid  = threadIdx.x;
    #pragma unroll
    for (int q=0;q<NEF_;q++) sE[q*256 + tid] = eemb[q*256 + tid];
    __syncthreads();

    const int wave = tid >> 6;
    const int lane = tid & 63;
    const int node = blockIdx.x*4 + wave;
    const int c4   = lane*4;

    uint2 hu = *(const uint2*)(h + (size_t)node*HIDDEN + c4);
    float4 acc;
    acc.x = __uint_as_float(hu.x << 16);
    acc.y = __uint_as_float(hu.x & 0xffff0000u);
    acc.z = __uint_as_float(hu.y << 16);
    acc.w = __uint_as_float(hu.y & 0xffff0000u);

    const int e0 = offs[node], e1 = offs[node+1];
    for (int j = e0; j < e1; j += 4){
        int p0 = epack[j];
        int p1 = (j+1 < e1) ? epack[j+1] : p0;
        int p2 = (j+2 < e1) ? epack[j+2] : p0;
        int p3 = (j+3 < e1) ? epack[j+3] : p0;
        uint2 g0 = *(const uint2*)(h + (size_t)(p0 & 0xffff)*HIDDEN + c4);
        uint2 g1 = *(const uint2*)(h + (size_t)(p1 & 0xffff)*HIDDEN + c4);
        uint2 g2 = *(const uint2*)(h + (size_t)(p2 & 0xffff)*HIDDEN + c4);
        uint2 g3 = *(const uint2*)(h + (size_t)(p3 & 0xffff)*HIDDEN + c4);
        {
            const float4 ev = *(const float4*)&sE[(p0 >> 16)*HIDDEN + c4];
            acc.x += fmaxf(__uint_as_float(g0.x << 16)        + ev.x, 0.f);
            acc.y += fmaxf(__uint_as_float(g0.x & 0xffff0000u) + ev.y, 0.f);
            acc.z += fmaxf(__uint_as_float(g0.y << 16)        + ev.z, 0.f);
            acc.w += fmaxf(__uint_as_float(g0.y & 0xffff0000u) + ev.w, 0.f);
        }
        if (j+1 < e1){
            const float4 ev = *(const float4*)&sE[(p1 >> 16)*HIDDEN + c4];
            acc.x += fmaxf(__uint_as_float(g1.x << 16)        + ev.x, 0.f);
            acc.y += fmaxf(__uint_as_float(g1.x & 0xffff0000u) + ev.y, 0.f);
            acc.z += fmaxf(__uint_as_float(g1.y << 16)        + ev.z, 0.f);
            acc.w += fmaxf(__uint_as_float(g1.y & 0xffff0000u) + ev.w, 0.f);
        }
        if (j+2 < e1){
            const float4 ev = *(const float4*)&sE[(p2 >> 16)*HIDDEN + c4];
            acc.x += fmaxf(__uint_as_float(g2.x << 16)        + ev.x, 0.f);
            acc.y += fmaxf(__uint_as_float(g2.x & 0xffff0000u) + ev.y, 0.f);
            acc.z += fmaxf(__uint_as_float(g2.y << 16)        + ev.z, 0.f);
            acc.w += fmaxf(__uint_as_float(g2.y & 0xffff0000u) + ev.w, 0.f);
        }
        if (j+3 < e1){
            const float4 ev = *(const float4*)&sE[(p3 >> 16)*HIDDEN + c4];
            acc.x += fmaxf(__uint_as_float(g3.x << 16)        + ev.x, 0.f);
            acc.y += fmaxf(__uint_as_float(g3.x & 0xffff0000u) + ev.y, 0.f);
            acc.z += fmaxf(__uint_as_float(g3.y << 16)        + ev.z, 0.f);
            acc.w += fmaxf(__uint_as_float(g3.y & 0xffff0000u) + ev.w, 0.f);
        }
    }

    uint2 o;
    o.x = (uint32_t)to_b16(acc.x) | ((uint32_t)to_b16(acc.y) << 16);
    o.y = (uint32_t)to_b16(acc.z) | ((uint32_t)to_b16(acc.w) << 16);
    *(uint2*)(t + (size_t)node*HIDDEN + c4) = o;
}

// ---------------- fused weight / activation converter (single launch) ----------------
// conv weights are packed into MFMA-fragment streaming order:
//   dst_rem = (k>>3)*2048 + o*8 + (k&7)   -- [kc*4+lq][out][8 elems]
// so each 32-K-column chunk is a contiguous 16KB block for global_load_lds.

#define CVT_TOTAL 4408320

__global__ void k_cvt_all(
    const float* __restrict__ conv_w1, const float* __restrict__ conv_w2,
    const float* __restrict__ mu_w, const float* __restrict__ mu_b,
    const float* __restrict__ lv_w, const float* __restrict__ lv_b,
    const float* __restrict__ fw1, const float* __restrict__ fw2,
    const float* __restrict__ dn_w1, const float* __restrict__ dn_w2,
    const float* __restrict__ de_w1, const float* __restrict__ de_w2,
    uint16_t* __restrict__ cw1b, uint16_t* __restrict__ cw2b,
    uint32_t* __restrict__ mvwpk, float* __restrict__ mvb,
    uint16_t* __restrict__ w1hi, uint16_t* __restrict__ w1lo,
    uint16_t* __restrict__ w2hi, uint16_t* __restrict__ w2lo,
    uint16_t* __restrict__ dnw1b, uint16_t* __restrict__ dnw2b,
    uint16_t* __restrict__ dew1b, uint16_t* __restrict__ dew2b)
{
    int i = blockIdx.x*256 + threadIdx.x;
    if (i < 262144){
        int o = (i >> 8) & 255, k = i & 255;
        int dst = (i & ~65535) | ((k >> 3) << 11) | (o << 3) | (k & 7);
        cw1b[dst] = to_b16(conv_w1[i]);
        return;
    }
    i -= 262144;
    if (i < 262144){
        int o = (i >> 8) & 255, k = i & 255;
        int dst = (i & ~65535) | ((k >> 3) << 11) | (o << 3) | (k & 7);
        cw2b[dst] = to_b16(conv_w2[i]);
        return;
    }
    i -= 262144;
    if (i < 65536){
        int o = i >> 8, k2 = i & 255;
        float v = (o < 128) ? mu_w[o*256 + k2] : lv_w[(o-128)*256 + k2];
        mvwpk[i] = pack_hl(v);
        if (i < 256) mvb[i] = (i < 128) ? mu_b[i] : lv_b[i-128];
        return;
    }
    i -= 65536;
    if (i < 131072){
        int o = (i >> 7) & 255; int kk = i & 127;
        float v = (kk <= (o % 127)) ? fw1[i] : 0.f;
        uint32_t h = bf16_rne_bits(v);
        w1hi[i] = (uint16_t)(h >> 16);
        w1lo[i] = (uint16_t)(bf16_rne_bits(v - __uint_as_float(h)) >> 16);
        return;
    }
    i -= 131072;
    if (i < 262144){
        int o = (i >> 8) & 255; int hh = i & 255;
        float v = ((hh % 127) < (o & 127)) ? fw2[i] : 0.f;
        uint32_t h = bf16_rne_bits(v);
        w2hi[i] = (uint16_t)(h >> 16);
        w2lo[i] = (uint16_t)(bf16_rne_bits(v - __uint_as_float(h)) >> 16);
        return;
    }
    i -= 262144;
    if (i < 32768){ dnw1b[i] = to_b16(dn_w1[i]); return; }
    i -= 32768;
    if (i < 369664){ dnw2b[i] = to_b16(dn_w2[i]); return; }
    i -= 369664;
    if (i < 65536){ dew1b[i] = to_b16(de_w1[i]); return; }
    i -= 65536;
    if (i < 2957312){ dew2b[i] = to_b16(de_w2[i]); }
}

// ---------------- fused conv v4: LDS-streamed weights (contiguous staging) ----------------
// The R1-R4 versions streamed weights with per-lane 16B loads at 512B row
// stride (16 scattered lines/instr) -> ~8 B/cy/CU effective; that wall was
// ~80% of conv2 time. Now weights are packed contiguously per 32-K chunk and
// staged via global_load_lds (coalesced 4KB/instr), fragments served from
// LDS conflict-free (16 lanes read 256B contiguous = 2-way, free).
// LDS: [0,32K) A-stage / h1 / out-tile; [32K,64K) weight chunk dbuf.

__global__ __launch_bounds__(256) void k_conv2(
    const uint16_t* __restrict__ A,
    const uint16_t* __restrict__ W1p, const float* __restrict__ B1,
    const uint16_t* __restrict__ W2p, const float* __restrict__ B2,
    uint16_t* __restrict__ C)
{
    extern __shared__ __align__(16) char smem[];
    const int tid  = threadIdx.x;
    const int wave = tid >> 6;
    const int lane = tid & 63;
    const int l15  = lane & 15;
    const int lq   = lane >> 4;
    const int l7   = lane & 7;
    const int row0 = blockIdx.x * 64;
    char* wb0 = smem + 32768;
    char* wb1 = smem + 32768 + 16384;

    // stage chunk kc of a packed weight matrix into wbuf (16KB, contiguous)
    #define STAGE_W(Wp, kc, wb)                                              \
        { _Pragma("unroll")                                                  \
          for (int it=0; it<4; ++it){                                        \
            int s = it*256 + tid;                                            \
            __builtin_amdgcn_global_load_lds(                                \
                (const __attribute__((address_space(1))) uint32_t*)          \
                    ((const char*)(Wp) + (size_t)(kc)*16384 + (size_t)s*16), \
                (__attribute__((address_space(3))) uint32_t*)((wb) + s*16),  \
                16, 0, 0);                                                   \
          } }

    // stage A: 64 rows x 512B = 32KB, granule-swizzled
    #pragma unroll
    for (int it = 0; it < 8; ++it) {
        int s  = it*256 + tid;
        int m  = s >> 5;
        int gl = (s & 31) ^ (m & 7);
        const char* gp = (const char*)A + ((size_t)(row0+m)*HIDDEN)*2 + gl*16;
        __builtin_amdgcn_global_load_lds(
            (const __attribute__((address_space(1))) uint32_t*)gp,
            (__attribute__((address_space(3))) uint32_t*)(smem + (size_t)s*16),
            16, 0, 0);
    }
    STAGE_W(W1p, 0, wb0);
    __syncthreads();    // A + W1c0 ready

    // ---- GEMM1 ----
    f32x4 acc[4][4];
    #pragma unroll
    for (int mt=0;mt<4;mt++)
        #pragma unroll
        for (int nt=0;nt<4;nt++) acc[mt][nt] = (f32x4)(0.f);

    #pragma unroll
    for (int kc = 0; kc < 8; ++kc){
        char* rdb = (kc & 1) ? wb1 : wb0;
        if (kc < 7){ char* stb = (kc & 1) ? wb0 : wb1; STAGE_W(W1p, kc+1, stb); }
        bf16x8 bw[4];
        #pragma unroll
        for (int nt=0;nt<4;nt++)
            bw[nt] = *(const bf16x8*)(rdb + (size_t)((lq*256 + wave*64 + nt*16 + l15)) * 16);
        #pragma unroll
        for (int mt=0;mt<4;mt++){
            const int mb = (mt*16 + l15) << 5;
            int g = kc*4 + lq;
            bf16x8 a = *(const bf16x8*)(smem + (size_t)(mb + (g ^ l7))*16);
            #pragma unroll
            for (int nt=0;nt<4;nt++)
                acc[mt][nt] = MFMA16(a, bw[nt], acc[mt][nt], 0, 0, 0);
        }
        __syncthreads();   // drains vmcnt (next chunk landed) + lgkm
    }

    // epilogue1 -> h1 into A region (dead); stage W2 chunk0 under the writes
    STAGE_W(W2p, 0, wb0);
    uint16_t* h1 = (uint16_t*)smem;
    #pragma unroll
    for (int mt=0;mt<4;mt++){
        #pragma unroll
        for (int nt=0;nt<4;nt++){
            int col = wave*64 + nt*16 + l15;
            float bb = B1[col];
            #pragma unroll
            for (int reg=0;reg<4;reg++){
                int r = mt*16 + lq*4 + reg;
                float v = fmaxf(acc[mt][nt][reg] + bb, 0.f);
                h1[(r*32 + ((col>>3) ^ (r&7)))*8 + (col&7)] = to_b16(v);
            }
        }
    }
    __syncthreads();   // h1 + W2c0 ready

    // ---- GEMM2 ----
    #pragma unroll
    for (int mt=0;mt<4;mt++)
        #pragma unroll
        for (int nt=0;nt<4;nt++) acc[mt][nt] = (f32x4)(0.f);

    #pragma unroll
    for (int kc = 0; kc < 8; ++kc){
        char* rdb = (kc & 1) ? wb1 : wb0;
        if (kc < 7){ char* stb = (kc & 1) ? wb0 : wb1; STAGE_W(W2p, kc+1, stb); }
        bf16x8 bw[4];
        #pragma unroll
        for (int nt=0;nt<4;nt++)
            bw[nt] = *(const bf16x8*)(rdb + (size_t)((lq*256 + wave*64 + nt*16 + l15)) * 16);
        #pragma unroll
        for (int mt=0;mt<4;mt++){
            int m = mt*16 + l15;
            bf16x8 a = *(const bf16x8*)(h1 + (size_t)(m*32 + ((kc*4 + lq) ^ (m & 7)))*8);
            #pragma unroll
            for (int nt=0;nt<4;nt++)
                acc[mt][nt] = MFMA16(a, bw[nt], acc[mt][nt], 0, 0, 0);
        }
        __syncthreads();
    }

    // epilogue2 -> A region, stage-style swizzle for coalesced copy-out
    uint16_t* rs = (uint16_t*)smem;
    #pragma unroll
    for (int mt=0;mt<4;mt++){
        #pragma unroll
        for (int nt=0;nt<4;nt++){
            int col = wave*64 + nt*16 + l15;
            float bb = B2[col];
            #pragma unroll
            for (int reg=0;reg<4;reg++){
                int r = mt*16 + lq*4 + reg;
                float v = fmaxf(acc[mt][nt][reg] + bb, 0.f);
                rs[(r*32 + ((col>>3) ^ (r&7)))*8 + (col&7)] = to_b16(v);
            }
        }
    }
    BARRIER();

    #pragma unroll
    for (int it = 0; it < 8; ++it){
        int s   = it*256 + tid;
        int row = s >> 5;
        int gc  = s & 31;
        uint4 d = *(const uint4*)(smem + (size_t)(row*32 + (gc ^ (row & 7)))*16);
        *(uint4*)(C + (size_t)(row0+row)*HIDDEN + gc*8) = d;
    }
    #undef STAGE_W
}

// ---------------- MFMA GEMM (mu/lv + decoders) ----------------

template<int SPLIT, int OUTM>
__global__ __launch_bounds__(256) void mfma_gemm(
    const void* __restrict__ Ap, const void* __restrict__ Wp,
    const float* __restrict__ bias, void* __restrict__ Cp,
    int M, int N, int K, int relu)
{
    extern __shared__ __align__(16) char smem[];
    const int tid  = threadIdx.x;
    const int wave = tid >> 6;
    const int lane = tid & 63;
    const int l15  = lane & 15;
    const int lq   = lane >> 4;
    const int l7   = lane & 7;
    const int row0 = blockIdx.y * 64;
    const int n0   = blockIdx.x * 256;
    const int ELB  = SPLIT ? 4 : 2;
    const int KC   = (K < 256) ? K : 256;
    const int GR   = (KC * ELB) >> 4;
    const int rsh  = (GR == 64) ? 6 : ((GR == 32) ? 5 : 4);

    f32x4 acc[4][4];
    #pragma unroll
    for (int mt=0;mt<4;mt++)
        #pragma unroll
        for (int nt=0;nt<4;nt++) acc[mt][nt] = (f32x4)(0.f);

    const char* Ab = (const char*)Ap;
    const char* Wb = (const char*)Wp;

    for (int kbase = 0; kbase < K; kbase += KC) {
        const int rounds = GR >> 2;
        for (int it = 0; it < rounds; ++it) {
            int sbase = it*256 + wave*64;
            int s  = sbase + lane;
            int m  = s >> rsh;
            int gl = (s & (GR-1)) ^ (m & 7);
            const char* gp = Ab + ((size_t)(row0+m)*K + kbase)*ELB + gl*16;
            __builtin_amdgcn_global_load_lds(
                (const __attribute__((address_space(1))) uint32_t*)gp,
                (__attribute__((address_space(3))) uint32_t*)(smem + sbase*16),
                16, 0, 0);
        }
        __syncthreads();

        for (int kc = 0; kc < (KC >> 5); ++kc) {
            bf16x8 bhi[4], blo[4];
            #pragma unroll
            for (int nt=0;nt<4;nt++){
                int n = n0 + wave*64 + nt*16 + l15;
                if (n >= N) n = N-1;
                if (SPLIT){
                    const uint4* wp4 = (const uint4*)(Wb + ((size_t)n*K + kbase + kc*32 + lq*8)*4);
                    uint4 xx = wp4[0], yy = wp4[1];
                    unpack_frag(xx, yy, bhi[nt], blo[nt]);
                } else {
                    bhi[nt] = *(const bf16x8*)(Wb + ((size_t)n*K + kbase + kc*32 + lq*8)*2);
                }
            }
            #pragma unroll
            for (int mt=0;mt<4;mt++){
                const int mb = (mt*16 + l15) << rsh;
                if (SPLIT){
                    int g0 = kc*8 + lq*2;
                    uint4 xx = *(const uint4*)(smem + (size_t)(mb + ((g0  ) ^ l7))*16);
                    uint4 yy = *(const uint4*)(smem + (size_t)(mb + ((g0+1) ^ l7))*16);
                    bf16x8 ahi, alo;
                    unpack_frag(xx, yy, ahi, alo);
                    #pragma unroll
                    for (int nt=0;nt<4;nt++){
                        acc[mt][nt] = MFMA16(ahi, bhi[nt], acc[mt][nt], 0, 0, 0);
                        acc[mt][nt] = MFMA16(ahi, blo[nt], acc[mt][nt], 0, 0, 0);
                        acc[mt][nt] = MFMA16(alo, bhi[nt], acc[mt][nt], 0, 0, 0);
                    }
                } else {
                    int g = kc*4 + lq;
                    bf16x8 a = *(const bf16x8*)(smem + (size_t)(mb + (g ^ l7))*16);
                    #pragma unroll
                    for (int nt=0;nt<4;nt++){
                        acc[mt][nt] = MFMA16(a, bhi[nt], acc[mt][nt], 0, 0, 0);
                    }
                }
            }
        }
        __syncthreads();
    }

    const int ES = (OUTM == 1) ? 2 : 4;
    char* rs = smem + wave*(64*64*ES);
    const int colbase = n0 + wave*64;
    #pragma unroll
    for (int mt=0;mt<4;mt++){
        #pragma unroll
        for (int nt=0;nt<4;nt++){
            int cl = nt*16 + l15;
            int col = colbase + cl;
            float bb = bias[col < N ? col : N-1];
            #pragma unroll
            for (int reg=0;reg<4;reg++){
                int r = mt*16 + lq*4 + reg;
                float v = acc[mt][nt][reg] + bb;
                if (relu) v = fmaxf(v, 0.f);
                if (OUTM == 1) ((uint16_t*)rs)[r*64 + cl] = to_b16(v);
                else           ((float*)rs)[r*64 + cl] = v;
            }
        }
    }
    __syncthreads();
    for (int it = 0; it < 32; ++it) {
        int r   = it*2 + (lane>>5);
        int clp = lane & 31;
        int col = colbase + clp*2;
        if (col < N){
            if (OUTM == 1){
                uint32_t d = *(const uint32_t*)((const uint16_t*)rs + r*64 + clp*2);
                *(uint32_t*)((char*)Cp + ((size_t)(row0+r)*N + col)*2) = d;
            } else {
                float2 d = *(const float2*)((const float*)rs + r*64 + clp*2);
                *(float2*)((float*)Cp + (size_t)(row0+r)*N + col) = d;
            }
        }
    }
}

// ---------------- pooling + z0 elementwise ----------------

__global__ void k_pool(const uint16_t* __restrict__ h, const int* __restrict__ gstart,
                       const int* __restrict__ gcnt, uint32_t* __restrict__ hg){
    int b = blockIdx.x; int c = threadIdx.x;
    int s0 = gstart[b]; int n = gcnt[b];
    float s = 0.f;
    for (int j=0;j<n;j++) s += from_b16(h[(size_t)(s0+j)*HIDDEN + c]);
    hg[(size_t)b*HIDDEN + c] = pack_hl(s);
}

__global__ void k_z0(const float* __restrict__ mv, const float* __restrict__ eps,
                     float* __restrict__ mu_o, float* __restrict__ lv_o, float* __restrict__ z0_o){
    int i = blockIdx.x*256 + threadIdx.x;
    if (i >= NB*LAT) return;
    int b = i >> 7, l = i & 127;
    float m = mv[(size_t)b*256 + l];
    float v = mv[(size_t)b*256 + l + 128];
    mu_o[i] = m;
    lv_o[i] = v;
    z0_o[i] = m + eps[i]*expf(0.5f*v);
}

// ---------------- fused MFMA flows v6: asm-load pipeline, counted vmcnt ----------------

#define WAITV16() { asm volatile("s_waitcnt vmcnt(16)" ::: "memory"); SBAR0(); }
#define WAITV0()  { asm volatile("s_waitcnt vmcnt(0)" ::: "memory"); SBAR0(); }

__global__ __launch_bounds__(512) void k_flows_mfma6(
    const float* __restrict__ z0,
    const uint16_t* __restrict__ w1hi, const uint16_t* __restrict__ w1lo, const float* __restrict__ fb1,
    const uint16_t* __restrict__ w2hi, const uint16_t* __restrict__ w2lo, const float* __restrict__ fb2,
    float* __restrict__ zK, uint16_t* __restrict__ zkb, float* __restrict__ sld)
{
    __shared__ __align__(16) uint16_t zhi[16][136];
    __shared__ __align__(16) uint16_t zlo[16][136];
    __shared__ __align__(16) uint16_t h1hi[16][280];
    __shared__ __align__(16) uint16_t h1lo[16][280];
    __shared__ __align__(16) float    oS[16][268];
    const int tid  = threadIdx.x;
    const int wave = tid >> 6;          // 0..7
    const int lane = tid & 63;
    const int l15  = lane & 15;
    const int lq   = lane >> 4;
    const int g0   = blockIdx.x * 16;
    const int col0 = wave*32 + l15;
    const int col1 = col0 + 16;

    uint4 R[2][16];

    #pragma unroll
    for (int g=0; g<2; ++g){
        const size_t c = (size_t)(wave*32 + g*16 + l15);
        #pragma unroll
        for (int kc=0; kc<4; ++kc){
            gload16(R[0][g*8+kc*2+0], w1hi + c*LAT + kc*32 + lq*8);
            gload16(R[0][g*8+kc*2+1], w1lo + c*LAT + kc*32 + lq*8);
        }
    }
    #pragma unroll
    for (int g=0; g<2; ++g){
        const size_t c = (size_t)(wave*32 + g*16 + l15);
        #pragma unroll
        for (int kc=0; kc<4; ++kc){
            gload16(R[1][g*8+kc*2+0], w2hi + c*FHID + kc*32 + lq*8);
            gload16(R[1][g*8+kc*2+1], w2lo + c*FHID + kc*32 + lq*8);
        }
    }

    float b1r[4][2], b2r[4][2];
    #pragma unroll
    for (int kf=0;kf<4;kf++){
        b1r[kf][0] = fb1[kf*FHID + col0];
        b1r[kf][1] = fb1[kf*FHID + col1];
        b2r[kf][0] = fb2[kf*2*LAT + col0];
        b2r[kf][1] = fb2[kf*2*LAT + col1];
        asm volatile("" : "+v"(b1r[kf][0]), "+v"(b1r[kf][1]),
                          "+v"(b2r[kf][0]), "+v"(b2r[kf][1]));
    }

    #pragma unroll
    for (int q=0;q<4;q++){
        int idx = q*512 + tid;
        int r = idx >> 7, l = idx & 127;
        float v = z0[(size_t)(g0 + r)*LAT + l];
        uint32_t h = bf16_rne_bits(v);
        zhi[r][l] = (uint16_t)(h >> 16);
        zlo[r][l] = (uint16_t)(bf16_rne_bits(v - __uint_as_float(h)) >> 16);
    }
    float ldacc = 0.f;

    asm volatile("s_waitcnt vmcnt(16) lgkmcnt(0)" ::: "memory");
    SBAR0();
    __builtin_amdgcn_s_barrier();

    #pragma unroll
    for (int kf=0; kf<NFLOWS; kf++){
        const int s = kf & 1;
        const uint16_t* W2h = w2hi + (size_t)kf*2*LAT*FHID;
        const uint16_t* W2l = w2lo + (size_t)kf*2*LAT*FHID;

        {
            f32x4 a0 = (f32x4)(0.f), a1 = (f32x4)(0.f);
            #pragma unroll
            for (int kc=0;kc<4;kc++){
                bf16x8 ah = *(const bf16x8*)&zhi[l15][kc*32 + lq*8];
                bf16x8 al = *(const bf16x8*)&zlo[l15][kc*32 + lq*8];
                bf16x8 w0h = as_bf16x8(R[s][kc*2+0]);
                bf16x8 w0l = as_bf16x8(R[s][kc*2+1]);
                bf16x8 w1h_ = as_bf16x8(R[s][8+kc*2+0]);
                bf16x8 w1l_ = as_bf16x8(R[s][8+kc*2+1]);
                a0 = MFMA16(ah, w0h, a0, 0, 0, 0);
                a0 = MFMA16(ah, w0l, a0, 0, 0, 0);
                a0 = MFMA16(al, w0h, a0, 0, 0, 0);
                a1 = MFMA16(ah, w1h_, a1, 0, 0, 0);
                a1 = MFMA16(ah, w1l_, a1, 0, 0, 0);
                a1 = MFMA16(al, w1h_, a1, 0, 0, 0);
            }
            #pragma unroll
            for (int g=0; g<2; ++g){
                const size_t c = (size_t)(wave*32 + g*16 + l15);
                #pragma unroll
                for (int kc=4; kc<8; ++kc){
                    gload16(R[s][g*8+(kc-4)*2+0], W2h + c*FHID + kc*32 + lq*8);
                    gload16(R[s][g*8+(kc-4)*2+1], W2l + c*FHID + kc*32 + lq*8);
                }
            }
            #pragma unroll
            for (int reg=0;reg<4;reg++){
                int r = lq*4 + reg;
                float v0 = fmaxf(a0[reg] + b1r[kf][0], 0.f);
                uint32_t h0 = bf16_rne_bits(v0);
                h1hi[r][col0] = (uint16_t)(h0 >> 16);
                h1lo[r][col0] = (uint16_t)(bf16_rne_bits(v0 - __uint_as_float(h0)) >> 16);
                float v1 = fmaxf(a1[reg] + b1r[kf][1], 0.f);
                uint32_t h1_ = bf16_rne_bits(v1);
                h1hi[r][col1] = (uint16_t)(h1_ >> 16);
                h1lo[r][col1] = (uint16_t)(bf16_rne_bits(v1 - __uint_as_float(h1_)) >> 16);
            }
        }
        BARRIER();

        {
            f32x4 a0 = (f32x4)(0.f), a1 = (f32x4)(0.f);
            WAITV16();
            #pragma unroll
            for (int kc=0;kc<4;kc++){
                bf16x8 ah = *(const bf16x8*)&h1hi[l15][kc*32 + lq*8];
                bf16x8 al = *(const bf16x8*)&h1lo[l15][kc*32 + lq*8];
                bf16x8 w0h = as_bf16x8(R[s^1][kc*2+0]);
                bf16x8 w0l = as_bf16x8(R[s^1][kc*2+1]);
                bf16x8 w1h_ = as_bf16x8(R[s^1][8+kc*2+0]);
                bf16x8 w1l_ = as_bf16x8(R[s^1][8+kc*2+1]);
                a0 = MFMA16(ah, w0h, a0, 0, 0, 0);
                a0 = MFMA16(ah, w0l, a0, 0, 0, 0);
                a0 = MFMA16(al, w0h, a0, 0, 0, 0);
                a1 = MFMA16(ah, w1h_, a1, 0, 0, 0);
                a1 = MFMA16(ah, w1l_, a1, 0, 0, 0);
                a1 = MFMA16(al, w1h_, a1, 0, 0, 0);
            }
            if (kf < NFLOWS-1){
                const uint16_t* W1hn = w1hi + (size_t)(kf+1)*FHID*LAT;
                const uint16_t* W1ln = w1lo + (size_t)(kf+1)*FHID*LAT;
                #pragma unroll
                for (int g=0; g<2; ++g){
                    const size_t c = (size_t)(wave*32 + g*16 + l15);
                    #pragma unroll
                    for (int kc=0; kc<4; ++kc){
                        gload16(R[s^1][g*8+kc*2+0], W1hn + c*LAT + kc*32 + lq*8);
                        gload16(R[s^1][g*8+kc*2+1], W1ln + c*LAT + kc*32 + lq*8);
                    }
                }
                WAITV16();
            } else {
                WAITV0();
            }
            #pragma unroll
            for (int kc=4;kc<8;kc++){
                bf16x8 ah = *(const bf16x8*)&h1hi[l15][kc*32 + lq*8];
                bf16x8 al = *(const bf16x8*)&h1lo[l15][kc*32 + lq*8];
                bf16x8 w0h = as_bf16x8(R[s][(kc-4)*2+0]);
                bf16x8 w0l = as_bf16x8(R[s][(kc-4)*2+1]);
                bf16x8 w1h_ = as_bf16x8(R[s][8+(kc-4)*2+0]);
                bf16x8 w1l_ = as_bf16x8(R[s][8+(kc-4)*2+1]);
                a0 = MFMA16(ah, w0h, a0, 0, 0, 0);
                a0 = MFMA16(ah, w0l, a0, 0, 0, 0);
                a0 = MFMA16(al, w0h, a0, 0, 0, 0);
                a1 = MFMA16(ah, w1h_, a1, 0, 0, 0);
                a1 = MFMA16(ah, w1l_, a1, 0, 0, 0);
                a1 = MFMA16(al, w1h_, a1, 0, 0, 0);
            }
            if (kf < NFLOWS-1){
                const uint16_t* W2hn = w2hi + (size_t)(kf+1)*2*LAT*FHID;
                const uint16_t* W2ln = w2lo + (size_t)(kf+1)*2*LAT*FHID;
                #pragma unroll
                for (int g=0; g<2; ++g){
                    const size_t c = (size_t)(wave*32 + g*16 + l15);
                    #pragma unroll
                    for (int kc=0; kc<4; ++kc){
                        gload16(R[s][g*8+kc*2+0], W2hn + c*FHID + kc*32 + lq*8);
                        gload16(R[s][g*8+kc*2+1], W2ln + c*FHID + kc*32 + lq*8);
                    }
                }
            }
            #pragma unroll
            for (int reg=0;reg<4;reg++){
                oS[lq*4 + reg][col0] = a0[reg] + b2r[kf][0];
                oS[lq*4 + reg][col1] = a1[reg] + b2r[kf][1];
            }
        }
        BARRIER();

        {
            const int r  = 2*wave + (lane >> 5);
            const int ln = lane & 31;
            float ldp = 0.f;
            #pragma unroll
            for (int j=0;j<4;j++){
                int l = ln + j*32;
                float m = oS[r][l];
                float s2 = oS[r][l + 128];
                float g = 1.f/(1.f + expf(-s2));
                float zv = __uint_as_float((uint32_t)zhi[r][l] << 16)
                         + __uint_as_float((uint32_t)zlo[r][l] << 16);
                float zn = g*zv + (1.f - g)*m;
                uint32_t h = bf16_rne_bits(zn);
                zhi[r][l] = (uint16_t)(h >> 16);
                zlo[r][l] = (uint16_t)(bf16_rne_bits(zn - __uint_as_float(h)) >> 16);
                ldp += logf(g + 1e-8f);
            }
            #pragma unroll
            for (int off=1; off<32; off<<=1) ldp += __shfl_xor(ldp, off);
            ldacc += ldp;
        }
        BARRIER();

        if (kf < NFLOWS-1){
            WAITV16();
        }
    }

    #pragma unroll
    for (int q=0;q<4;q++){
        int idx = q*512 + tid;
        int r = idx >> 7, l = idx & 127;
        uint32_t h = (uint32_t)zhi[r][l] << 16;
        float zv = __uint_as_float(h) + __uint_as_float((uint32_t)zlo[r][l] << 16);
        zK[(size_t)(g0+r)*LAT + l] = zv;
        zkb[(size_t)(g0+r)*LAT + l] = (uint16_t)(h >> 16);
    }
    if ((lane & 31) == 0) sld[g0 + 2*wave + (lane >> 5)] = ldacc;
}

// ---------------- edge-logits symmetrize ----------------

__global__ void k_sym(const float* __restrict__ raw, float* __restrict__ outp){
    int idx = blockIdx.x*256 + threadIdx.x;
    const int total = NB*MA*MA;
    if (idx >= total) return;
    int b = idx / (MA*MA);
    int rem = idx - b*(MA*MA);
    int i = rem / MA;
    int j = rem - i*MA;
    const size_t base = (size_t)b*(MA*MA*NEF_);
    const float4 a  = *(const float4*)(raw + base + (size_t)(i*MA + j)*NEF_);
    const float4 bt = *(const float4*)(raw + base + (size_t)(j*MA + i)*NEF_);
    float4 r;
    r.x = (a.x + bt.x)*0.5f;
    r.y = (a.y + bt.y)*0.5f;
    r.z = (a.z + bt.z)*0.5f;
    r.w = (a.w + bt.w)*0.5f;
    *(float4*)(outp + base + (size_t)(i*MA + j)*NEF_) = r;
}

// ---------------- launch ----------------

extern "C" void kernel_launch(void* const* d_in, const int* in_sizes, int n_in,
                              void* d_out, int out_size, void* d_ws, size_t ws_size,
                              hipStream_t stream){
    (void)in_sizes; (void)n_in; (void)out_size; (void)ws_size;
    const int*   x        = (const int*)d_in[0];
    const int*   eidx     = (const int*)d_in[1];
    const int*   eattr    = (const int*)d_in[2];
    const int*   batch    = (const int*)d_in[3];
    const float* eps      = (const float*)d_in[4];
    const float* node_emb = (const float*)d_in[5];
    const float* edge_emb = (const float*)d_in[6];
    const float* conv_w1  = (const float*)d_in[7];
    const float* conv_b1  = (const float*)d_in[8];
    const float* conv_w2  = (const float*)d_in[9];
    const float* conv_b2  = (const float*)d_in[10];
    const float* mu_w     = (const float*)d_in[11];
    const float* mu_b     = (const float*)d_in[12];
    const float* lv_w     = (const float*)d_in[13];
    const float* lv_b     = (const float*)d_in[14];
    const float* fw1      = (const float*)d_in[15];
    const float* fb1      = (const float*)d_in[16];
    const float* fw2      = (const float*)d_in[17];
    const float* fb2      = (const float*)d_in[18];
    const float* dn_w1    = (const float*)d_in[19];
    const float* dn_b1    = (const float*)d_in[20];
    const float* dn_w2    = (const float*)d_in[21];
    const float* dn_b2    = (const float*)d_in[22];
    const float* de_w1    = (const float*)d_in[23];
    const float* de_b1    = (const float*)d_in[24];
    const float* de_w2    = (const float*)d_in[25];
    const float* de_b2    = (const float*)d_in[26];

    float* out = (float*)d_out;
    const size_t off_node = 0;
    const size_t off_edge = (size_t)NB*MA*NNF_;
    const size_t off_mu   = off_edge + (size_t)NB*MA*MA*NEF_;
    const size_t off_lv   = off_mu + (size_t)NB*LAT;
    const size_t off_z0   = off_lv + (size_t)NB*LAT;
    const size_t off_zk   = off_z0 + (size_t)NB*LAT;
    const size_t off_sld  = off_zk + (size_t)NB*LAT;
    (void)off_node;

    char* p = (char*)d_ws;
    auto alloc = [&](size_t bytes)->char*{ char* r = p; p += (bytes + 255) & ~(size_t)255; return r; };
    uint16_t* h_b   = (uint16_t*)alloc((size_t)N_NODES*HIDDEN*2);
    uint16_t* t_b   = (uint16_t*)alloc((size_t)N_NODES*HIDDEN*2);
    int*   offs   = (int*)  alloc((size_t)(N_NODES+1)*4);
    int*   cursor = (int*)  alloc((size_t)N_NODES*4);
    int*   epack  = (int*)  alloc((size_t)N_EDGES*4);
    int*   gstart = (int*)  alloc((size_t)NB*4);
    int*   gcnt   = (int*)  alloc((size_t)NB*4);
    uint32_t* hg_pk = (uint32_t*)alloc((size_t)NB*HIDDEN*4);
    float* mv       = (float*)alloc((size_t)NB*256*4);
    uint16_t* cw1b  = (uint16_t*)alloc((size_t)4*HIDDEN*HIDDEN*2);
    uint16_t* cw2b  = (uint16_t*)alloc((size_t)4*HIDDEN*HIDDEN*2);
    uint32_t* mvwpk = (uint32_t*)alloc((size_t)256*256*4);
    float*    mvb   = (float*)  alloc((size_t)256*4);
    uint16_t* w1hi  = (uint16_t*)alloc((size_t)NFLOWS*FHID*LAT*2);
    uint16_t* w1lo  = (uint16_t*)alloc((size_t)NFLOWS*FHID*LAT*2);
    uint16_t* w2hi  = (uint16_t*)alloc((size_t)NFLOWS*2*LAT*FHID*2);
    uint16_t* w2lo  = (uint16_t*)alloc((size_t)NFLOWS*2*LAT*FHID*2);
    uint16_t* dnw1b = (uint16_t*)alloc((size_t)256*LAT*2);
    uint16_t* dnw2b = (uint16_t*)alloc((size_t)MA*NNF_*256*2);
    uint16_t* dew1b = (uint16_t*)alloc((size_t)512*LAT*2);
    uint16_t* dew2b = (uint16_t*)alloc((size_t)MA*MA*NEF_*512*2);
    uint16_t* zkb   = (uint16_t*)alloc((size_t)NB*LAT*2);
    uint16_t* hnb   = (uint16_t*)alloc((size_t)NB*256*2);
    uint16_t* heb   = (uint16_t*)alloc((size_t)NB*512*2);
    float* edge_raw = (float*)alloc((size_t)NB*MA*MA*NEF_*4);

    const int* esrc = eidx;
    const int* edst = eidx + N_EDGES;

    k_cvt_all<<<(CVT_TOTAL+255)/256, 256, 0, stream>>>(
        conv_w1, conv_w2, mu_w, mu_b, lv_w, lv_b, fw1, fw2,
        dn_w1, dn_w2, de_w1, de_w2,
        cw1b, cw2b, mvwpk, mvb, w1hi, w1lo, w2hi, w2lo,
        dnw1b, dnw2b, dew1b, dew2b);

    k_init   <<<(N_NODES+255)/256, 256, 0, stream>>>(cursor, gstart, gcnt);
    k_embed  <<<N_NODES, HIDDEN, 0, stream>>>(x, node_emb, h_b);
    k_deg    <<<(N_EDGES+255)/256, 256, 0, stream>>>(edst, cursor);
    k_meta   <<<(N_NODES+255)/256, 256, 0, stream>>>(batch, gstart, gcnt);
    k_scan   <<<1, 1024, 0, stream>>>(cursor, offs);
    k_scatter<<<(N_EDGES+255)/256, 256, 0, stream>>>(esrc, edst, eattr, offs, cursor, epack);

    const size_t SM32 = 32768, SM64 = 65536;
    for (int k=0;k<4;k++){
        k_aggr<<<N_NODES/4, 256, 0, stream>>>(h_b, edge_emb, offs, epack, t_b);
        k_conv2<<<N_NODES/64, 256, SM64, stream>>>(
            t_b,
            cw1b + (size_t)k*HIDDEN*HIDDEN, conv_b1 + (size_t)k*HIDDEN,
            cw2b + (size_t)k*HIDDEN*HIDDEN, conv_b2 + (size_t)k*HIDDEN,
            h_b);
    }

    k_pool<<<NB, HIDDEN, 0, stream>>>(h_b, gstart, gcnt, hg_pk);
    mfma_gemm<1,2><<<dim3(1, NB/64), 256, SM64, stream>>>(hg_pk, mvwpk, mvb, mv, NB, 256, HIDDEN, 0);
    k_z0<<<(NB*LAT+255)/256, 256, 0, stream>>>(mv, eps, out+off_mu, out+off_lv, out+off_z0);

    k_flows_mfma6<<<NB/16, 512, 0, stream>>>(out+off_z0, w1hi, w1lo, fb1, w2hi, w2lo, fb2,
                                             out+off_zk, zkb, out+off_sld);

    mfma_gemm<0,1><<<dim3(1, NB/64), 256, SM32, stream>>>(zkb, dnw1b, dn_b1, hnb, NB, 256, LAT, 1);
    mfma_gemm<0,2><<<dim3(6, NB/64), 256, SM64, stream>>>(hnb, dnw2b, dn_b2, out+off_node, NB, MA*NNF_, 256, 0);
    mfma_gemm<0,1><<<dim3(2, NB/64), 256, SM32, stream>>>(zkb, dew1b, de_b1, heb, NB, 512, LAT, 1);
    mfma_gemm<0,2><<<dim3(23, NB/64), 256, SM64, stream>>>(heb, dew2b, de_b2, edge_raw, NB, MA*MA*NEF_, 512, 0);
    k_sym<<<(NB*MA*MA + 255)/256, 256, 0, stream>>>(edge_raw, out + off_edge);
}

// Round 6
// 577.754 us; speedup vs baseline: 1.4891x; 1.0142x over previous
//
#include <hip/hip_runtime.h>
#include <hip/hip_bf16.h>
#include <math.h>
#include <stdint.h>

#define N_NODES 49152
#define N_EDGES 196608
#define NB      2048
#define HIDDEN  256
#define LAT     128
#define FHID    256
#define NFLOWS  4
#define MA      38
#define NNF_    38
#define NEF_    4

typedef __attribute__((ext_vector_type(8))) short bf16x8;
typedef __attribute__((ext_vector_type(4))) float f32x4;

#define MEMPIN() asm volatile("" ::: "memory")
#define BARRIER() asm volatile("s_waitcnt lgkmcnt(0)\n\ts_barrier" ::: "memory")
#define MFMA16 __builtin_amdgcn_mfma_f32_16x16x32_bf16

// ---------- bf16 helpers ----------
__device__ inline uint32_t bf16_rne_bits(float v){
    uint32_t u = __float_as_uint(v);
    u += 0x7fffu + ((u >> 16) & 1u);
    return u & 0xffff0000u;
}
__device__ inline uint16_t to_b16(float v){ return (uint16_t)(bf16_rne_bits(v) >> 16); }
__device__ inline float from_b16(uint16_t u){ return __uint_as_float((uint32_t)u << 16); }
__device__ inline uint32_t pack_hl(float v){
    uint32_t hu = bf16_rne_bits(v);
    float r = v - __uint_as_float(hu);
    uint32_t lu = bf16_rne_bits(r);
    return hu | (lu >> 16);
}

__device__ inline void unpack_frag(const uint4& x, const uint4& y, bf16x8& hi, bf16x8& lo){
    union { bf16x8 v; uint32_t u[4]; } H, L;
    H.u[0] = __builtin_amdgcn_perm(x.y, x.x, 0x07060302u);
    H.u[1] = __builtin_amdgcn_perm(x.w, x.z, 0x07060302u);
    H.u[2] = __builtin_amdgcn_perm(y.y, y.x, 0x07060302u);
    H.u[3] = __builtin_amdgcn_perm(y.w, y.z, 0x07060302u);
    L.u[0] = __builtin_amdgcn_perm(x.y, x.x, 0x05040100u);
    L.u[1] = __builtin_amdgcn_perm(x.w, x.z, 0x05040100u);
    L.u[2] = __builtin_amdgcn_perm(y.y, y.x, 0x05040100u);
    L.u[3] = __builtin_amdgcn_perm(y.w, y.z, 0x05040100u);
    hi = H.v; lo = L.v;
}

// ---------------- init / CSR build ----------------

__global__ void k_init(int* __restrict__ cursor, int* __restrict__ gstart, int* __restrict__ gcnt){
    int i = blockIdx.x*256 + threadIdx.x;
    if (i < N_NODES) cursor[i] = 0;
    if (i < NB){ gstart[i] = 0x7fffffff; gcnt[i] = 0; }
}

__global__ void k_embed(const int* __restrict__ x, const float* __restrict__ emb, uint16_t* __restrict__ h){
    int i = blockIdx.x; int c = threadIdx.x;
    h[(size_t)i*HIDDEN + c] = to_b16(emb[x[i]*HIDDEN + c]);
}

__global__ void k_deg(const int* __restrict__ dst, int* __restrict__ cursor){
    int e = blockIdx.x*256 + threadIdx.x;
    if (e < N_EDGES) atomicAdd(&cursor[dst[e]], 1);
}

__global__ void k_meta(const int* __restrict__ batch, int* __restrict__ gstart, int* __restrict__ gcnt){
    int i = blockIdx.x*256 + threadIdx.x;
    if (i < N_NODES){ int b = batch[i]; atomicMin(&gstart[b], i); atomicAdd(&gcnt[b], 1); }
}

__global__ __launch_bounds__(1024) void k_scan(int* __restrict__ cursor, int* __restrict__ offs){
    __shared__ int part[1024];
    const int tid = threadIdx.x;
    const int CH = N_NODES/1024; // 48
    int local[48];
    int s = 0;
    int base = tid*CH;
    for (int j=0;j<CH;j++){ local[j] = cursor[base+j]; s += local[j]; }
    part[tid] = s;
    __syncthreads();
    for (int off=1; off<1024; off<<=1){
        int v = (tid>=off) ? part[tid-off] : 0;
        __syncthreads();
        part[tid] += v;
        __syncthreads();
    }
    int excl = (tid==0) ? 0 : part[tid-1];
    for (int j=0;j<CH;j++){ offs[base+j] = excl; excl += local[j]; cursor[base+j] = 0; }
    if (tid == 1023) offs[N_NODES] = excl;
}

__global__ void k_scatter(const int* __restrict__ src, const int* __restrict__ dst, const int* __restrict__ attr,
                          const int* __restrict__ offs, int* __restrict__ cursor, int* __restrict__ epack){
    int e = blockIdx.x*256 + threadIdx.x;
    if (e < N_EDGES){
        int d = dst[e];
        int pos = atomicAdd(&cursor[d], 1);
        epack[offs[d] + pos] = (src[e] & 0xffff) | (attr[e] << 16);
    }
}

// ---------------- message aggregation: wave-per-node, 4-edge MLP chunks ----------------

__global__ __launch_bounds__(256) void k_aggr(const uint16_t* __restrict__ h, const float* __restrict__ eemb,
                                              const int* __restrict__ offs, const int* __restrict__ epack,
                                              uint16_t* __restrict__ t){
    __shared__ float sE[NEF_*HIDDEN];
    const int tid  = threadIdx.x;
    #pragma unroll
    for (int q=0;q<NEF_;q++) sE[q*256 + tid] = eemb[q*256 + tid];
    __syncthreads();

    const int wave = tid >> 6;
    const int lane = tid & 63;
    const int node = blockIdx.x*4 + wave;
    const int c4   = lane*4;

    uint2 hu = *(const uint2*)(h + (size_t)node*HIDDEN + c4);
    float4 acc;
    acc.x = __uint_as_float(hu.x << 16);
    acc.y = __uint_as_float(hu.x & 0xffff0000u);
    acc.z = __uint_as_float(hu.y << 16);
    acc.w = __uint_as_float(hu.y & 0xffff0000u);

    const int e0 = offs[node], e1 = offs[node+1];
    for (int j = e0; j < e1; j += 4){
        int p0 = epack[j];
        int p1 = (j+1 < e1) ? epack[j+1] : p0;
        int p2 = (j+2 < e1) ? epack[j+2] : p0;
        int p3 = (j+3 < e1) ? epack[j+3] : p0;
        uint2 g0 = *(const uint2*)(h + (size_t)(p0 & 0xffff)*HIDDEN + c4);
        uint2 g1 = *(const uint2*)(h + (size_t)(p1 & 0xffff)*HIDDEN + c4);
        uint2 g2 = *(const uint2*)(h + (size_t)(p2 & 0xffff)*HIDDEN + c4);
        uint2 g3 = *(const uint2*)(h + (size_t)(p3 & 0xffff)*HIDDEN + c4);
        {
            const float4 ev = *(const float4*)&sE[(p0 >> 16)*HIDDEN + c4];
            acc.x += fmaxf(__uint_as_float(g0.x << 16)        + ev.x, 0.f);
            acc.y += fmaxf(__uint_as_float(g0.x & 0xffff0000u) + ev.y, 0.f);
            acc.z += fmaxf(__uint_as_float(g0.y << 16)        + ev.z, 0.f);
            acc.w += fmaxf(__uint_as_float(g0.y & 0xffff0000u) + ev.w, 0.f);
        }
        if (j+1 < e1){
            const float4 ev = *(const float4*)&sE[(p1 >> 16)*HIDDEN + c4];
            acc.x += fmaxf(__uint_as_float(g1.x << 16)        + ev.x, 0.f);
            acc.y += fmaxf(__uint_as_float(g1.x & 0xffff0000u) + ev.y, 0.f);
            acc.z += fmaxf(__uint_as_float(g1.y << 16)        + ev.z, 0.f);
            acc.w += fmaxf(__uint_as_float(g1.y & 0xffff0000u) + ev.w, 0.f);
        }
        if (j+2 < e1){
            const float4 ev = *(const float4*)&sE[(p2 >> 16)*HIDDEN + c4];
            acc.x += fmaxf(__uint_as_float(g2.x << 16)        + ev.x, 0.f);
            acc.y += fmaxf(__uint_as_float(g2.x & 0xffff0000u) + ev.y, 0.f);
            acc.z += fmaxf(__uint_as_float(g2.y << 16)        + ev.z, 0.f);
            acc.w += fmaxf(__uint_as_float(g2.y & 0xffff0000u) + ev.w, 0.f);
        }
        if (j+3 < e1){
            const float4 ev = *(const float4*)&sE[(p3 >> 16)*HIDDEN + c4];
            acc.x += fmaxf(__uint_as_float(g3.x << 16)        + ev.x, 0.f);
            acc.y += fmaxf(__uint_as_float(g3.x & 0xffff0000u) + ev.y, 0.f);
            acc.z += fmaxf(__uint_as_float(g3.y << 16)        + ev.z, 0.f);
            acc.w += fmaxf(__uint_as_float(g3.y & 0xffff0000u) + ev.w, 0.f);
        }
    }

    uint2 o;
    o.x = (uint32_t)to_b16(acc.x) | ((uint32_t)to_b16(acc.y) << 16);
    o.y = (uint32_t)to_b16(acc.z) | ((uint32_t)to_b16(acc.w) << 16);
    *(uint2*)(t + (size_t)node*HIDDEN + c4) = o;
}

// ---------------- fused weight / activation converter (single launch) ----------------
// conv weights packed into [kc][out][8] streaming chunks (16KB each).
// flow weights packed into [flow][kc][hi|lo][(lq*256+col)*8] chunks (32KB each,
// hi half then lo half) so flows can stream them via global_load_lds too.

#define CVT_TOTAL 4408320

__global__ void k_cvt_all(
    const float* __restrict__ conv_w1, const float* __restrict__ conv_w2,
    const float* __restrict__ mu_w, const float* __restrict__ mu_b,
    const float* __restrict__ lv_w, const float* __restrict__ lv_b,
    const float* __restrict__ fw1, const float* __restrict__ fw2,
    const float* __restrict__ dn_w1, const float* __restrict__ dn_w2,
    const float* __restrict__ de_w1, const float* __restrict__ de_w2,
    uint16_t* __restrict__ cw1b, uint16_t* __restrict__ cw2b,
    uint32_t* __restrict__ mvwpk, float* __restrict__ mvb,
    uint16_t* __restrict__ w1p, uint16_t* __restrict__ w2p,
    uint16_t* __restrict__ dnw1b, uint16_t* __restrict__ dnw2b,
    uint16_t* __restrict__ dew1b, uint16_t* __restrict__ dew2b)
{
    int i = blockIdx.x*256 + threadIdx.x;
    if (i < 262144){
        int o = (i >> 8) & 255, k = i & 255;
        int dst = (i & ~65535) | ((k >> 3) << 11) | (o << 3) | (k & 7);
        cw1b[dst] = to_b16(conv_w1[i]);
        return;
    }
    i -= 262144;
    if (i < 262144){
        int o = (i >> 8) & 255, k = i & 255;
        int dst = (i & ~65535) | ((k >> 3) << 11) | (o << 3) | (k & 7);
        cw2b[dst] = to_b16(conv_w2[i]);
        return;
    }
    i -= 262144;
    if (i < 65536){
        int o = i >> 8, k2 = i & 255;
        float v = (o < 128) ? mu_w[o*256 + k2] : lv_w[(o-128)*256 + k2];
        mvwpk[i] = pack_hl(v);
        if (i < 256) mvb[i] = (i < 128) ? mu_b[i] : lv_b[i-128];
        return;
    }
    i -= 65536;
    if (i < 131072){
        int flow = i >> 15;
        int o  = (i >> 7) & 255;
        int kk = i & 127;
        float v = (kk <= (o % 127)) ? fw1[i] : 0.f;
        uint32_t h = bf16_rne_bits(v);
        int kc = kk >> 5, lq = (kk >> 3) & 3, e = kk & 7;
        size_t dst = (size_t)flow*65536 + (size_t)kc*16384 + (size_t)(lq*256 + o)*8 + e;
        w1p[dst]        = (uint16_t)(h >> 16);
        w1p[dst + 8192] = (uint16_t)(bf16_rne_bits(v - __uint_as_float(h)) >> 16);
        return;
    }
    i -= 131072;
    if (i < 262144){
        int flow = i >> 16;
        int o  = (i >> 8) & 255;
        int hh = i & 255;
        float v = ((hh % 127) < (o & 127)) ? fw2[i] : 0.f;
        uint32_t h = bf16_rne_bits(v);
        int kc = hh >> 5, lq = (hh >> 3) & 3, e = hh & 7;
        size_t dst = (size_t)flow*131072 + (size_t)kc*16384 + (size_t)(lq*256 + o)*8 + e;
        w2p[dst]        = (uint16_t)(h >> 16);
        w2p[dst + 8192] = (uint16_t)(bf16_rne_bits(v - __uint_as_float(h)) >> 16);
        return;
    }
    i -= 262144;
    if (i < 32768){ dnw1b[i] = to_b16(dn_w1[i]); return; }
    i -= 32768;
    if (i < 369664){ dnw2b[i] = to_b16(dn_w2[i]); return; }
    i -= 369664;
    if (i < 65536){ dew1b[i] = to_b16(de_w1[i]); return; }
    i -= 65536;
    if (i < 2957312){ dew2b[i] = to_b16(de_w2[i]); }
}

// ---------------- fused conv v4: LDS-streamed weights (contiguous staging) ----------------

__global__ __launch_bounds__(256) void k_conv2(
    const uint16_t* __restrict__ A,
    const uint16_t* __restrict__ W1p, const float* __restrict__ B1,
    const uint16_t* __restrict__ W2p, const float* __restrict__ B2,
    uint16_t* __restrict__ C)
{
    extern __shared__ __align__(16) char smem[];
    const int tid  = threadIdx.x;
    const int wave = tid >> 6;
    const int lane = tid & 63;
    const int l15  = lane & 15;
    const int lq   = lane >> 4;
    const int l7   = lane & 7;
    const int row0 = blockIdx.x * 64;
    char* wb0 = smem + 32768;
    char* wb1 = smem + 32768 + 16384;

    #define STAGE_W(Wp, kc, wb)                                              \
        { _Pragma("unroll")                                                  \
          for (int it=0; it<4; ++it){                                        \
            int s = it*256 + tid;                                            \
            __builtin_amdgcn_global_load_lds(                                \
                (const __attribute__((address_space(1))) uint32_t*)          \
                    ((const char*)(Wp) + (size_t)(kc)*16384 + (size_t)s*16), \
                (__attribute__((address_space(3))) uint32_t*)((wb) + s*16),  \
                16, 0, 0);                                                   \
          } }

    #pragma unroll
    for (int it = 0; it < 8; ++it) {
        int s  = it*256 + tid;
        int m  = s >> 5;
        int gl = (s & 31) ^ (m & 7);
        const char* gp = (const char*)A + ((size_t)(row0+m)*HIDDEN)*2 + gl*16;
        __builtin_amdgcn_global_load_lds(
            (const __attribute__((address_space(1))) uint32_t*)gp,
            (__attribute__((address_space(3))) uint32_t*)(smem + (size_t)s*16),
            16, 0, 0);
    }
    STAGE_W(W1p, 0, wb0);
    __syncthreads();

    f32x4 acc[4][4];
    #pragma unroll
    for (int mt=0;mt<4;mt++)
        #pragma unroll
        for (int nt=0;nt<4;nt++) acc[mt][nt] = (f32x4)(0.f);

    #pragma unroll
    for (int kc = 0; kc < 8; ++kc){
        char* rdb = (kc & 1) ? wb1 : wb0;
        if (kc < 7){ char* stb = (kc & 1) ? wb0 : wb1; STAGE_W(W1p, kc+1, stb); }
        bf16x8 bw[4];
        #pragma unroll
        for (int nt=0;nt<4;nt++)
            bw[nt] = *(const bf16x8*)(rdb + (size_t)((lq*256 + wave*64 + nt*16 + l15)) * 16);
        #pragma unroll
        for (int mt=0;mt<4;mt++){
            const int mb = (mt*16 + l15) << 5;
            int g = kc*4 + lq;
            bf16x8 a = *(const bf16x8*)(smem + (size_t)(mb + (g ^ l7))*16);
            #pragma unroll
            for (int nt=0;nt<4;nt++)
                acc[mt][nt] = MFMA16(a, bw[nt], acc[mt][nt], 0, 0, 0);
        }
        __syncthreads();
    }

    STAGE_W(W2p, 0, wb0);
    uint16_t* h1 = (uint16_t*)smem;
    #pragma unroll
    for (int mt=0;mt<4;mt++){
        #pragma unroll
        for (int nt=0;nt<4;nt++){
            int col = wave*64 + nt*16 + l15;
            float bb = B1[col];
            #pragma unroll
            for (int reg=0;reg<4;reg++){
                int r = mt*16 + lq*4 + reg;
                float v = fmaxf(acc[mt][nt][reg] + bb, 0.f);
                h1[(r*32 + ((col>>3) ^ (r&7)))*8 + (col&7)] = to_b16(v);
            }
        }
    }
    __syncthreads();

    #pragma unroll
    for (int mt=0;mt<4;mt++)
        #pragma unroll
        for (int nt=0;nt<4;nt++) acc[mt][nt] = (f32x4)(0.f);

    #pragma unroll
    for (int kc = 0; kc < 8; ++kc){
        char* rdb = (kc & 1) ? wb1 : wb0;
        if (kc < 7){ char* stb = (kc & 1) ? wb0 : wb1; STAGE_W(W2p, kc+1, stb); }
        bf16x8 bw[4];
        #pragma unroll
        for (int nt=0;nt<4;nt++)
            bw[nt] = *(const bf16x8*)(rdb + (size_t)((lq*256 + wave*64 + nt*16 + l15)) * 16);
        #pragma unroll
        for (int mt=0;mt<4;mt++){
            int m = mt*16 + l15;
            bf16x8 a = *(const bf16x8*)(h1 + (size_t)(m*32 + ((kc*4 + lq) ^ (m & 7)))*8);
            #pragma unroll
            for (int nt=0;nt<4;nt++)
                acc[mt][nt] = MFMA16(a, bw[nt], acc[mt][nt], 0, 0, 0);
        }
        __syncthreads();
    }

    uint16_t* rs = (uint16_t*)smem;
    #pragma unroll
    for (int mt=0;mt<4;mt++){
        #pragma unroll
        for (int nt=0;nt<4;nt++){
            int col = wave*64 + nt*16 + l15;
            float bb = B2[col];
            #pragma unroll
            for (int reg=0;reg<4;reg++){
                int r = mt*16 + lq*4 + reg;
                float v = fmaxf(acc[mt][nt][reg] + bb, 0.f);
                rs[(r*32 + ((col>>3) ^ (r&7)))*8 + (col&7)] = to_b16(v);
            }
        }
    }
    BARRIER();

    #pragma unroll
    for (int it = 0; it < 8; ++it){
        int s   = it*256 + tid;
        int row = s >> 5;
        int gc  = s & 31;
        uint4 d = *(const uint4*)(smem + (size_t)(row*32 + (gc ^ (row & 7)))*16);
        *(uint4*)(C + (size_t)(row0+row)*HIDDEN + gc*8) = d;
    }
    #undef STAGE_W
}

// ---------------- MFMA GEMM (mu/lv + decoders) ----------------

template<int SPLIT, int OUTM>
__global__ __launch_bounds__(256) void mfma_gemm(
    const void* __restrict__ Ap, const void* __restrict__ Wp,
    const float* __restrict__ bias, void* __restrict__ Cp,
    int M, int N, int K, int relu)
{
    extern __shared__ __align__(16) char smem[];
    const int tid  = threadIdx.x;
    const int wave = tid >> 6;
    const int lane = tid & 63;
    const int l15  = lane & 15;
    const int lq   = lane >> 4;
    const int l7   = lane & 7;
    const int row0 = blockIdx.y * 64;
    const int n0   = blockIdx.x * 256;
    const int ELB  = SPLIT ? 4 : 2;
    const int KC   = (K < 256) ? K : 256;
    const int GR   = (KC * ELB) >> 4;
    const int rsh  = (GR == 64) ? 6 : ((GR == 32) ? 5 : 4);

    f32x4 acc[4][4];
    #pragma unroll
    for (int mt=0;mt<4;mt++)
        #pragma unroll
        for (int nt=0;nt<4;nt++) acc[mt][nt] = (f32x4)(0.f);

    const char* Ab = (const char*)Ap;
    const char* Wb = (const char*)Wp;

    for (int kbase = 0; kbase < K; kbase += KC) {
        const int rounds = GR >> 2;
        for (int it = 0; it < rounds; ++it) {
            int sbase = it*256 + wave*64;
            int s  = sbase + lane;
            int m  = s >> rsh;
            int gl = (s & (GR-1)) ^ (m & 7);
            const char* gp = Ab + ((size_t)(row0+m)*K + kbase)*ELB + gl*16;
            __builtin_amdgcn_global_load_lds(
                (const __attribute__((address_space(1))) uint32_t*)gp,
                (__attribute__((address_space(3))) uint32_t*)(smem + sbase*16),
                16, 0, 0);
        }
        __syncthreads();

        for (int kc = 0; kc < (KC >> 5); ++kc) {
            bf16x8 bhi[4], blo[4];
            #pragma unroll
            for (int nt=0;nt<4;nt++){
                int n = n0 + wave*64 + nt*16 + l15;
                if (n >= N) n = N-1;
                if (SPLIT){
                    const uint4* wp4 = (const uint4*)(Wb + ((size_t)n*K + kbase + kc*32 + lq*8)*4);
                    uint4 xx = wp4[0], yy = wp4[1];
                    unpack_frag(xx, yy, bhi[nt], blo[nt]);
                } else {
                    bhi[nt] = *(const bf16x8*)(Wb + ((size_t)n*K + kbase + kc*32 + lq*8)*2);
                }
            }
            #pragma unroll
            for (int mt=0;mt<4;mt++){
                const int mb = (mt*16 + l15) << rsh;
                if (SPLIT){
                    int g0 = kc*8 + lq*2;
                    uint4 xx = *(const uint4*)(smem + (size_t)(mb + ((g0  ) ^ l7))*16);
                    uint4 yy = *(const uint4*)(smem + (size_t)(mb + ((g0+1) ^ l7))*16);
                    bf16x8 ahi, alo;
                    unpack_frag(xx, yy, ahi, alo);
                    #pragma unroll
                    for (int nt=0;nt<4;nt++){
                        acc[mt][nt] = MFMA16(ahi, bhi[nt], acc[mt][nt], 0, 0, 0);
                        acc[mt][nt] = MFMA16(ahi, blo[nt], acc[mt][nt], 0, 0, 0);
                        acc[mt][nt] = MFMA16(alo, bhi[nt], acc[mt][nt], 0, 0, 0);
                    }
                } else {
                    int g = kc*4 + lq;
                    bf16x8 a = *(const bf16x8*)(smem + (size_t)(mb + (g ^ l7))*16);
                    #pragma unroll
                    for (int nt=0;nt<4;nt++){
                        acc[mt][nt] = MFMA16(a, bhi[nt], acc[mt][nt], 0, 0, 0);
                    }
                }
            }
        }
        __syncthreads();
    }

    const int ES = (OUTM == 1) ? 2 : 4;
    char* rs = smem + wave*(64*64*ES);
    const int colbase = n0 + wave*64;
    #pragma unroll
    for (int mt=0;mt<4;mt++){
        #pragma unroll
        for (int nt=0;nt<4;nt++){
            int cl = nt*16 + l15;
            int col = colbase + cl;
            float bb = bias[col < N ? col : N-1];
            #pragma unroll
            for (int reg=0;reg<4;reg++){
                int r = mt*16 + lq*4 + reg;
                float v = acc[mt][nt][reg] + bb;
                if (relu) v = fmaxf(v, 0.f);
                if (OUTM == 1) ((uint16_t*)rs)[r*64 + cl] = to_b16(v);
                else           ((float*)rs)[r*64 + cl] = v;
            }
        }
    }
    __syncthreads();
    for (int it = 0; it < 32; ++it) {
        int r   = it*2 + (lane>>5);
        int clp = lane & 31;
        int col = colbase + clp*2;
        if (col < N){
            if (OUTM == 1){
                uint32_t d = *(const uint32_t*)((const uint16_t*)rs + r*64 + clp*2);
                *(uint32_t*)((char*)Cp + ((size_t)(row0+r)*N + col)*2) = d;
            } else {
                float2 d = *(const float2*)((const float*)rs + r*64 + clp*2);
                *(float2*)((float*)Cp + (size_t)(row0+r)*N + col) = d;
            }
        }
    }
}

// ---------------- pooling + z0 elementwise ----------------

__global__ void k_pool(const uint16_t* __restrict__ h, const int* __restrict__ gstart,
                       const int* __restrict__ gcnt, uint32_t* __restrict__ hg){
    int b = blockIdx.x; int c = threadIdx.x;
    int s0 = gstart[b]; int n = gcnt[b];
    float s = 0.f;
    for (int j=0;j<n;j++) s += from_b16(h[(size_t)(s0+j)*HIDDEN + c]);
    hg[(size_t)b*HIDDEN + c] = pack_hl(s);
}

__global__ void k_z0(const float* __restrict__ mv, const float* __restrict__ eps,
                     float* __restrict__ mu_o, float* __restrict__ lv_o, float* __restrict__ z0_o){
    int i = blockIdx.x*256 + threadIdx.x;
    if (i >= NB*LAT) return;
    int b = i >> 7, l = i & 127;
    float m = mv[(size_t)b*256 + l];
    float v = mv[(size_t)b*256 + l + 128];
    mu_o[i] = m;
    lv_o[i] = v;
    z0_o[i] = m + eps[i]*expf(0.5f*v);
}

// ---------------- fused MFMA flows v7: LDS-streamed packed weights ----------------
// 128 blocks x 1024 threads (16 waves); 16 graphs/block; wave w owns cols
// [16w,16w+16). Weights stream as 32KB fragment-order chunks (hi half + lo
// half) through a 64KB LDS double buffer via global_load_lds (coalesced),
// replacing v6's per-lane scattered loads (the conv2-proven fix). 48 chunks
// per block = the full 1.5MB weight set; one __syncthreads per chunk.
// Static LDS ~107KB -> 1 block/CU, 16 waves.

__global__ __launch_bounds__(1024) void k_flows_mfma7(
    const float* __restrict__ z0,
    const uint16_t* __restrict__ w1p, const float* __restrict__ fb1,
    const uint16_t* __restrict__ w2p, const float* __restrict__ fb2,
    float* __restrict__ zK, uint16_t* __restrict__ zkb, float* __restrict__ sld)
{
    __shared__ __align__(16) uint16_t zhi[16][136];
    __shared__ __align__(16) uint16_t zlo[16][136];
    __shared__ __align__(16) uint16_t h1hi[16][280];
    __shared__ __align__(16) uint16_t h1lo[16][280];
    __shared__ __align__(16) float    oS[16][268];
    __shared__ __align__(16) uint16_t wbuf[2][16384];   // 2 x 32KB chunk dbuf
    const int tid  = threadIdx.x;
    const int wave = tid >> 6;
    const int lane = tid & 63;
    const int l15  = lane & 15;
    const int lq   = lane >> 4;
    const int g0   = blockIdx.x * 16;
    const int col  = wave*16 + l15;
    const int fo   = (lq*256 + col)*8;      // hi-frag elem offset in chunk

    // stage one 32KB chunk: 2 rounds x 1024 threads x 16B
    #define STAGE_C(srcp, buf)                                               \
        { _Pragma("unroll")                                                  \
          for (int it=0; it<2; ++it){                                        \
            int s = it*1024 + tid;                                           \
            __builtin_amdgcn_global_load_lds(                                \
                (const __attribute__((address_space(1))) uint32_t*)          \
                    ((const char*)(srcp) + (size_t)s*16),                    \
                (__attribute__((address_space(3))) uint32_t*)                \
                    ((char*)&wbuf[buf][0] + (size_t)s*16),                   \
                16, 0, 0);                                                   \
          } }

    int pb = 0;
    STAGE_C(w1p, 0);   // flow 0, W1 chunk 0

    // z0 staging (hi/lo split): 2048 elems
    #pragma unroll
    for (int q=0;q<2;q++){
        int idx = q*1024 + tid;
        int r = idx >> 7, l = idx & 127;
        float v = z0[(size_t)(g0 + r)*LAT + l];
        uint32_t h = bf16_rne_bits(v);
        zhi[r][l] = (uint16_t)(h >> 16);
        zlo[r][l] = (uint16_t)(bf16_rne_bits(v - __uint_as_float(h)) >> 16);
    }
    float ldacc = 0.f;
    __syncthreads();

    for (int kf=0; kf<NFLOWS; kf++){
        const uint16_t* W1f = w1p + (size_t)kf*65536;
        const uint16_t* W2f = w2p + (size_t)kf*131072;

        // ---- GEMM1: h1 = relu(z @ W1^T + b1), 4 chunks ----
        f32x4 acc = (f32x4)(0.f);
        #pragma unroll
        for (int kc=0;kc<4;kc++){
            const uint16_t* nxt = (kc < 3) ? (W1f + (size_t)(kc+1)*16384) : W2f;
            STAGE_C(nxt, pb^1);
            bf16x8 wh = *(const bf16x8*)&wbuf[pb][fo];
            bf16x8 wl = *(const bf16x8*)&wbuf[pb][fo + 8192];
            bf16x8 ah = *(const bf16x8*)&zhi[l15][kc*32 + lq*8];
            bf16x8 al = *(const bf16x8*)&zlo[l15][kc*32 + lq*8];
            acc = MFMA16(ah, wh, acc, 0, 0, 0);
            acc = MFMA16(ah, wl, acc, 0, 0, 0);
            acc = MFMA16(al, wh, acc, 0, 0, 0);
            __syncthreads();
            pb ^= 1;
        }
        {
            float bb = fb1[kf*FHID + col];
            #pragma unroll
            for (int reg=0;reg<4;reg++){
                int r = lq*4 + reg;
                float v = fmaxf(acc[reg] + bb, 0.f);
                uint32_t h = bf16_rne_bits(v);
                h1hi[r][col] = (uint16_t)(h >> 16);
                h1lo[r][col] = (uint16_t)(bf16_rne_bits(v - __uint_as_float(h)) >> 16);
            }
        }
        BARRIER();   // h1 visible (W2 chunk0 already staged+drained)

        // ---- GEMM2: out = h1 @ W2^T + b2, 8 chunks ----
        f32x4 a2 = (f32x4)(0.f);
        #pragma unroll
        for (int kc=0;kc<8;kc++){
            if (kc < 7){
                STAGE_C(W2f + (size_t)(kc+1)*16384, pb^1);
            } else if (kf < NFLOWS-1){
                STAGE_C(w1p + (size_t)(kf+1)*65536, pb^1);
            }
            bf16x8 wh = *(const bf16x8*)&wbuf[pb][fo];
            bf16x8 wl = *(const bf16x8*)&wbuf[pb][fo + 8192];
            bf16x8 ah = *(const bf16x8*)&h1hi[l15][kc*32 + lq*8];
            bf16x8 al = *(const bf16x8*)&h1lo[l15][kc*32 + lq*8];
            a2 = MFMA16(ah, wh, a2, 0, 0, 0);
            a2 = MFMA16(ah, wl, a2, 0, 0, 0);
            a2 = MFMA16(al, wh, a2, 0, 0, 0);
            __syncthreads();
            pb ^= 1;
        }
        {
            float bb = fb2[kf*2*LAT + col];
            #pragma unroll
            for (int reg=0;reg<4;reg++)
                oS[lq*4 + reg][col] = a2[reg] + bb;
        }
        BARRIER();

        // ---- z update + log-det: wave w handles row w, 2 cols/lane ----
        {
            const int r = wave;
            float ldp = 0.f;
            #pragma unroll
            for (int j=0;j<2;j++){
                int l = lane + j*64;
                float m = oS[r][l];
                float s = oS[r][l + 128];
                float g = 1.f/(1.f + expf(-s));
                float zv = __uint_as_float((uint32_t)zhi[r][l] << 16)
                         + __uint_as_float((uint32_t)zlo[r][l] << 16);
                float zn = g*zv + (1.f - g)*m;
                uint32_t h = bf16_rne_bits(zn);
                zhi[r][l] = (uint16_t)(h >> 16);
                zlo[r][l] = (uint16_t)(bf16_rne_bits(zn - __uint_as_float(h)) >> 16);
                ldp += logf(g + 1e-8f);
            }
            #pragma unroll
            for (int off=1; off<64; off<<=1) ldp += __shfl_xor(ldp, off);
            ldacc += ldp;
        }
        BARRIER();
    }

    #pragma unroll
    for (int q=0;q<2;q++){
        int idx = q*1024 + tid;
        int r = idx >> 7, l = idx & 127;
        uint32_t h = (uint32_t)zhi[r][l] << 16;
        float zv = __uint_as_float(h) + __uint_as_float((uint32_t)zlo[r][l] << 16);
        zK[(size_t)(g0+r)*LAT + l] = zv;
        zkb[(size_t)(g0+r)*LAT + l] = (uint16_t)(h >> 16);
    }
    if (lane == 0) sld[g0 + wave] = ldacc;
    #undef STAGE_C
}

// ---------------- edge-logits symmetrize ----------------

__global__ void k_sym(const float* __restrict__ raw, float* __restrict__ outp){
    int idx = blockIdx.x*256 + threadIdx.x;
    const int total = NB*MA*MA;
    if (idx >= total) return;
    int b = idx / (MA*MA);
    int rem = idx - b*(MA*MA);
    int i = rem / MA;
    int j = rem - i*MA;
    const size_t base = (size_t)b*(MA*MA*NEF_);
    const float4 a  = *(const float4*)(raw + base + (size_t)(i*MA + j)*NEF_);
    const float4 bt = *(const float4*)(raw + base + (size_t)(j*MA + i)*NEF_);
    float4 r;
    r.x = (a.x + bt.x)*0.5f;
    r.y = (a.y + bt.y)*0.5f;
    r.z = (a.z + bt.z)*0.5f;
    r.w = (a.w + bt.w)*0.5f;
    *(float4*)(outp + base + (size_t)(i*MA + j)*NEF_) = r;
}

// ---------------- launch ----------------

extern "C" void kernel_launch(void* const* d_in, const int* in_sizes, int n_in,
                              void* d_out, int out_size, void* d_ws, size_t ws_size,
                              hipStream_t stream){
    (void)in_sizes; (void)n_in; (void)out_size; (void)ws_size;
    const int*   x        = (const int*)d_in[0];
    const int*   eidx     = (const int*)d_in[1];
    const int*   eattr    = (const int*)d_in[2];
    const int*   batch    = (const int*)d_in[3];
    const float* eps      = (const float*)d_in[4];
    const float* node_emb = (const float*)d_in[5];
    const float* edge_emb = (const float*)d_in[6];
    const float* conv_w1  = (const float*)d_in[7];
    const float* conv_b1  = (const float*)d_in[8];
    const float* conv_w2  = (const float*)d_in[9];
    const float* conv_b2  = (const float*)d_in[10];
    const float* mu_w     = (const float*)d_in[11];
    const float* mu_b     = (const float*)d_in[12];
    const float* lv_w     = (const float*)d_in[13];
    const float* lv_b     = (const float*)d_in[14];
    const float* fw1      = (const float*)d_in[15];
    const float* fb1      = (const float*)d_in[16];
    const float* fw2      = (const float*)d_in[17];
    const float* fb2      = (const float*)d_in[18];
    const float* dn_w1    = (const float*)d_in[19];
    const float* dn_b1    = (const float*)d_in[20];
    const float* dn_w2    = (const float*)d_in[21];
    const float* dn_b2    = (const float*)d_in[22];
    const float* de_w1    = (const float*)d_in[23];
    const float* de_b1    = (const float*)d_in[24];
    const float* de_w2    = (const float*)d_in[25];
    const float* de_b2    = (const float*)d_in[26];

    float* out = (float*)d_out;
    const size_t off_node = 0;
    const size_t off_edge = (size_t)NB*MA*NNF_;
    const size_t off_mu   = off_edge + (size_t)NB*MA*MA*NEF_;
    const size_t off_lv   = off_mu + (size_t)NB*LAT;
    const size_t off_z0   = off_lv + (size_t)NB*LAT;
    const size_t off_zk   = off_z0 + (size_t)NB*LAT;
    const size_t off_sld  = off_zk + (size_t)NB*LAT;
    (void)off_node;

    char* p = (char*)d_ws;
    auto alloc = [&](size_t bytes)->char*{ char* r = p; p += (bytes + 255) & ~(size_t)255; return r; };
    uint16_t* h_b   = (uint16_t*)alloc((size_t)N_NODES*HIDDEN*2);
    uint16_t* t_b   = (uint16_t*)alloc((size_t)N_NODES*HIDDEN*2);
    int*   offs   = (int*)  alloc((size_t)(N_NODES+1)*4);
    int*   cursor = (int*)  alloc((size_t)N_NODES*4);
    int*   epack  = (int*)  alloc((size_t)N_EDGES*4);
    int*   gstart = (int*)  alloc((size_t)NB*4);
    int*   gcnt   = (int*)  alloc((size_t)NB*4);
    uint32_t* hg_pk = (uint32_t*)alloc((size_t)NB*HIDDEN*4);
    float* mv       = (float*)alloc((size_t)NB*256*4);
    uint16_t* cw1b  = (uint16_t*)alloc((size_t)4*HIDDEN*HIDDEN*2);
    uint16_t* cw2b  = (uint16_t*)alloc((size_t)4*HIDDEN*HIDDEN*2);
    uint32_t* mvwpk = (uint32_t*)alloc((size_t)256*256*4);
    float*    mvb   = (float*)  alloc((size_t)256*4);
    uint16_t* w1p   = (uint16_t*)alloc((size_t)NFLOWS*65536*2);
    uint16_t* w2p   = (uint16_t*)alloc((size_t)NFLOWS*131072*2);
    uint16_t* dnw1b = (uint16_t*)alloc((size_t)256*LAT*2);
    uint16_t* dnw2b = (uint16_t*)alloc((size_t)MA*NNF_*256*2);
    uint16_t* dew1b = (uint16_t*)alloc((size_t)512*LAT*2);
    uint16_t* dew2b = (uint16_t*)alloc((size_t)MA*MA*NEF_*512*2);
    uint16_t* zkb   = (uint16_t*)alloc((size_t)NB*LAT*2);
    uint16_t* hnb   = (uint16_t*)alloc((size_t)NB*256*2);
    uint16_t* heb   = (uint16_t*)alloc((size_t)NB*512*2);
    float* edge_raw = (float*)alloc((size_t)NB*MA*MA*NEF_*4);

    const int* esrc = eidx;
    const int* edst = eidx + N_EDGES;

    k_cvt_all<<<(CVT_TOTAL+255)/256, 256, 0, stream>>>(
        conv_w1, conv_w2, mu_w, mu_b, lv_w, lv_b, fw1, fw2,
        dn_w1, dn_w2, de_w1, de_w2,
        cw1b, cw2b, mvwpk, mvb, w1p, w2p,
        dnw1b, dnw2b, dew1b, dew2b);

    k_init   <<<(N_NODES+255)/256, 256, 0, stream>>>(cursor, gstart, gcnt);
    k_embed  <<<N_NODES, HIDDEN, 0, stream>>>(x, node_emb, h_b);
    k_deg    <<<(N_EDGES+255)/256, 256, 0, stream>>>(edst, cursor);
    k_meta   <<<(N_NODES+255)/256, 256, 0, stream>>>(batch, gstart, gcnt);
    k_scan   <<<1, 1024, 0, stream>>>(cursor, offs);
    k_scatter<<<(N_EDGES+255)/256, 256, 0, stream>>>(esrc, edst, eattr, offs, cursor, epack);

    const size_t SM32 = 32768, SM64 = 65536;
    for (int k=0;k<4;k++){
        k_aggr<<<N_NODES/4, 256, 0, stream>>>(h_b, edge_emb, offs, epack, t_b);
        k_conv2<<<N_NODES/64, 256, SM64, stream>>>(
            t_b,
            cw1b + (size_t)k*HIDDEN*HIDDEN, conv_b1 + (size_t)k*HIDDEN,
            cw2b + (size_t)k*HIDDEN*HIDDEN, conv_b2 + (size_t)k*HIDDEN,
            h_b);
    }

    k_pool<<<NB, HIDDEN, 0, stream>>>(h_b, gstart, gcnt, hg_pk);
    mfma_gemm<1,2><<<dim3(1, NB/64), 256, SM64, stream>>>(hg_pk, mvwpk, mvb, mv, NB, 256, HIDDEN, 0);
    k_z0<<<(NB*LAT+255)/256, 256, 0, stream>>>(mv, eps, out+off_mu, out+off_lv, out+off_z0);

    k_flows_mfma7<<<NB/16, 1024, 0, stream>>>(out+off_z0, w1p, fb1, w2p, fb2,
                                              out+off_zk, zkb, out+off_sld);

    mfma_gemm<0,1><<<dim3(1, NB/64), 256, SM32, stream>>>(zkb, dnw1b, dn_b1, hnb, NB, 256, LAT, 1);
    mfma_gemm<0,2><<<dim3(6, NB/64), 256, SM64, stream>>>(hnb, dnw2b, dn_b2, out+off_node, NB, MA*NNF_, 256, 0);
    mfma_gemm<0,1><<<dim3(2, NB/64), 256, SM32, stream>>>(zkb, dew1b, de_b1, heb, NB, 512, LAT, 1);
    mfma_gemm<0,2><<<dim3(23, NB/64), 256, SM64, stream>>>(heb, dew2b, de_b2, edge_raw, NB, MA*MA*NEF_, 512, 0);
    k_sym<<<(NB*MA*MA + 255)/256, 256, 0, stream>>>(edge_raw, out + off_edge);
}

// Round 7
// 547.016 us; speedup vs baseline: 1.5728x; 1.0562x over previous
//
#include <hip/hip_runtime.h>
#include <hip/hip_bf16.h>
#include <math.h>
#include <stdint.h>

#define N_NODES 49152
#define N_EDGES 196608
#define NB      2048
#define HIDDEN  256
#define LAT     128
#define FHID    256
#define NFLOWS  4
#define MA      38
#define NNF_    38
#define NEF_    4

typedef __attribute__((ext_vector_type(8))) short bf16x8;
typedef __attribute__((ext_vector_type(4))) float f32x4;

#define MEMPIN() asm volatile("" ::: "memory")
#define BARRIER() asm volatile("s_waitcnt lgkmcnt(0)\n\ts_barrier" ::: "memory")
#define MFMA16 __builtin_amdgcn_mfma_f32_16x16x32_bf16

// ---------- bf16 helpers ----------
__device__ inline uint32_t bf16_rne_bits(float v){
    uint32_t u = __float_as_uint(v);
    u += 0x7fffu + ((u >> 16) & 1u);
    return u & 0xffff0000u;
}
__device__ inline uint16_t to_b16(float v){ return (uint16_t)(bf16_rne_bits(v) >> 16); }
__device__ inline float from_b16(uint16_t u){ return __uint_as_float((uint32_t)u << 16); }
__device__ inline uint32_t pack_hl(float v){
    uint32_t hu = bf16_rne_bits(v);
    float r = v - __uint_as_float(hu);
    uint32_t lu = bf16_rne_bits(r);
    return hu | (lu >> 16);
}

__device__ inline void unpack_frag(const uint4& x, const uint4& y, bf16x8& hi, bf16x8& lo){
    union { bf16x8 v; uint32_t u[4]; } H, L;
    H.u[0] = __builtin_amdgcn_perm(x.y, x.x, 0x07060302u);
    H.u[1] = __builtin_amdgcn_perm(x.w, x.z, 0x07060302u);
    H.u[2] = __builtin_amdgcn_perm(y.y, y.x, 0x07060302u);
    H.u[3] = __builtin_amdgcn_perm(y.w, y.z, 0x07060302u);
    L.u[0] = __builtin_amdgcn_perm(x.y, x.x, 0x05040100u);
    L.u[1] = __builtin_amdgcn_perm(x.w, x.z, 0x05040100u);
    L.u[2] = __builtin_amdgcn_perm(y.y, y.x, 0x05040100u);
    L.u[3] = __builtin_amdgcn_perm(y.w, y.z, 0x05040100u);
    hi = H.v; lo = L.v;
}

// ---------------- init / CSR build ----------------

__global__ void k_init(int* __restrict__ cursor, int* __restrict__ gstart, int* __restrict__ gcnt){
    int i = blockIdx.x*256 + threadIdx.x;
    if (i < N_NODES) cursor[i] = 0;
    if (i < NB){ gstart[i] = 0x7fffffff; gcnt[i] = 0; }
}

__global__ void k_embed(const int* __restrict__ x, const float* __restrict__ emb, uint16_t* __restrict__ h){
    int i = blockIdx.x; int c = threadIdx.x;
    h[(size_t)i*HIDDEN + c] = to_b16(emb[x[i]*HIDDEN + c]);
}

__global__ void k_deg(const int* __restrict__ dst, int* __restrict__ cursor){
    int e = blockIdx.x*256 + threadIdx.x;
    if (e < N_EDGES) atomicAdd(&cursor[dst[e]], 1);
}

__global__ void k_meta(const int* __restrict__ batch, int* __restrict__ gstart, int* __restrict__ gcnt){
    int i = blockIdx.x*256 + threadIdx.x;
    if (i < N_NODES){ int b = batch[i]; atomicMin(&gstart[b], i); atomicAdd(&gcnt[b], 1); }
}

__global__ __launch_bounds__(1024) void k_scan(int* __restrict__ cursor, int* __restrict__ offs){
    __shared__ int part[1024];
    const int tid = threadIdx.x;
    const int CH = N_NODES/1024; // 48
    int local[48];
    int s = 0;
    int base = tid*CH;
    for (int j=0;j<CH;j++){ local[j] = cursor[base+j]; s += local[j]; }
    part[tid] = s;
    __syncthreads();
    for (int off=1; off<1024; off<<=1){
        int v = (tid>=off) ? part[tid-off] : 0;
        __syncthreads();
        part[tid] += v;
        __syncthreads();
    }
    int excl = (tid==0) ? 0 : part[tid-1];
    for (int j=0;j<CH;j++){ offs[base+j] = excl; excl += local[j]; cursor[base+j] = 0; }
    if (tid == 1023) offs[N_NODES] = excl;
}

__global__ void k_scatter(const int* __restrict__ src, const int* __restrict__ dst, const int* __restrict__ attr,
                          const int* __restrict__ offs, int* __restrict__ cursor, int* __restrict__ epack){
    int e = blockIdx.x*256 + threadIdx.x;
    if (e < N_EDGES){
        int d = dst[e];
        int pos = atomicAdd(&cursor[d], 1);
        epack[offs[d] + pos] = (src[e] & 0xffff) | (attr[e] << 16);
    }
}

// ---------------- message aggregation: wave-per-node, 4-edge MLP chunks ----------------

__global__ __launch_bounds__(256) void k_aggr(const uint16_t* __restrict__ h, const float* __restrict__ eemb,
                                              const int* __restrict__ offs, const int* __restrict__ epack,
                                              uint16_t* __restrict__ t){
    __shared__ float sE[NEF_*HIDDEN];
    const int tid  = threadIdx.x;
    #pragma unroll
    for (int q=0;q<NEF_;q++) sE[q*256 + tid] = eemb[q*256 + tid];
    __syncthreads();

    const int wave = tid >> 6;
    const int lane = tid & 63;
    const int node = blockIdx.x*4 + wave;
    const int c4   = lane*4;

    uint2 hu = *(const uint2*)(h + (size_t)node*HIDDEN + c4);
    float4 acc;
    acc.x = __uint_as_float(hu.x << 16);
    acc.y = __uint_as_float(hu.x & 0xffff0000u);
    acc.z = __uint_as_float(hu.y << 16);
    acc.w = __uint_as_float(hu.y & 0xffff0000u);

    const int e0 = offs[node], e1 = offs[node+1];
    for (int j = e0; j < e1; j += 4){
        int p0 = epack[j];
        int p1 = (j+1 < e1) ? epack[j+1] : p0;
        int p2 = (j+2 < e1) ? epack[j+2] : p0;
        int p3 = (j+3 < e1) ? epack[j+3] : p0;
        uint2 g0 = *(const uint2*)(h + (size_t)(p0 & 0xffff)*HIDDEN + c4);
        uint2 g1 = *(const uint2*)(h + (size_t)(p1 & 0xffff)*HIDDEN + c4);
        uint2 g2 = *(const uint2*)(h + (size_t)(p2 & 0xffff)*HIDDEN + c4);
        uint2 g3 = *(const uint2*)(h + (size_t)(p3 & 0xffff)*HIDDEN + c4);
        {
            const float4 ev = *(const float4*)&sE[(p0 >> 16)*HIDDEN + c4];
            acc.x += fmaxf(__uint_as_float(g0.x << 16)        + ev.x, 0.f);
            acc.y += fmaxf(__uint_as_float(g0.x & 0xffff0000u) + ev.y, 0.f);
            acc.z += fmaxf(__uint_as_float(g0.y << 16)        + ev.z, 0.f);
            acc.w += fmaxf(__uint_as_float(g0.y & 0xffff0000u) + ev.w, 0.f);
        }
        if (j+1 < e1){
            const float4 ev = *(const float4*)&sE[(p1 >> 16)*HIDDEN + c4];
            acc.x += fmaxf(__uint_as_float(g1.x << 16)        + ev.x, 0.f);
            acc.y += fmaxf(__uint_as_float(g1.x & 0xffff0000u) + ev.y, 0.f);
            acc.z += fmaxf(__uint_as_float(g1.y << 16)        + ev.z, 0.f);
            acc.w += fmaxf(__uint_as_float(g1.y & 0xffff0000u) + ev.w, 0.f);
        }
        if (j+2 < e1){
            const float4 ev = *(const float4*)&sE[(p2 >> 16)*HIDDEN + c4];
            acc.x += fmaxf(__uint_as_float(g2.x << 16)        + ev.x, 0.f);
            acc.y += fmaxf(__uint_as_float(g2.x & 0xffff0000u) + ev.y, 0.f);
            acc.z += fmaxf(__uint_as_float(g2.y << 16)        + ev.z, 0.f);
            acc.w += fmaxf(__uint_as_float(g2.y & 0xffff0000u) + ev.w, 0.f);
        }
        if (j+3 < e1){
            const float4 ev = *(const float4*)&sE[(p3 >> 16)*HIDDEN + c4];
            acc.x += fmaxf(__uint_as_float(g3.x << 16)        + ev.x, 0.f);
            acc.y += fmaxf(__uint_as_float(g3.x & 0xffff0000u) + ev.y, 0.f);
            acc.z += fmaxf(__uint_as_float(g3.y << 16)        + ev.z, 0.f);
            acc.w += fmaxf(__uint_as_float(g3.y & 0xffff0000u) + ev.w, 0.f);
        }
    }

    uint2 o;
    o.x = (uint32_t)to_b16(acc.x) | ((uint32_t)to_b16(acc.y) << 16);
    o.y = (uint32_t)to_b16(acc.z) | ((uint32_t)to_b16(acc.w) << 16);
    *(uint2*)(t + (size_t)node*HIDDEN + c4) = o;
}

// ---------------- fused weight / activation converter (single launch) ----------------
// conv + decoder weights packed into [nblk][kc][lq][col][8] streaming chunks
// (16KB each) for global_load_lds. Edge-decoder weights are additionally
// SYMMETRIZED: S = he @ (0.5*(W[ij]+W[ji]))^T + 0.5*(b[ij]+b[ji]) equals the
// reference post-hoc (E+E^T)/2 because symmetrization is linear and he is
// independent of (i,j) -> k_sym kernel and edge_raw buffer eliminated.

#define CVT_TOTAL 4489216

__global__ void k_cvt_all(
    const float* __restrict__ conv_w1, const float* __restrict__ conv_w2,
    const float* __restrict__ mu_w, const float* __restrict__ mu_b,
    const float* __restrict__ lv_w, const float* __restrict__ lv_b,
    const float* __restrict__ fw1, const float* __restrict__ fw2,
    const float* __restrict__ dn_w1, const float* __restrict__ dn_w2,
    const float* __restrict__ de_w1, const float* __restrict__ de_w2,
    const float* __restrict__ de_b2,
    uint16_t* __restrict__ cw1b, uint16_t* __restrict__ cw2b,
    uint32_t* __restrict__ mvwpk, float* __restrict__ mvb,
    uint16_t* __restrict__ w1p, uint16_t* __restrict__ w2p,
    uint16_t* __restrict__ dnw1b, uint16_t* __restrict__ dnw2b,
    uint16_t* __restrict__ dew1b, uint16_t* __restrict__ dew2b,
    float* __restrict__ deb2s)
{
    int i = blockIdx.x*256 + threadIdx.x;
    if (i < 262144){
        int o = (i >> 8) & 255, k = i & 255;
        int dst = (i & ~65535) | ((k >> 3) << 11) | (o << 3) | (k & 7);
        cw1b[dst] = to_b16(conv_w1[i]);
        return;
    }
    i -= 262144;
    if (i < 262144){
        int o = (i >> 8) & 255, k = i & 255;
        int dst = (i & ~65535) | ((k >> 3) << 11) | (o << 3) | (k & 7);
        cw2b[dst] = to_b16(conv_w2[i]);
        return;
    }
    i -= 262144;
    if (i < 65536){
        int o = i >> 8, k2 = i & 255;
        float v = (o < 128) ? mu_w[o*256 + k2] : lv_w[(o-128)*256 + k2];
        mvwpk[i] = pack_hl(v);
        if (i < 256) mvb[i] = (i < 128) ? mu_b[i] : lv_b[i-128];
        return;
    }
    i -= 65536;
    if (i < 131072){
        int flow = i >> 15;
        int o  = (i >> 7) & 255;
        int kk = i & 127;
        float v = (kk <= (o % 127)) ? fw1[i] : 0.f;
        uint32_t h = bf16_rne_bits(v);
        int kc = kk >> 5, lq = (kk >> 3) & 3, e = kk & 7;
        size_t dst = (size_t)flow*65536 + (size_t)kc*16384 + (size_t)(lq*256 + o)*8 + e;
        w1p[dst]        = (uint16_t)(h >> 16);
        w1p[dst + 8192] = (uint16_t)(bf16_rne_bits(v - __uint_as_float(h)) >> 16);
        return;
    }
    i -= 131072;
    if (i < 262144){
        int flow = i >> 16;
        int o  = (i >> 8) & 255;
        int hh = i & 255;
        float v = ((hh % 127) < (o & 127)) ? fw2[i] : 0.f;
        uint32_t h = bf16_rne_bits(v);
        int kc = hh >> 5, lq = (hh >> 3) & 3, e = hh & 7;
        size_t dst = (size_t)flow*131072 + (size_t)kc*16384 + (size_t)(lq*256 + o)*8 + e;
        w2p[dst]        = (uint16_t)(h >> 16);
        w2p[dst + 8192] = (uint16_t)(bf16_rne_bits(v - __uint_as_float(h)) >> 16);
        return;
    }
    i -= 262144;
    if (i < 32768){ dnw1b[i] = to_b16(dn_w1[i]); return; }
    i -= 32768;
    if (i < 393216){           // node-decoder W2: 1444 rows padded to 1536, packed
        int o = i >> 8, k = i & 255;
        float v = (o < MA*NNF_) ? dn_w2[(size_t)o*256 + k] : 0.f;
        size_t dst = (size_t)(o >> 8)*65536 + (size_t)(k >> 5)*8192
                   + (size_t)((k >> 3) & 3)*2048 + (size_t)(o & 255)*8 + (size_t)(k & 7);
        dnw2b[dst] = to_b16(v);
        return;
    }
    i -= 393216;
    if (i < 65536){ dew1b[i] = to_b16(de_w1[i]); return; }
    i -= 65536;
    if (i < 3014656){          // edge-decoder W2: symmetrized, 5776 rows padded to 5888, packed
        int o = i >> 9, k = i & 511;
        float v = 0.f;
        if (o < MA*MA*NEF_){
            int e = o & 3, cell = o >> 2;
            int ii = cell / MA, jj = cell - ii*MA;
            int ot = (jj*MA + ii)*4 + e;
            v = 0.5f*(de_w2[(size_t)o*512 + k] + de_w2[(size_t)ot*512 + k]);
            if (k == 0) deb2s[o] = 0.5f*(de_b2[o] + de_b2[ot]);
        }
        size_t dst = (size_t)(o >> 8)*131072 + (size_t)(k >> 5)*8192
                   + (size_t)((k >> 3) & 3)*2048 + (size_t)(o & 255)*8 + (size_t)(k & 7);
        dew2b[dst] = to_b16(v);
    }
}

// ---------------- fused conv v4: LDS-streamed weights (contiguous staging) ----------------

__global__ __launch_bounds__(256) void k_conv2(
    const uint16_t* __restrict__ A,
    const uint16_t* __restrict__ W1p, const float* __restrict__ B1,
    const uint16_t* __restrict__ W2p, const float* __restrict__ B2,
    uint16_t* __restrict__ C)
{
    extern __shared__ __align__(16) char smem[];
    const int tid  = threadIdx.x;
    const int wave = tid >> 6;
    const int lane = tid & 63;
    const int l15  = lane & 15;
    const int lq   = lane >> 4;
    const int l7   = lane & 7;
    const int row0 = blockIdx.x * 64;
    char* wb0 = smem + 32768;
    char* wb1 = smem + 32768 + 16384;

    #define STAGE_W(Wp, kc, wb)                                              \
        { _Pragma("unroll")                                                  \
          for (int it=0; it<4; ++it){                                        \
            int s = it*256 + tid;                                            \
            __builtin_amdgcn_global_load_lds(                                \
                (const __attribute__((address_space(1))) uint32_t*)          \
                    ((const char*)(Wp) + (size_t)(kc)*16384 + (size_t)s*16), \
                (__attribute__((address_space(3))) uint32_t*)((wb) + s*16),  \
                16, 0, 0);                                                   \
          } }

    #pragma unroll
    for (int it = 0; it < 8; ++it) {
        int s  = it*256 + tid;
        int m  = s >> 5;
        int gl = (s & 31) ^ (m & 7);
        const char* gp = (const char*)A + ((size_t)(row0+m)*HIDDEN)*2 + gl*16;
        __builtin_amdgcn_global_load_lds(
            (const __attribute__((address_space(1))) uint32_t*)gp,
            (__attribute__((address_space(3))) uint32_t*)(smem + (size_t)s*16),
            16, 0, 0);
    }
    STAGE_W(W1p, 0, wb0);
    __syncthreads();

    f32x4 acc[4][4];
    #pragma unroll
    for (int mt=0;mt<4;mt++)
        #pragma unroll
        for (int nt=0;nt<4;nt++) acc[mt][nt] = (f32x4)(0.f);

    #pragma unroll
    for (int kc = 0; kc < 8; ++kc){
        char* rdb = (kc & 1) ? wb1 : wb0;
        if (kc < 7){ char* stb = (kc & 1) ? wb0 : wb1; STAGE_W(W1p, kc+1, stb); }
        bf16x8 bw[4];
        #pragma unroll
        for (int nt=0;nt<4;nt++)
            bw[nt] = *(const bf16x8*)(rdb + (size_t)((lq*256 + wave*64 + nt*16 + l15)) * 16);
        #pragma unroll
        for (int mt=0;mt<4;mt++){
            const int mb = (mt*16 + l15) << 5;
            int g = kc*4 + lq;
            bf16x8 a = *(const bf16x8*)(smem + (size_t)(mb + (g ^ l7))*16);
            #pragma unroll
            for (int nt=0;nt<4;nt++)
                acc[mt][nt] = MFMA16(a, bw[nt], acc[mt][nt], 0, 0, 0);
        }
        __syncthreads();
    }

    STAGE_W(W2p, 0, wb0);
    uint16_t* h1 = (uint16_t*)smem;
    #pragma unroll
    for (int mt=0;mt<4;mt++){
        #pragma unroll
        for (int nt=0;nt<4;nt++){
            int col = wave*64 + nt*16 + l15;
            float bb = B1[col];
            #pragma unroll
            for (int reg=0;reg<4;reg++){
                int r = mt*16 + lq*4 + reg;
                float v = fmaxf(acc[mt][nt][reg] + bb, 0.f);
                h1[(r*32 + ((col>>3) ^ (r&7)))*8 + (col&7)] = to_b16(v);
            }
        }
    }
    __syncthreads();

    #pragma unroll
    for (int mt=0;mt<4;mt++)
        #pragma unroll
        for (int nt=0;nt<4;nt++) acc[mt][nt] = (f32x4)(0.f);

    #pragma unroll
    for (int kc = 0; kc < 8; ++kc){
        char* rdb = (kc & 1) ? wb1 : wb0;
        if (kc < 7){ char* stb = (kc & 1) ? wb0 : wb1; STAGE_W(W2p, kc+1, stb); }
        bf16x8 bw[4];
        #pragma unroll
        for (int nt=0;nt<4;nt++)
            bw[nt] = *(const bf16x8*)(rdb + (size_t)((lq*256 + wave*64 + nt*16 + l15)) * 16);
        #pragma unroll
        for (int mt=0;mt<4;mt++){
            int m = mt*16 + l15;
            bf16x8 a = *(const bf16x8*)(h1 + (size_t)(m*32 + ((kc*4 + lq) ^ (m & 7)))*8);
            #pragma unroll
            for (int nt=0;nt<4;nt++)
                acc[mt][nt] = MFMA16(a, bw[nt], acc[mt][nt], 0, 0, 0);
        }
        __syncthreads();
    }

    uint16_t* rs = (uint16_t*)smem;
    #pragma unroll
    for (int mt=0;mt<4;mt++){
        #pragma unroll
        for (int nt=0;nt<4;nt++){
            int col = wave*64 + nt*16 + l15;
            float bb = B2[col];
            #pragma unroll
            for (int reg=0;reg<4;reg++){
                int r = mt*16 + lq*4 + reg;
                float v = fmaxf(acc[mt][nt][reg] + bb, 0.f);
                rs[(r*32 + ((col>>3) ^ (r&7)))*8 + (col&7)] = to_b16(v);
            }
        }
    }
    BARRIER();

    #pragma unroll
    for (int it = 0; it < 8; ++it){
        int s   = it*256 + tid;
        int row = s >> 5;
        int gc  = s & 31;
        uint4 d = *(const uint4*)(smem + (size_t)(row*32 + (gc ^ (row & 7)))*16);
        *(uint4*)(C + (size_t)(row0+row)*HIDDEN + gc*8) = d;
    }
    #undef STAGE_W
}

// ---------------- MFMA GEMM (mu/lv + decoders) ----------------
// PACKED=1: weights pre-packed per 256-col n-block into fragment-order 16KB
// chunks; streamed via global_load_lds dbuf (the conv2-proven fix for the
// scattered-weight-read wall). N must be padded to blockDim-x*256 in the pack.

template<int SPLIT, int OUTM, int PACKED = 0>
__global__ __launch_bounds__(256) void mfma_gemm(
    const void* __restrict__ Ap, const void* __restrict__ Wp,
    const float* __restrict__ bias, void* __restrict__ Cp,
    int M, int N, int K, int relu)
{
    extern __shared__ __align__(16) char smem[];
    const int tid  = threadIdx.x;
    const int wave = tid >> 6;
    const int lane = tid & 63;
    const int l15  = lane & 15;
    const int lq   = lane >> 4;
    const int l7   = lane & 7;
    const int row0 = blockIdx.y * 64;
    const int n0   = blockIdx.x * 256;
    const int ELB  = SPLIT ? 4 : 2;
    const int KC   = (K < 256) ? K : 256;
    const int GR   = (KC * ELB) >> 4;
    const int rsh  = (GR == 64) ? 6 : ((GR == 32) ? 5 : 4);

    f32x4 acc[4][4];
    #pragma unroll
    for (int mt=0;mt<4;mt++)
        #pragma unroll
        for (int nt=0;nt<4;nt++) acc[mt][nt] = (f32x4)(0.f);

    const char* Ab = (const char*)Ap;
    const char* Wb = (const char*)Wp;
    const char* Wsl = Wb + (size_t)blockIdx.x * (size_t)K * 512;  // packed slice (256 cols x K x 2B)
    char* wbp0 = smem + 32768;
    char* wbp1 = smem + 32768 + 16384;
    int pb = 0;
    const int NCH = K >> 5;

    #define STAGE_PK(ch, wb)                                                 \
        { _Pragma("unroll")                                                  \
          for (int it=0; it<4; ++it){                                        \
            int s = it*256 + tid;                                            \
            __builtin_amdgcn_global_load_lds(                                \
                (const __attribute__((address_space(1))) uint32_t*)          \
                    (Wsl + (size_t)(ch)*16384 + (size_t)s*16),               \
                (__attribute__((address_space(3))) uint32_t*)((wb) + s*16),  \
                16, 0, 0);                                                   \
          } }

    for (int kbase = 0; kbase < K; kbase += KC) {
        const int rounds = GR >> 2;
        for (int it = 0; it < rounds; ++it) {
            int sbase = it*256 + wave*64;
            int s  = sbase + lane;
            int m  = s >> rsh;
            int gl = (s & (GR-1)) ^ (m & 7);
            const char* gp = Ab + ((size_t)(row0+m)*K + kbase)*ELB + gl*16;
            __builtin_amdgcn_global_load_lds(
                (const __attribute__((address_space(1))) uint32_t*)gp,
                (__attribute__((address_space(3))) uint32_t*)(smem + sbase*16),
                16, 0, 0);
        }
        if (PACKED && kbase == 0) STAGE_PK(0, wbp0);
        __syncthreads();

        for (int kc = 0; kc < (KC >> 5); ++kc) {
            bf16x8 bhi[4], blo[4];
            if (PACKED){
                int gch = (kbase >> 5) + kc;
                char* rdb = pb ? wbp1 : wbp0;
                if (gch + 1 < NCH){ char* stb = pb ? wbp0 : wbp1; STAGE_PK(gch+1, stb); }
                #pragma unroll
                for (int nt=0;nt<4;nt++)
                    bhi[nt] = *(const bf16x8*)(rdb + (size_t)(lq*256 + wave*64 + nt*16 + l15)*16);
            } else {
                #pragma unroll
                for (int nt=0;nt<4;nt++){
                    int n = n0 + wave*64 + nt*16 + l15;
                    if (n >= N) n = N-1;
                    if (SPLIT){
                        const uint4* wp4 = (const uint4*)(Wb + ((size_t)n*K + kbase + kc*32 + lq*8)*4);
                        uint4 xx = wp4[0], yy = wp4[1];
                        unpack_frag(xx, yy, bhi[nt], blo[nt]);
                    } else {
                        bhi[nt] = *(const bf16x8*)(Wb + ((size_t)n*K + kbase + kc*32 + lq*8)*2);
                    }
                }
            }
            #pragma unroll
            for (int mt=0;mt<4;mt++){
                const int mb = (mt*16 + l15) << rsh;
                if (SPLIT){
                    int g0 = kc*8 + lq*2;
                    uint4 xx = *(const uint4*)(smem + (size_t)(mb + ((g0  ) ^ l7))*16);
                    uint4 yy = *(const uint4*)(smem + (size_t)(mb + ((g0+1) ^ l7))*16);
                    bf16x8 ahi, alo;
                    unpack_frag(xx, yy, ahi, alo);
                    #pragma unroll
                    for (int nt=0;nt<4;nt++){
                        acc[mt][nt] = MFMA16(ahi, bhi[nt], acc[mt][nt], 0, 0, 0);
                        acc[mt][nt] = MFMA16(ahi, blo[nt], acc[mt][nt], 0, 0, 0);
                        acc[mt][nt] = MFMA16(alo, bhi[nt], acc[mt][nt], 0, 0, 0);
                    }
                } else {
                    int g = kc*4 + lq;
                    bf16x8 a = *(const bf16x8*)(smem + (size_t)(mb + (g ^ l7))*16);
                    #pragma unroll
                    for (int nt=0;nt<4;nt++){
                        acc[mt][nt] = MFMA16(a, bhi[nt], acc[mt][nt], 0, 0, 0);
                    }
                }
            }
            if (PACKED){ __syncthreads(); pb ^= 1; }
        }
        __syncthreads();
    }

    const int ES = (OUTM == 1) ? 2 : 4;
    char* rs = smem + wave*(64*64*ES);
    const int colbase = n0 + wave*64;
    #pragma unroll
    for (int mt=0;mt<4;mt++){
        #pragma unroll
        for (int nt=0;nt<4;nt++){
            int cl = nt*16 + l15;
            int col = colbase + cl;
            float bb = bias[col < N ? col : N-1];
            #pragma unroll
            for (int reg=0;reg<4;reg++){
                int r = mt*16 + lq*4 + reg;
                float v = acc[mt][nt][reg] + bb;
                if (relu) v = fmaxf(v, 0.f);
                if (OUTM == 1) ((uint16_t*)rs)[r*64 + cl] = to_b16(v);
                else           ((float*)rs)[r*64 + cl] = v;
            }
        }
    }
    __syncthreads();
    for (int it = 0; it < 32; ++it) {
        int r   = it*2 + (lane>>5);
        int clp = lane & 31;
        int col = colbase + clp*2;
        if (col < N){
            if (OUTM == 1){
                uint32_t d = *(const uint32_t*)((const uint16_t*)rs + r*64 + clp*2);
                *(uint32_t*)((char*)Cp + ((size_t)(row0+r)*N + col)*2) = d;
            } else {
                float2 d = *(const float2*)((const float*)rs + r*64 + clp*2);
                *(float2*)((float*)Cp + (size_t)(row0+r)*N + col) = d;
            }
        }
    }
    #undef STAGE_PK
}

// ---------------- pooling + z0 elementwise ----------------

__global__ void k_pool(const uint16_t* __restrict__ h, const int* __restrict__ gstart,
                       const int* __restrict__ gcnt, uint32_t* __restrict__ hg){
    int b = blockIdx.x; int c = threadIdx.x;
    int s0 = gstart[b]; int n = gcnt[b];
    float s = 0.f;
    for (int j=0;j<n;j++) s += from_b16(h[(size_t)(s0+j)*HIDDEN + c]);
    hg[(size_t)b*HIDDEN + c] = pack_hl(s);
}

__global__ void k_z0(const float* __restrict__ mv, const float* __restrict__ eps,
                     float* __restrict__ mu_o, float* __restrict__ lv_o, float* __restrict__ z0_o){
    int i = blockIdx.x*256 + threadIdx.x;
    if (i >= NB*LAT) return;
    int b = i >> 7, l = i & 127;
    float m = mv[(size_t)b*256 + l];
    float v = mv[(size_t)b*256 + l + 128];
    mu_o[i] = m;
    lv_o[i] = v;
    z0_o[i] = m + eps[i]*expf(0.5f*v);
}

// ---------------- fused MFMA flows v7: LDS-streamed packed weights ----------------

__global__ __launch_bounds__(1024) void k_flows_mfma7(
    const float* __restrict__ z0,
    const uint16_t* __restrict__ w1p, const float* __restrict__ fb1,
    const uint16_t* __restrict__ w2p, const float* __restrict__ fb2,
    float* __restrict__ zK, uint16_t* __restrict__ zkb, float* __restrict__ sld)
{
    __shared__ __align__(16) uint16_t zhi[16][136];
    __shared__ __align__(16) uint16_t zlo[16][136];
    __shared__ __align__(16) uint16_t h1hi[16][280];
    __shared__ __align__(16) uint16_t h1lo[16][280];
    __shared__ __align__(16) float    oS[16][268];
    __shared__ __align__(16) uint16_t wbuf[2][16384];
    const int tid  = threadIdx.x;
    const int wave = tid >> 6;
    const int lane = tid & 63;
    const int l15  = lane & 15;
    const int lq   = lane >> 4;
    const int g0   = blockIdx.x * 16;
    const int col  = wave*16 + l15;
    const int fo   = (lq*256 + col)*8;

    #define STAGE_C(srcp, buf)                                               \
        { _Pragma("unroll")                                                  \
          for (int it=0; it<2; ++it){                                        \
            int s = it*1024 + tid;                                           \
            __builtin_amdgcn_global_load_lds(                                \
                (const __attribute__((address_space(1))) uint32_t*)          \
                    ((const char*)(srcp) + (size_t)s*16),                    \
                (__attribute__((address_space(3))) uint32_t*)                \
                    ((char*)&wbuf[buf][0] + (size_t)s*16),                   \
                16, 0, 0);                                                   \
          } }

    int pb = 0;
    STAGE_C(w1p, 0);

    #pragma unroll
    for (int q=0;q<2;q++){
        int idx = q*1024 + tid;
        int r = idx >> 7, l = idx & 127;
        float v = z0[(size_t)(g0 + r)*LAT + l];
        uint32_t h = bf16_rne_bits(v);
        zhi[r][l] = (uint16_t)(h >> 16);
        zlo[r][l] = (uint16_t)(bf16_rne_bits(v - __uint_as_float(h)) >> 16);
    }
    float ldacc = 0.f;
    __syncthreads();

    for (int kf=0; kf<NFLOWS; kf++){
        const uint16_t* W1f = w1p + (size_t)kf*65536;
        const uint16_t* W2f = w2p + (size_t)kf*131072;

        f32x4 acc = (f32x4)(0.f);
        #pragma unroll
        for (int kc=0;kc<4;kc++){
            const uint16_t* nxt = (kc < 3) ? (W1f + (size_t)(kc+1)*16384) : W2f;
            STAGE_C(nxt, pb^1);
            bf16x8 wh = *(const bf16x8*)&wbuf[pb][fo];
            bf16x8 wl = *(const bf16x8*)&wbuf[pb][fo + 8192];
            bf16x8 ah = *(const bf16x8*)&zhi[l15][kc*32 + lq*8];
            bf16x8 al = *(const bf16x8*)&zlo[l15][kc*32 + lq*8];
            acc = MFMA16(ah, wh, acc, 0, 0, 0);
            acc = MFMA16(ah, wl, acc, 0, 0, 0);
            acc = MFMA16(al, wh, acc, 0, 0, 0);
            __syncthreads();
            pb ^= 1;
        }
        {
            float bb = fb1[kf*FHID + col];
            #pragma unroll
            for (int reg=0;reg<4;reg++){
                int r = lq*4 + reg;
                float v = fmaxf(acc[reg] + bb, 0.f);
                uint32_t h = bf16_rne_bits(v);
                h1hi[r][col] = (uint16_t)(h >> 16);
                h1lo[r][col] = (uint16_t)(bf16_rne_bits(v - __uint_as_float(h)) >> 16);
            }
        }
        BARRIER();

        f32x4 a2 = (f32x4)(0.f);
        #pragma unroll
        for (int kc=0;kc<8;kc++){
            if (kc < 7){
                STAGE_C(W2f + (size_t)(kc+1)*16384, pb^1);
            } else if (kf < NFLOWS-1){
                STAGE_C(w1p + (size_t)(kf+1)*65536, pb^1);
            }
            bf16x8 wh = *(const bf16x8*)&wbuf[pb][fo];
            bf16x8 wl = *(const bf16x8*)&wbuf[pb][fo + 8192];
            bf16x8 ah = *(const bf16x8*)&h1hi[l15][kc*32 + lq*8];
            bf16x8 al = *(const bf16x8*)&h1lo[l15][kc*32 + lq*8];
            a2 = MFMA16(ah, wh, a2, 0, 0, 0);
            a2 = MFMA16(ah, wl, a2, 0, 0, 0);
            a2 = MFMA16(al, wh, a2, 0, 0, 0);
            __syncthreads();
            pb ^= 1;
        }
        {
            float bb = fb2[kf*2*LAT + col];
            #pragma unroll
            for (int reg=0;reg<4;reg++)
                oS[lq*4 + reg][col] = a2[reg] + bb;
        }
        BARRIER();

        {
            const int r = wave;
            float ldp = 0.f;
            #pragma unroll
            for (int j=0;j<2;j++){
                int l = lane + j*64;
                float m = oS[r][l];
                float s = oS[r][l + 128];
                float g = 1.f/(1.f + expf(-s));
                float zv = __uint_as_float((uint32_t)zhi[r][l] << 16)
                         + __uint_as_float((uint32_t)zlo[r][l] << 16);
                float zn = g*zv + (1.f - g)*m;
                uint32_t h = bf16_rne_bits(zn);
                zhi[r][l] = (uint16_t)(h >> 16);
                zlo[r][l] = (uint16_t)(bf16_rne_bits(zn - __uint_as_float(h)) >> 16);
                ldp += logf(g + 1e-8f);
            }
            #pragma unroll
            for (int off=1; off<64; off<<=1) ldp += __shfl_xor(ldp, off);
            ldacc += ldp;
        }
        BARRIER();
    }

    #pragma unroll
    for (int q=0;q<2;q++){
        int idx = q*1024 + tid;
        int r = idx >> 7, l = idx & 127;
        uint32_t h = (uint32_t)zhi[r][l] << 16;
        float zv = __uint_as_float(h) + __uint_as_float((uint32_t)zlo[r][l] << 16);
        zK[(size_t)(g0+r)*LAT + l] = zv;
        zkb[(size_t)(g0+r)*LAT + l] = (uint16_t)(h >> 16);
    }
    if (lane == 0) sld[g0 + wave] = ldacc;
    #undef STAGE_C
}

// ---------------- launch ----------------

extern "C" void kernel_launch(void* const* d_in, const int* in_sizes, int n_in,
                              void* d_out, int out_size, void* d_ws, size_t ws_size,
                              hipStream_t stream){
    (void)in_sizes; (void)n_in; (void)out_size; (void)ws_size;
    const int*   x        = (const int*)d_in[0];
    const int*   eidx     = (const int*)d_in[1];
    const int*   eattr    = (const int*)d_in[2];
    const int*   batch    = (const int*)d_in[3];
    const float* eps      = (const float*)d_in[4];
    const float* node_emb = (const float*)d_in[5];
    const float* edge_emb = (const float*)d_in[6];
    const float* conv_w1  = (const float*)d_in[7];
    const float* conv_b1  = (const float*)d_in[8];
    const float* conv_w2  = (const float*)d_in[9];
    const float* conv_b2  = (const float*)d_in[10];
    const float* mu_w     = (const float*)d_in[11];
    const float* mu_b     = (const float*)d_in[12];
    const float* lv_w     = (const float*)d_in[13];
    const float* lv_b     = (const float*)d_in[14];
    const float* fw1      = (const float*)d_in[15];
    const float* fb1      = (const float*)d_in[16];
    const float* fw2      = (const float*)d_in[17];
    const float* fb2      = (const float*)d_in[18];
    const float* dn_w1    = (const float*)d_in[19];
    const float* dn_b1    = (const float*)d_in[20];
    const float* dn_w2    = (const float*)d_in[21];
    const float* dn_b2    = (const float*)d_in[22];
    const float* de_w1    = (const float*)d_in[23];
    const float* de_b1    = (const float*)d_in[24];
    const float* de_w2    = (const float*)d_in[25];
    const float* de_b2    = (const float*)d_in[26];

    float* out = (float*)d_out;
    const size_t off_node = 0;
    const size_t off_edge = (size_t)NB*MA*NNF_;
    const size_t off_mu   = off_edge + (size_t)NB*MA*MA*NEF_;
    const size_t off_lv   = off_mu + (size_t)NB*LAT;
    const size_t off_z0   = off_lv + (size_t)NB*LAT;
    const size_t off_zk   = off_z0 + (size_t)NB*LAT;
    const size_t off_sld  = off_zk + (size_t)NB*LAT;
    (void)off_node;

    char* p = (char*)d_ws;
    auto alloc = [&](size_t bytes)->char*{ char* r = p; p += (bytes + 255) & ~(size_t)255; return r; };
    uint16_t* h_b   = (uint16_t*)alloc((size_t)N_NODES*HIDDEN*2);
    uint16_t* t_b   = (uint16_t*)alloc((size_t)N_NODES*HIDDEN*2);
    int*   offs   = (int*)  alloc((size_t)(N_NODES+1)*4);
    int*   cursor = (int*)  alloc((size_t)N_NODES*4);
    int*   epack  = (int*)  alloc((size_t)N_EDGES*4);
    int*   gstart = (int*)  alloc((size_t)NB*4);
    int*   gcnt   = (int*)  alloc((size_t)NB*4);
    uint32_t* hg_pk = (uint32_t*)alloc((size_t)NB*HIDDEN*4);
    float* mv       = (float*)alloc((size_t)NB*256*4);
    uint16_t* cw1b  = (uint16_t*)alloc((size_t)4*HIDDEN*HIDDEN*2);
    uint16_t* cw2b  = (uint16_t*)alloc((size_t)4*HIDDEN*HIDDEN*2);
    uint32_t* mvwpk = (uint32_t*)alloc((size_t)256*256*4);
    float*    mvb   = (float*)  alloc((size_t)256*4);
    uint16_t* w1p   = (uint16_t*)alloc((size_t)NFLOWS*65536*2);
    uint16_t* w2p   = (uint16_t*)alloc((size_t)NFLOWS*131072*2);
    uint16_t* dnw1b = (uint16_t*)alloc((size_t)256*LAT*2);
    uint16_t* dnw2b = (uint16_t*)alloc((size_t)1536*256*2);        // packed, padded
    uint16_t* dew1b = (uint16_t*)alloc((size_t)512*LAT*2);
    uint16_t* dew2b = (uint16_t*)alloc((size_t)5888*512*2);        // packed, padded, symmetrized
    float*    deb2s = (float*)  alloc((size_t)MA*MA*NEF_*4);       // symmetrized bias
    uint16_t* zkb   = (uint16_t*)alloc((size_t)NB*LAT*2);
    uint16_t* hnb   = (uint16_t*)alloc((size_t)NB*256*2);
    uint16_t* heb   = (uint16_t*)alloc((size_t)NB*512*2);

    const int* esrc = eidx;
    const int* edst = eidx + N_EDGES;

    k_cvt_all<<<(CVT_TOTAL+255)/256, 256, 0, stream>>>(
        conv_w1, conv_w2, mu_w, mu_b, lv_w, lv_b, fw1, fw2,
        dn_w1, dn_w2, de_w1, de_w2, de_b2,
        cw1b, cw2b, mvwpk, mvb, w1p, w2p,
        dnw1b, dnw2b, dew1b, dew2b, deb2s);

    k_init   <<<(N_NODES+255)/256, 256, 0, stream>>>(cursor, gstart, gcnt);
    k_embed  <<<N_NODES, HIDDEN, 0, stream>>>(x, node_emb, h_b);
    k_deg    <<<(N_EDGES+255)/256, 256, 0, stream>>>(edst, cursor);
    k_meta   <<<(N_NODES+255)/256, 256, 0, stream>>>(batch, gstart, gcnt);
    k_scan   <<<1, 1024, 0, stream>>>(cursor, offs);
    k_scatter<<<(N_EDGES+255)/256, 256, 0, stream>>>(esrc, edst, eattr, offs, cursor, epack);

    const size_t SM32 = 32768, SM64 = 65536;
    for (int k=0;k<4;k++){
        k_aggr<<<N_NODES/4, 256, 0, stream>>>(h_b, edge_emb, offs, epack, t_b);
        k_conv2<<<N_NODES/64, 256, SM64, stream>>>(
            t_b,
            cw1b + (size_t)k*HIDDEN*HIDDEN, conv_b1 + (size_t)k*HIDDEN,
            cw2b + (size_t)k*HIDDEN*HIDDEN, conv_b2 + (size_t)k*HIDDEN,
            h_b);
    }

    k_pool<<<NB, HIDDEN, 0, stream>>>(h_b, gstart, gcnt, hg_pk);
    mfma_gemm<1,2><<<dim3(1, NB/64), 256, SM64, stream>>>(hg_pk, mvwpk, mvb, mv, NB, 256, HIDDEN, 0);
    k_z0<<<(NB*LAT+255)/256, 256, 0, stream>>>(mv, eps, out+off_mu, out+off_lv, out+off_z0);

    k_flows_mfma7<<<NB/16, 1024, 0, stream>>>(out+off_z0, w1p, fb1, w2p, fb2,
                                              out+off_zk, zkb, out+off_sld);

    mfma_gemm<0,1><<<dim3(1, NB/64), 256, SM32, stream>>>(zkb, dnw1b, dn_b1, hnb, NB, 256, LAT, 1);
    mfma_gemm<0,2,1><<<dim3(6, NB/64), 256, SM64, stream>>>(hnb, dnw2b, dn_b2, out+off_node, NB, MA*NNF_, 256, 0);
    mfma_gemm<0,1><<<dim3(2, NB/64), 256, SM32, stream>>>(zkb, dew1b, de_b1, heb, NB, 512, LAT, 1);
    // edge decoder: symmetrized packed weights -> writes final output directly
    mfma_gemm<0,2,1><<<dim3(23, NB/64), 256, SM64, stream>>>(heb, dew2b, deb2s, out+off_edge, NB, MA*MA*NEF_, 512, 0);
}

// Round 8
// 530.253 us; speedup vs baseline: 1.6225x; 1.0316x over previous
//
#include <hip/hip_runtime.h>
#include <hip/hip_bf16.h>
#include <math.h>
#include <stdint.h>

#define N_NODES 49152
#define N_EDGES 196608
#define NB      2048
#define HIDDEN  256
#define LAT     128
#define FHID    256
#define NFLOWS  4
#define MA      38
#define NNF_    38
#define NEF_    4

typedef __attribute__((ext_vector_type(8))) short bf16x8;
typedef __attribute__((ext_vector_type(4))) float f32x4;

#define MEMPIN() asm volatile("" ::: "memory")
#define BARRIER() asm volatile("s_waitcnt lgkmcnt(0)\n\ts_barrier" ::: "memory")
#define SBAR() __builtin_amdgcn_s_barrier()
// counted vmem waits (T4): never drain to 0 inside a chunk loop. FIFO
// retirement => vmcnt(N) guarantees everything older than the newest N
// loads has landed, independent of compiler-inserted loads.
#define WAITV0() { asm volatile("s_waitcnt vmcnt(0)" ::: "memory"); __builtin_amdgcn_sched_barrier(0); }
#define WAITV2() { asm volatile("s_waitcnt vmcnt(2)" ::: "memory"); __builtin_amdgcn_sched_barrier(0); }
#define WAITV4() { asm volatile("s_waitcnt vmcnt(4)" ::: "memory"); __builtin_amdgcn_sched_barrier(0); }
#define MFMA16 __builtin_amdgcn_mfma_f32_16x16x32_bf16

// ---------- bf16 helpers ----------
__device__ inline uint32_t bf16_rne_bits(float v){
    uint32_t u = __float_as_uint(v);
    u += 0x7fffu + ((u >> 16) & 1u);
    return u & 0xffff0000u;
}
__device__ inline uint16_t to_b16(float v){ return (uint16_t)(bf16_rne_bits(v) >> 16); }
__device__ inline float from_b16(uint16_t u){ return __uint_as_float((uint32_t)u << 16); }
__device__ inline uint32_t pack_hl(float v){
    uint32_t hu = bf16_rne_bits(v);
    float r = v - __uint_as_float(hu);
    uint32_t lu = bf16_rne_bits(r);
    return hu | (lu >> 16);
}

__device__ inline void unpack_frag(const uint4& x, const uint4& y, bf16x8& hi, bf16x8& lo){
    union { bf16x8 v; uint32_t u[4]; } H, L;
    H.u[0] = __builtin_amdgcn_perm(x.y, x.x, 0x07060302u);
    H.u[1] = __builtin_amdgcn_perm(x.w, x.z, 0x07060302u);
    H.u[2] = __builtin_amdgcn_perm(y.y, y.x, 0x07060302u);
    H.u[3] = __builtin_amdgcn_perm(y.w, y.z, 0x07060302u);
    L.u[0] = __builtin_amdgcn_perm(x.y, x.x, 0x05040100u);
    L.u[1] = __builtin_amdgcn_perm(x.w, x.z, 0x05040100u);
    L.u[2] = __builtin_amdgcn_perm(y.y, y.x, 0x05040100u);
    L.u[3] = __builtin_amdgcn_perm(y.w, y.z, 0x05040100u);
    hi = H.v; lo = L.v;
}

// ---------------- init / CSR build ----------------

__global__ void k_init(int* __restrict__ cursor, int* __restrict__ gstart, int* __restrict__ gcnt){
    int i = blockIdx.x*256 + threadIdx.x;
    if (i < N_NODES) cursor[i] = 0;
    if (i < NB){ gstart[i] = 0x7fffffff; gcnt[i] = 0; }
}

__global__ void k_embed(const int* __restrict__ x, const float* __restrict__ emb, uint16_t* __restrict__ h){
    int i = blockIdx.x; int c = threadIdx.x;
    h[(size_t)i*HIDDEN + c] = to_b16(emb[x[i]*HIDDEN + c]);
}

__global__ void k_deg(const int* __restrict__ dst, int* __restrict__ cursor){
    int e = blockIdx.x*256 + threadIdx.x;
    if (e < N_EDGES) atomicAdd(&cursor[dst[e]], 1);
}

__global__ void k_meta(const int* __restrict__ batch, int* __restrict__ gstart, int* __restrict__ gcnt){
    int i = blockIdx.x*256 + threadIdx.x;
    if (i < N_NODES){ int b = batch[i]; atomicMin(&gstart[b], i); atomicAdd(&gcnt[b], 1); }
}

__global__ __launch_bounds__(1024) void k_scan(int* __restrict__ cursor, int* __restrict__ offs){
    __shared__ int part[1024];
    const int tid = threadIdx.x;
    const int CH = N_NODES/1024; // 48
    int local[48];
    int s = 0;
    int base = tid*CH;
    for (int j=0;j<CH;j++){ local[j] = cursor[base+j]; s += local[j]; }
    part[tid] = s;
    __syncthreads();
    for (int off=1; off<1024; off<<=1){
        int v = (tid>=off) ? part[tid-off] : 0;
        __syncthreads();
        part[tid] += v;
        __syncthreads();
    }
    int excl = (tid==0) ? 0 : part[tid-1];
    for (int j=0;j<CH;j++){ offs[base+j] = excl; excl += local[j]; cursor[base+j] = 0; }
    if (tid == 1023) offs[N_NODES] = excl;
}

__global__ void k_scatter(const int* __restrict__ src, const int* __restrict__ dst, const int* __restrict__ attr,
                          const int* __restrict__ offs, int* __restrict__ cursor, int* __restrict__ epack){
    int e = blockIdx.x*256 + threadIdx.x;
    if (e < N_EDGES){
        int d = dst[e];
        int pos = atomicAdd(&cursor[d], 1);
        epack[offs[d] + pos] = (src[e] & 0xffff) | (attr[e] << 16);
    }
}

// ---------------- message aggregation: wave-per-node, 4-edge MLP chunks ----------------

__global__ __launch_bounds__(256) void k_aggr(const uint16_t* __restrict__ h, const float* __restrict__ eemb,
                                              const int* __restrict__ offs, const int* __restrict__ epack,
                                              uint16_t* __restrict__ t){
    __shared__ float sE[NEF_*HIDDEN];
    const int tid  = threadIdx.x;
    #pragma unroll
    for (int q=0;q<NEF_;q++) sE[q*256 + tid] = eemb[q*256 + tid];
    __syncthreads();

    const int wave = tid >> 6;
    const int lane = tid & 63;
    const int node = blockIdx.x*4 + wave;
    const int c4   = lane*4;

    uint2 hu = *(const uint2*)(h + (size_t)node*HIDDEN + c4);
    float4 acc;
    acc.x = __uint_as_float(hu.x << 16);
    acc.y = __uint_as_float(hu.x & 0xffff0000u);
    acc.z = __uint_as_float(hu.y << 16);
    acc.w = __uint_as_float(hu.y & 0xffff0000u);

    const int e0 = offs[node], e1 = offs[node+1];
    for (int j = e0; j < e1; j += 4){
        int p0 = epack[j];
        int p1 = (j+1 < e1) ? epack[j+1] : p0;
        int p2 = (j+2 < e1) ? epack[j+2] : p0;
        int p3 = (j+3 < e1) ? epack[j+3] : p0;
        uint2 g0 = *(const uint2*)(h + (size_t)(p0 & 0xffff)*HIDDEN + c4);
        uint2 g1 = *(const uint2*)(h + (size_t)(p1 & 0xffff)*HIDDEN + c4);
        uint2 g2 = *(const uint2*)(h + (size_t)(p2 & 0xffff)*HIDDEN + c4);
        uint2 g3 = *(const uint2*)(h + (size_t)(p3 & 0xffff)*HIDDEN + c4);
        {
            const float4 ev = *(const float4*)&sE[(p0 >> 16)*HIDDEN + c4];
            acc.x += fmaxf(__uint_as_float(g0.x << 16)        + ev.x, 0.f);
            acc.y += fmaxf(__uint_as_float(g0.x & 0xffff0000u) + ev.y, 0.f);
            acc.z += fmaxf(__uint_as_float(g0.y << 16)        + ev.z, 0.f);
            acc.w += fmaxf(__uint_as_float(g0.y & 0xffff0000u) + ev.w, 0.f);
        }
        if (j+1 < e1){
            const float4 ev = *(const float4*)&sE[(p1 >> 16)*HIDDEN + c4];
            acc.x += fmaxf(__uint_as_float(g1.x << 16)        + ev.x, 0.f);
            acc.y += fmaxf(__uint_as_float(g1.x & 0xffff0000u) + ev.y, 0.f);
            acc.z += fmaxf(__uint_as_float(g1.y << 16)        + ev.z, 0.f);
            acc.w += fmaxf(__uint_as_float(g1.y & 0xffff0000u) + ev.w, 0.f);
        }
        if (j+2 < e1){
            const float4 ev = *(const float4*)&sE[(p2 >> 16)*HIDDEN + c4];
            acc.x += fmaxf(__uint_as_float(g2.x << 16)        + ev.x, 0.f);
            acc.y += fmaxf(__uint_as_float(g2.x & 0xffff0000u) + ev.y, 0.f);
            acc.z += fmaxf(__uint_as_float(g2.y << 16)        + ev.z, 0.f);
            acc.w += fmaxf(__uint_as_float(g2.y & 0xffff0000u) + ev.w, 0.f);
        }
        if (j+3 < e1){
            const float4 ev = *(const float4*)&sE[(p3 >> 16)*HIDDEN + c4];
            acc.x += fmaxf(__uint_as_float(g3.x << 16)        + ev.x, 0.f);
            acc.y += fmaxf(__uint_as_float(g3.x & 0xffff0000u) + ev.y, 0.f);
            acc.z += fmaxf(__uint_as_float(g3.y << 16)        + ev.z, 0.f);
            acc.w += fmaxf(__uint_as_float(g3.y & 0xffff0000u) + ev.w, 0.f);
        }
    }

    uint2 o;
    o.x = (uint32_t)to_b16(acc.x) | ((uint32_t)to_b16(acc.y) << 16);
    o.y = (uint32_t)to_b16(acc.z) | ((uint32_t)to_b16(acc.w) << 16);
    *(uint2*)(t + (size_t)node*HIDDEN + c4) = o;
}

// ---------------- fused weight / activation converter (single launch) ----------------

#define CVT_TOTAL 4489216

__global__ void k_cvt_all(
    const float* __restrict__ conv_w1, const float* __restrict__ conv_w2,
    const float* __restrict__ mu_w, const float* __restrict__ mu_b,
    const float* __restrict__ lv_w, const float* __restrict__ lv_b,
    const float* __restrict__ fw1, const float* __restrict__ fw2,
    const float* __restrict__ dn_w1, const float* __restrict__ dn_w2,
    const float* __restrict__ de_w1, const float* __restrict__ de_w2,
    const float* __restrict__ de_b2,
    uint16_t* __restrict__ cw1b, uint16_t* __restrict__ cw2b,
    uint32_t* __restrict__ mvwpk, float* __restrict__ mvb,
    uint16_t* __restrict__ w1p, uint16_t* __restrict__ w2p,
    uint16_t* __restrict__ dnw1b, uint16_t* __restrict__ dnw2b,
    uint16_t* __restrict__ dew1b, uint16_t* __restrict__ dew2b,
    float* __restrict__ deb2s)
{
    int i = blockIdx.x*256 + threadIdx.x;
    if (i < 262144){
        int o = (i >> 8) & 255, k = i & 255;
        int dst = (i & ~65535) | ((k >> 3) << 11) | (o << 3) | (k & 7);
        cw1b[dst] = to_b16(conv_w1[i]);
        return;
    }
    i -= 262144;
    if (i < 262144){
        int o = (i >> 8) & 255, k = i & 255;
        int dst = (i & ~65535) | ((k >> 3) << 11) | (o << 3) | (k & 7);
        cw2b[dst] = to_b16(conv_w2[i]);
        return;
    }
    i -= 262144;
    if (i < 65536){
        int o = i >> 8, k2 = i & 255;
        float v = (o < 128) ? mu_w[o*256 + k2] : lv_w[(o-128)*256 + k2];
        mvwpk[i] = pack_hl(v);
        if (i < 256) mvb[i] = (i < 128) ? mu_b[i] : lv_b[i-128];
        return;
    }
    i -= 65536;
    if (i < 131072){
        int flow = i >> 15;
        int o  = (i >> 7) & 255;
        int kk = i & 127;
        float v = (kk <= (o % 127)) ? fw1[i] : 0.f;
        uint32_t h = bf16_rne_bits(v);
        int kc = kk >> 5, lq = (kk >> 3) & 3, e = kk & 7;
        size_t dst = (size_t)flow*65536 + (size_t)kc*16384 + (size_t)(lq*256 + o)*8 + e;
        w1p[dst]        = (uint16_t)(h >> 16);
        w1p[dst + 8192] = (uint16_t)(bf16_rne_bits(v - __uint_as_float(h)) >> 16);
        return;
    }
    i -= 131072;
    if (i < 262144){
        int flow = i >> 16;
        int o  = (i >> 8) & 255;
        int hh = i & 255;
        float v = ((hh % 127) < (o & 127)) ? fw2[i] : 0.f;
        uint32_t h = bf16_rne_bits(v);
        int kc = hh >> 5, lq = (hh >> 3) & 3, e = hh & 7;
        size_t dst = (size_t)flow*131072 + (size_t)kc*16384 + (size_t)(lq*256 + o)*8 + e;
        w2p[dst]        = (uint16_t)(h >> 16);
        w2p[dst + 8192] = (uint16_t)(bf16_rne_bits(v - __uint_as_float(h)) >> 16);
        return;
    }
    i -= 262144;
    if (i < 32768){ dnw1b[i] = to_b16(dn_w1[i]); return; }
    i -= 32768;
    if (i < 393216){           // node-decoder W2: 1444 rows padded to 1536, packed
        int o = i >> 8, k = i & 255;
        float v = (o < MA*NNF_) ? dn_w2[(size_t)o*256 + k] : 0.f;
        size_t dst = (size_t)(o >> 8)*65536 + (size_t)(k >> 5)*8192
                   + (size_t)((k >> 3) & 3)*2048 + (size_t)(o & 255)*8 + (size_t)(k & 7);
        dnw2b[dst] = to_b16(v);
        return;
    }
    i -= 393216;
    if (i < 65536){ dew1b[i] = to_b16(de_w1[i]); return; }
    i -= 65536;
    if (i < 3014656){          // edge-decoder W2: symmetrized, 5776 rows padded to 5888, packed
        int o = i >> 9, k = i & 511;
        float v = 0.f;
        if (o < MA*MA*NEF_){
            int e = o & 3, cell = o >> 2;
            int ii = cell / MA, jj = cell - ii*MA;
            int ot = (jj*MA + ii)*4 + e;
            v = 0.5f*(de_w2[(size_t)o*512 + k] + de_w2[(size_t)ot*512 + k]);
            if (k == 0) deb2s[o] = 0.5f*(de_b2[o] + de_b2[ot]);
        }
        size_t dst = (size_t)(o >> 8)*131072 + (size_t)(k >> 5)*8192
                   + (size_t)((k >> 3) & 3)*2048 + (size_t)(o & 255)*8 + (size_t)(k & 7);
        dew2b[dst] = to_b16(v);
    }
}

// ---------------- fused conv v5: LDS-streamed weights + counted vmcnt ----------------
// R7 lesson: __syncthreads per chunk drains vmcnt(0) -> every chunk exposed
// full stage latency, dbuf useless. Now: STAGE(next); vmcnt(4) (chunk kc
// landed, next stays in flight); s_barrier; MFMA; s_barrier. Phase
// boundaries use lgkm-only BARRIER so the next phase's chunk0 rides across.

__global__ __launch_bounds__(256) void k_conv2(
    const uint16_t* __restrict__ A,
    const uint16_t* __restrict__ W1p, const float* __restrict__ B1,
    const uint16_t* __restrict__ W2p, const float* __restrict__ B2,
    uint16_t* __restrict__ C)
{
    extern __shared__ __align__(16) char smem[];
    const int tid  = threadIdx.x;
    const int wave = tid >> 6;
    const int lane = tid & 63;
    const int l15  = lane & 15;
    const int lq   = lane >> 4;
    const int l7   = lane & 7;
    const int row0 = blockIdx.x * 64;
    char* wb0 = smem + 32768;
    char* wb1 = smem + 32768 + 16384;

    #define STAGE_W(Wp, kc, wb)                                              \
        { _Pragma("unroll")                                                  \
          for (int it=0; it<4; ++it){                                        \
            int s = it*256 + tid;                                            \
            __builtin_amdgcn_global_load_lds(                                \
                (const __attribute__((address_space(1))) uint32_t*)          \
                    ((const char*)(Wp) + (size_t)(kc)*16384 + (size_t)s*16), \
                (__attribute__((address_space(3))) uint32_t*)((wb) + s*16),  \
                16, 0, 0);                                                   \
          } }

    #pragma unroll
    for (int it = 0; it < 8; ++it) {
        int s  = it*256 + tid;
        int m  = s >> 5;
        int gl = (s & 31) ^ (m & 7);
        const char* gp = (const char*)A + ((size_t)(row0+m)*HIDDEN)*2 + gl*16;
        __builtin_amdgcn_global_load_lds(
            (const __attribute__((address_space(1))) uint32_t*)gp,
            (__attribute__((address_space(3))) uint32_t*)(smem + (size_t)s*16),
            16, 0, 0);
    }
    STAGE_W(W1p, 0, wb0);
    asm volatile("s_waitcnt vmcnt(0) lgkmcnt(0)" ::: "memory");
    __builtin_amdgcn_sched_barrier(0);
    SBAR();

    // ---- GEMM1 ----
    f32x4 acc[4][4];
    #pragma unroll
    for (int mt=0;mt<4;mt++)
        #pragma unroll
        for (int nt=0;nt<4;nt++) acc[mt][nt] = (f32x4)(0.f);

    #pragma unroll
    for (int kc = 0; kc < 8; ++kc){
        char* rdb = (kc & 1) ? wb1 : wb0;
        char* stb = (kc & 1) ? wb0 : wb1;
        if (kc < 7){ STAGE_W(W1p, kc+1, stb); } else { STAGE_W(W2p, 0, stb); }
        WAITV4();        // chunk kc landed; next chunk stays in flight
        SBAR();
        bf16x8 bw[4];
        #pragma unroll
        for (int nt=0;nt<4;nt++)
            bw[nt] = *(const bf16x8*)(rdb + (size_t)((lq*256 + wave*64 + nt*16 + l15)) * 16);
        #pragma unroll
        for (int mt=0;mt<4;mt++){
            const int mb = (mt*16 + l15) << 5;
            int g = kc*4 + lq;
            bf16x8 a = *(const bf16x8*)(smem + (size_t)(mb + (g ^ l7))*16);
            #pragma unroll
            for (int nt=0;nt<4;nt++)
                acc[mt][nt] = MFMA16(a, bw[nt], acc[mt][nt], 0, 0, 0);
        }
        SBAR();          // reads of chunk kc done -> its buffer reusable
    }

    // epilogue1 -> h1 into A region (W2 chunk0 still in flight)
    uint16_t* h1 = (uint16_t*)smem;
    #pragma unroll
    for (int mt=0;mt<4;mt++){
        #pragma unroll
        for (int nt=0;nt<4;nt++){
            int col = wave*64 + nt*16 + l15;
            float bb = B1[col];
            #pragma unroll
            for (int reg=0;reg<4;reg++){
                int r = mt*16 + lq*4 + reg;
                float v = fmaxf(acc[mt][nt][reg] + bb, 0.f);
                h1[(r*32 + ((col>>3) ^ (r&7)))*8 + (col&7)] = to_b16(v);
            }
        }
    }
    BARRIER();           // lgkm only: h1 visible; W2c0 still streaming

    // ---- GEMM2 ----
    #pragma unroll
    for (int mt=0;mt<4;mt++)
        #pragma unroll
        for (int nt=0;nt<4;nt++) acc[mt][nt] = (f32x4)(0.f);

    #pragma unroll
    for (int kc = 0; kc < 8; ++kc){
        char* rdb = (kc & 1) ? wb1 : wb0;
        char* stb = (kc & 1) ? wb0 : wb1;
        if (kc < 7){ STAGE_W(W2p, kc+1, stb); WAITV4(); } else { WAITV0(); }
        SBAR();
        bf16x8 bw[4];
        #pragma unroll
        for (int nt=0;nt<4;nt++)
            bw[nt] = *(const bf16x8*)(rdb + (size_t)((lq*256 + wave*64 + nt*16 + l15)) * 16);
        #pragma unroll
        for (int mt=0;mt<4;mt++){
            int m = mt*16 + l15;
            bf16x8 a = *(const bf16x8*)(h1 + (size_t)(m*32 + ((kc*4 + lq) ^ (m & 7)))*8);
            #pragma unroll
            for (int nt=0;nt<4;nt++)
                acc[mt][nt] = MFMA16(a, bw[nt], acc[mt][nt], 0, 0, 0);
        }
        SBAR();
    }

    // epilogue2 -> A region, stage-style swizzle for coalesced copy-out
    uint16_t* rs = (uint16_t*)smem;
    #pragma unroll
    for (int mt=0;mt<4;mt++){
        #pragma unroll
        for (int nt=0;nt<4;nt++){
            int col = wave*64 + nt*16 + l15;
            float bb = B2[col];
            #pragma unroll
            for (int reg=0;reg<4;reg++){
                int r = mt*16 + lq*4 + reg;
                float v = fmaxf(acc[mt][nt][reg] + bb, 0.f);
                rs[(r*32 + ((col>>3) ^ (r&7)))*8 + (col&7)] = to_b16(v);
            }
        }
    }
    BARRIER();

    #pragma unroll
    for (int it = 0; it < 8; ++it){
        int s   = it*256 + tid;
        int row = s >> 5;
        int gc  = s & 31;
        uint4 d = *(const uint4*)(smem + (size_t)(row*32 + (gc ^ (row & 7)))*16);
        *(uint4*)(C + (size_t)(row0+row)*HIDDEN + gc*8) = d;
    }
    #undef STAGE_W
}

// ---------------- MFMA GEMM (mu/lv + decoders) ----------------
// PACKED=1: fragment-order 16KB chunks streamed via global_load_lds with
// counted vmcnt (no full drains inside the chunk loop).

template<int SPLIT, int OUTM, int PACKED = 0>
__global__ __launch_bounds__(256) void mfma_gemm(
    const void* __restrict__ Ap, const void* __restrict__ Wp,
    const float* __restrict__ bias, void* __restrict__ Cp,
    int M, int N, int K, int relu)
{
    extern __shared__ __align__(16) char smem[];
    const int tid  = threadIdx.x;
    const int wave = tid >> 6;
    const int lane = tid & 63;
    const int l15  = lane & 15;
    const int lq   = lane >> 4;
    const int l7   = lane & 7;
    const int row0 = blockIdx.y * 64;
    const int n0   = blockIdx.x * 256;
    const int ELB  = SPLIT ? 4 : 2;
    const int KC   = (K < 256) ? K : 256;
    const int GR   = (KC * ELB) >> 4;
    const int rsh  = (GR == 64) ? 6 : ((GR == 32) ? 5 : 4);

    f32x4 acc[4][4];
    #pragma unroll
    for (int mt=0;mt<4;mt++)
        #pragma unroll
        for (int nt=0;nt<4;nt++) acc[mt][nt] = (f32x4)(0.f);

    const char* Ab = (const char*)Ap;
    const char* Wb = (const char*)Wp;
    const char* Wsl = Wb + (size_t)blockIdx.x * (size_t)K * 512;
    char* wbp0 = smem + 32768;
    char* wbp1 = smem + 32768 + 16384;
    int pb = 0;
    const int NCH = K >> 5;

    #define STAGE_PK(ch, wb)                                                 \
        { _Pragma("unroll")                                                  \
          for (int it=0; it<4; ++it){                                        \
            int s = it*256 + tid;                                            \
            __builtin_amdgcn_global_load_lds(                                \
                (const __attribute__((address_space(1))) uint32_t*)          \
                    (Wsl + (size_t)(ch)*16384 + (size_t)s*16),               \
                (__attribute__((address_space(3))) uint32_t*)((wb) + s*16),  \
                16, 0, 0);                                                   \
          } }

    for (int kbase = 0; kbase < K; kbase += KC) {
        const int rounds = GR >> 2;
        for (int it = 0; it < rounds; ++it) {
            int sbase = it*256 + wave*64;
            int s  = sbase + lane;
            int m  = s >> rsh;
            int gl = (s & (GR-1)) ^ (m & 7);
            const char* gp = Ab + ((size_t)(row0+m)*K + kbase)*ELB + gl*16;
            __builtin_amdgcn_global_load_lds(
                (const __attribute__((address_space(1))) uint32_t*)gp,
                (__attribute__((address_space(3))) uint32_t*)(smem + sbase*16),
                16, 0, 0);
        }
        if (PACKED && kbase == 0) STAGE_PK(0, wbp0);
        if (!PACKED) __syncthreads();

        for (int kc = 0; kc < (KC >> 5); ++kc) {
            bf16x8 bhi[4], blo[4];
            if (PACKED){
                int gch = (kbase >> 5) + kc;
                char* rdb = pb ? wbp1 : wbp0;
                if (gch + 1 < NCH){ char* stb = pb ? wbp0 : wbp1; STAGE_PK(gch+1, stb); WAITV4(); }
                else { WAITV0(); }
                SBAR();          // chunk gch (and A for this kbase) ready for all waves
                #pragma unroll
                for (int nt=0;nt<4;nt++)
                    bhi[nt] = *(const bf16x8*)(rdb + (size_t)(lq*256 + wave*64 + nt*16 + l15)*16);
            } else {
                #pragma unroll
                for (int nt=0;nt<4;nt++){
                    int n = n0 + wave*64 + nt*16 + l15;
                    if (n >= N) n = N-1;
                    if (SPLIT){
                        const uint4* wp4 = (const uint4*)(Wb + ((size_t)n*K + kbase + kc*32 + lq*8)*4);
                        uint4 xx = wp4[0], yy = wp4[1];
                        unpack_frag(xx, yy, bhi[nt], blo[nt]);
                    } else {
                        bhi[nt] = *(const bf16x8*)(Wb + ((size_t)n*K + kbase + kc*32 + lq*8)*2);
                    }
                }
            }
            #pragma unroll
            for (int mt=0;mt<4;mt++){
                const int mb = (mt*16 + l15) << rsh;
                if (SPLIT){
                    int g0 = kc*8 + lq*2;
                    uint4 xx = *(const uint4*)(smem + (size_t)(mb + ((g0  ) ^ l7))*16);
                    uint4 yy = *(const uint4*)(smem + (size_t)(mb + ((g0+1) ^ l7))*16);
                    bf16x8 ahi, alo;
                    unpack_frag(xx, yy, ahi, alo);
                    #pragma unroll
                    for (int nt=0;nt<4;nt++){
                        acc[mt][nt] = MFMA16(ahi, bhi[nt], acc[mt][nt], 0, 0, 0);
                        acc[mt][nt] = MFMA16(ahi, blo[nt], acc[mt][nt], 0, 0, 0);
                        acc[mt][nt] = MFMA16(alo, bhi[nt], acc[mt][nt], 0, 0, 0);
                    }
                } else {
                    int g = kc*4 + lq;
                    bf16x8 a = *(const bf16x8*)(smem + (size_t)(mb + (g ^ l7))*16);
                    #pragma unroll
                    for (int nt=0;nt<4;nt++){
                        acc[mt][nt] = MFMA16(a, bhi[nt], acc[mt][nt], 0, 0, 0);
                    }
                }
            }
            if (PACKED){ SBAR(); pb ^= 1; }
        }
        if (!PACKED) __syncthreads(); else SBAR();
    }

    const int ES = (OUTM == 1) ? 2 : 4;
    char* rs = smem + wave*(64*64*ES);
    const int colbase = n0 + wave*64;
    #pragma unroll
    for (int mt=0;mt<4;mt++){
        #pragma unroll
        for (int nt=0;nt<4;nt++){
            int cl = nt*16 + l15;
            int col = colbase + cl;
            float bb = bias[col < N ? col : N-1];
            #pragma unroll
            for (int reg=0;reg<4;reg++){
                int r = mt*16 + lq*4 + reg;
                float v = acc[mt][nt][reg] + bb;
                if (relu) v = fmaxf(v, 0.f);
                if (OUTM == 1) ((uint16_t*)rs)[r*64 + cl] = to_b16(v);
                else           ((float*)rs)[r*64 + cl] = v;
            }
        }
    }
    __syncthreads();
    for (int it = 0; it < 32; ++it) {
        int r   = it*2 + (lane>>5);
        int clp = lane & 31;
        int col = colbase + clp*2;
        if (col < N){
            if (OUTM == 1){
                uint32_t d = *(const uint32_t*)((const uint16_t*)rs + r*64 + clp*2);
                *(uint32_t*)((char*)Cp + ((size_t)(row0+r)*N + col)*2) = d;
            } else {
                float2 d = *(const float2*)((const float*)rs + r*64 + clp*2);
                *(float2*)((float*)Cp + (size_t)(row0+r)*N + col) = d;
            }
        }
    }
    #undef STAGE_PK
}

// ---------------- pooling + z0 elementwise ----------------

__global__ void k_pool(const uint16_t* __restrict__ h, const int* __restrict__ gstart,
                       const int* __restrict__ gcnt, uint32_t* __restrict__ hg){
    int b = blockIdx.x; int c = threadIdx.x;
    int s0 = gstart[b]; int n = gcnt[b];
    float s = 0.f;
    for (int j=0;j<n;j++) s += from_b16(h[(size_t)(s0+j)*HIDDEN + c]);
    hg[(size_t)b*HIDDEN + c] = pack_hl(s);
}

__global__ void k_z0(const float* __restrict__ mv, const float* __restrict__ eps,
                     float* __restrict__ mu_o, float* __restrict__ lv_o, float* __restrict__ z0_o){
    int i = blockIdx.x*256 + threadIdx.x;
    if (i >= NB*LAT) return;
    int b = i >> 7, l = i & 127;
    float m = mv[(size_t)b*256 + l];
    float v = mv[(size_t)b*256 + l + 128];
    mu_o[i] = m;
    lv_o[i] = v;
    z0_o[i] = m + eps[i]*expf(0.5f*v);
}

// ---------------- fused MFMA flows v8: LDS-streamed weights + counted vmcnt ----------------

__global__ __launch_bounds__(1024) void k_flows_mfma8(
    const float* __restrict__ z0,
    const uint16_t* __restrict__ w1p, const float* __restrict__ fb1,
    const uint16_t* __restrict__ w2p, const float* __restrict__ fb2,
    float* __restrict__ zK, uint16_t* __restrict__ zkb, float* __restrict__ sld)
{
    __shared__ __align__(16) uint16_t zhi[16][136];
    __shared__ __align__(16) uint16_t zlo[16][136];
    __shared__ __align__(16) uint16_t h1hi[16][280];
    __shared__ __align__(16) uint16_t h1lo[16][280];
    __shared__ __align__(16) float    oS[16][268];
    __shared__ __align__(16) uint16_t wbuf[2][16384];
    const int tid  = threadIdx.x;
    const int wave = tid >> 6;
    const int lane = tid & 63;
    const int l15  = lane & 15;
    const int lq   = lane >> 4;
    const int g0   = blockIdx.x * 16;
    const int col  = wave*16 + l15;
    const int fo   = (lq*256 + col)*8;

    #define STAGE_C(srcp, buf)                                               \
        { _Pragma("unroll")                                                  \
          for (int it=0; it<2; ++it){                                        \
            int s = it*1024 + tid;                                           \
            __builtin_amdgcn_global_load_lds(                                \
                (const __attribute__((address_space(1))) uint32_t*)          \
                    ((const char*)(srcp) + (size_t)s*16),                    \
                (__attribute__((address_space(3))) uint32_t*)                \
                    ((char*)&wbuf[buf][0] + (size_t)s*16),                   \
                16, 0, 0);                                                   \
          } }

    int pb = 0;
    STAGE_C(w1p, 0);

    #pragma unroll
    for (int q=0;q<2;q++){
        int idx = q*1024 + tid;
        int r = idx >> 7, l = idx & 127;
        float v = z0[(size_t)(g0 + r)*LAT + l];
        uint32_t h = bf16_rne_bits(v);
        zhi[r][l] = (uint16_t)(h >> 16);
        zlo[r][l] = (uint16_t)(bf16_rne_bits(v - __uint_as_float(h)) >> 16);
    }
    float ldacc = 0.f;
    asm volatile("s_waitcnt vmcnt(0) lgkmcnt(0)" ::: "memory");
    __builtin_amdgcn_sched_barrier(0);
    SBAR();

    for (int kf=0; kf<NFLOWS; kf++){
        const uint16_t* W1f = w1p + (size_t)kf*65536;
        const uint16_t* W2f = w2p + (size_t)kf*131072;

        // ---- GEMM1: 4 chunks ----
        f32x4 acc = (f32x4)(0.f);
        #pragma unroll
        for (int kc=0;kc<4;kc++){
            const uint16_t* nxt = (kc < 3) ? (W1f + (size_t)(kc+1)*16384) : W2f;
            STAGE_C(nxt, pb^1);
            WAITV2();        // chunk kc ready; next stays in flight
            SBAR();
            bf16x8 wh = *(const bf16x8*)&wbuf[pb][fo];
            bf16x8 wl = *(const bf16x8*)&wbuf[pb][fo + 8192];
            bf16x8 ah = *(const bf16x8*)&zhi[l15][kc*32 + lq*8];
            bf16x8 al = *(const bf16x8*)&zlo[l15][kc*32 + lq*8];
            acc = MFMA16(ah, wh, acc, 0, 0, 0);
            acc = MFMA16(ah, wl, acc, 0, 0, 0);
            acc = MFMA16(al, wh, acc, 0, 0, 0);
            SBAR();
            pb ^= 1;
        }
        {
            float bb = fb1[kf*FHID + col];
            #pragma unroll
            for (int reg=0;reg<4;reg++){
                int r = lq*4 + reg;
                float v = fmaxf(acc[reg] + bb, 0.f);
                uint32_t h = bf16_rne_bits(v);
                h1hi[r][col] = (uint16_t)(h >> 16);
                h1lo[r][col] = (uint16_t)(bf16_rne_bits(v - __uint_as_float(h)) >> 16);
            }
        }
        BARRIER();   // lgkm only: h1 visible; W2 chunk0 still streaming

        // ---- GEMM2: 8 chunks ----
        f32x4 a2 = (f32x4)(0.f);
        #pragma unroll
        for (int kc=0;kc<8;kc++){
            if (kc < 7){
                STAGE_C(W2f + (size_t)(kc+1)*16384, pb^1);
                WAITV2();
            } else if (kf < NFLOWS-1){
                STAGE_C(w1p + (size_t)(kf+1)*65536, pb^1);
                WAITV2();
            } else {
                WAITV0();
            }
            SBAR();
            bf16x8 wh = *(const bf16x8*)&wbuf[pb][fo];
            bf16x8 wl = *(const bf16x8*)&wbuf[pb][fo + 8192];
            bf16x8 ah = *(const bf16x8*)&h1hi[l15][kc*32 + lq*8];
            bf16x8 al = *(const bf16x8*)&h1lo[l15][kc*32 + lq*8];
            a2 = MFMA16(ah, wh, a2, 0, 0, 0);
            a2 = MFMA16(ah, wl, a2, 0, 0, 0);
            a2 = MFMA16(al, wh, a2, 0, 0, 0);
            SBAR();
            pb ^= 1;
        }
        {
            float bb = fb2[kf*2*LAT + col];
            #pragma unroll
            for (int reg=0;reg<4;reg++)
                oS[lq*4 + reg][col] = a2[reg] + bb;
        }
        BARRIER();

        // ---- z update + log-det ----
        {
            const int r = wave;
            float ldp = 0.f;
            #pragma unroll
            for (int j=0;j<2;j++){
                int l = lane + j*64;
                float m = oS[r][l];
                float s = oS[r][l + 128];
                float g = 1.f/(1.f + expf(-s));
                float zv = __uint_as_float((uint32_t)zhi[r][l] << 16)
                         + __uint_as_float((uint32_t)zlo[r][l] << 16);
                float zn = g*zv + (1.f - g)*m;
                uint32_t h = bf16_rne_bits(zn);
                zhi[r][l] = (uint16_t)(h >> 16);
                zlo[r][l] = (uint16_t)(bf16_rne_bits(zn - __uint_as_float(h)) >> 16);
                ldp += logf(g + 1e-8f);
            }
            #pragma unroll
            for (int off=1; off<64; off<<=1) ldp += __shfl_xor(ldp, off);
            ldacc += ldp;
        }
        BARRIER();
    }

    #pragma unroll
    for (int q=0;q<2;q++){
        int idx = q*1024 + tid;
        int r = idx >> 7, l = idx & 127;
        uint32_t h = (uint32_t)zhi[r][l] << 16;
        float zv = __uint_as_float(h) + __uint_as_float((uint32_t)zlo[r][l] << 16);
        zK[(size_t)(g0+r)*LAT + l] = zv;
        zkb[(size_t)(g0+r)*LAT + l] = (uint16_t)(h >> 16);
    }
    if (lane == 0) sld[g0 + wave] = ldacc;
    #undef STAGE_C
}

// ---------------- launch ----------------

extern "C" void kernel_launch(void* const* d_in, const int* in_sizes, int n_in,
                              void* d_out, int out_size, void* d_ws, size_t ws_size,
                              hipStream_t stream){
    (void)in_sizes; (void)n_in; (void)out_size; (void)ws_size;
    const int*   x        = (const int*)d_in[0];
    const int*   eidx     = (const int*)d_in[1];
    const int*   eattr    = (const int*)d_in[2];
    const int*   batch    = (const int*)d_in[3];
    const float* eps      = (const float*)d_in[4];
    const float* node_emb = (const float*)d_in[5];
    const float* edge_emb = (const float*)d_in[6];
    const float* conv_w1  = (const float*)d_in[7];
    const float* conv_b1  = (const float*)d_in[8];
    const float* conv_w2  = (const float*)d_in[9];
    const float* conv_b2  = (const float*)d_in[10];
    const float* mu_w     = (const float*)d_in[11];
    const float* mu_b     = (const float*)d_in[12];
    const float* lv_w     = (const float*)d_in[13];
    const float* lv_b     = (const float*)d_in[14];
    const float* fw1      = (const float*)d_in[15];
    const float* fb1      = (const float*)d_in[16];
    const float* fw2      = (const float*)d_in[17];
    const float* fb2      = (const float*)d_in[18];
    const float* dn_w1    = (const float*)d_in[19];
    const float* dn_b1    = (const float*)d_in[20];
    const float* dn_w2    = (const float*)d_in[21];
    const float* dn_b2    = (const float*)d_in[22];
    const float* de_w1    = (const float*)d_in[23];
    const float* de_b1    = (const float*)d_in[24];
    const float* de_w2    = (const float*)d_in[25];
    const float* de_b2    = (const float*)d_in[26];

    float* out = (float*)d_out;
    const size_t off_node = 0;
    const size_t off_edge = (size_t)NB*MA*NNF_;
    const size_t off_mu   = off_edge + (size_t)NB*MA*MA*NEF_;
    const size_t off_lv   = off_mu + (size_t)NB*LAT;
    const size_t off_z0   = off_lv + (size_t)NB*LAT;
    const size_t off_zk   = off_z0 + (size_t)NB*LAT;
    const size_t off_sld  = off_zk + (size_t)NB*LAT;
    (void)off_node;

    char* p = (char*)d_ws;
    auto alloc = [&](size_t bytes)->char*{ char* r = p; p += (bytes + 255) & ~(size_t)255; return r; };
    uint16_t* h_b   = (uint16_t*)alloc((size_t)N_NODES*HIDDEN*2);
    uint16_t* t_b   = (uint16_t*)alloc((size_t)N_NODES*HIDDEN*2);
    int*   offs   = (int*)  alloc((size_t)(N_NODES+1)*4);
    int*   cursor = (int*)  alloc((size_t)N_NODES*4);
    int*   epack  = (int*)  alloc((size_t)N_EDGES*4);
    int*   gstart = (int*)  alloc((size_t)NB*4);
    int*   gcnt   = (int*)  alloc((size_t)NB*4);
    uint32_t* hg_pk = (uint32_t*)alloc((size_t)NB*HIDDEN*4);
    float* mv       = (float*)alloc((size_t)NB*256*4);
    uint16_t* cw1b  = (uint16_t*)alloc((size_t)4*HIDDEN*HIDDEN*2);
    uint16_t* cw2b  = (uint16_t*)alloc((size_t)4*HIDDEN*HIDDEN*2);
    uint32_t* mvwpk = (uint32_t*)alloc((size_t)256*256*4);
    float*    mvb   = (float*)  alloc((size_t)256*4);
    uint16_t* w1p   = (uint16_t*)alloc((size_t)NFLOWS*65536*2);
    uint16_t* w2p   = (uint16_t*)alloc((size_t)NFLOWS*131072*2);
    uint16_t* dnw1b = (uint16_t*)alloc((size_t)256*LAT*2);
    uint16_t* dnw2b = (uint16_t*)alloc((size_t)1536*256*2);
    uint16_t* dew1b = (uint16_t*)alloc((size_t)512*LAT*2);
    uint16_t* dew2b = (uint16_t*)alloc((size_t)5888*512*2);
    float*    deb2s = (float*)  alloc((size_t)MA*MA*NEF_*4);
    uint16_t* zkb   = (uint16_t*)alloc((size_t)NB*LAT*2);
    uint16_t* hnb   = (uint16_t*)alloc((size_t)NB*256*2);
    uint16_t* heb   = (uint16_t*)alloc((size_t)NB*512*2);

    const int* esrc = eidx;
    const int* edst = eidx + N_EDGES;

    k_cvt_all<<<(CVT_TOTAL+255)/256, 256, 0, stream>>>(
        conv_w1, conv_w2, mu_w, mu_b, lv_w, lv_b, fw1, fw2,
        dn_w1, dn_w2, de_w1, de_w2, de_b2,
        cw1b, cw2b, mvwpk, mvb, w1p, w2p,
        dnw1b, dnw2b, dew1b, dew2b, deb2s);

    k_init   <<<(N_NODES+255)/256, 256, 0, stream>>>(cursor, gstart, gcnt);
    k_embed  <<<N_NODES, HIDDEN, 0, stream>>>(x, node_emb, h_b);
    k_deg    <<<(N_EDGES+255)/256, 256, 0, stream>>>(edst, cursor);
    k_meta   <<<(N_NODES+255)/256, 256, 0, stream>>>(batch, gstart, gcnt);
    k_scan   <<<1, 1024, 0, stream>>>(cursor, offs);
    k_scatter<<<(N_EDGES+255)/256, 256, 0, stream>>>(esrc, edst, eattr, offs, cursor, epack);

    const size_t SM32 = 32768, SM64 = 65536;
    for (int k=0;k<4;k++){
        k_aggr<<<N_NODES/4, 256, 0, stream>>>(h_b, edge_emb, offs, epack, t_b);
        k_conv2<<<N_NODES/64, 256, SM64, stream>>>(
            t_b,
            cw1b + (size_t)k*HIDDEN*HIDDEN, conv_b1 + (size_t)k*HIDDEN,
            cw2b + (size_t)k*HIDDEN*HIDDEN, conv_b2 + (size_t)k*HIDDEN,
            h_b);
    }

    k_pool<<<NB, HIDDEN, 0, stream>>>(h_b, gstart, gcnt, hg_pk);
    mfma_gemm<1,2><<<dim3(1, NB/64), 256, SM64, stream>>>(hg_pk, mvwpk, mvb, mv, NB, 256, HIDDEN, 0);
    k_z0<<<(NB*LAT+255)/256, 256, 0, stream>>>(mv, eps, out+off_mu, out+off_lv, out+off_z0);

    k_flows_mfma8<<<NB/16, 1024, 0, stream>>>(out+off_z0, w1p, fb1, w2p, fb2,
                                              out+off_zk, zkb, out+off_sld);

    mfma_gemm<0,1><<<dim3(1, NB/64), 256, SM32, stream>>>(zkb, dnw1b, dn_b1, hnb, NB, 256, LAT, 1);
    mfma_gemm<0,2,1><<<dim3(6, NB/64), 256, SM64, stream>>>(hnb, dnw2b, dn_b2, out+off_node, NB, MA*NNF_, 256, 0);
    mfma_gemm<0,1><<<dim3(2, NB/64), 256, SM32, stream>>>(zkb, dew1b, de_b1, heb, NB, 512, LAT, 1);
    mfma_gemm<0,2,1><<<dim3(23, NB/64), 256, SM64, stream>>>(heb, dew2b, deb2s, out+off_edge, NB, MA*MA*NEF_, 512, 0);
}